// Round 1
// 946.671 us; speedup vs baseline: 1.0946x; 1.0946x over previous
//
#include <hip/hip_runtime.h>
#include <hip/hip_bf16.h>

// Problem constants (B=8, N=1024, D=512, H=8, HD=64, E=4096, NE=8, NSH=2, TOPK=2, DH=1024)
// ALL inputs/outputs are float32.
#define TT 8192
#define DD 512

typedef unsigned short u16;
typedef __attribute__((ext_vector_type(8))) short short8;
typedef __attribute__((ext_vector_type(4))) float f32x4;

__device__ __forceinline__ u16 f2b(float f) {
  union { float f; unsigned int i; } w; w.f = f;
  unsigned int x = w.i;
  unsigned int r = (x + 0x7FFFu + ((x >> 16) & 1u)) >> 16;
  if ((x & 0x7F800000u) == 0x7F800000u) r = x >> 16;
  return (u16)r;
}
__device__ __forceinline__ float b2f(u16 u) {
  union { unsigned int i; float f; } w; w.i = ((unsigned int)u) << 16; return w.f;
}

__device__ __forceinline__ void blockReduce2(float& a, float& b, float* s4a, float* s4b) {
  #pragma unroll
  for (int off = 32; off; off >>= 1) { a += __shfl_xor(a, off); b += __shfl_xor(b, off); }
  int wid = threadIdx.x >> 6;
  if ((threadIdx.x & 63) == 0) { s4a[wid] = a; s4b[wid] = b; }
  __syncthreads();
  a = s4a[0] + s4a[1] + s4a[2] + s4a[3];
  b = s4b[0] + s4b[1] + s4b[2] + s4b[3];
}

// ---- zero esum ----
__global__ __launch_bounds__(256) void k_zero(float* __restrict__ esum) {
  esum[blockIdx.x * 256 + threadIdx.x] = 0.f;
}

// ---- edge sum: [B,E,D] -> [B,D] ----
__global__ __launch_bounds__(256) void k_esum(const float* __restrict__ ef, float* __restrict__ esum) {
  int b = blockIdx.x, ec = blockIdx.y, tid = threadIdx.x;
  float a0 = 0.f, a1 = 0.f;
  const float* base = ef + ((size_t)b * 4096 + (size_t)ec * 128) * 512;
  for (int e = 0; e < 128; ++e) {
    a0 += base[(size_t)e * 512 + tid];
    a1 += base[(size_t)e * 512 + tid + 256];
  }
  atomicAdd(&esum[b * 512 + tid], a0);
  atomicAdd(&esum[b * 512 + tid + 256], a1);
}

// ---- einj[b,dp] = (esum[b,:]/E) @ B_w[:,dp] + B_b[dp] ----
__global__ __launch_bounds__(256) void k_einj(const float* __restrict__ esum,
                                              const float* __restrict__ Bw, const float* __restrict__ Bb,
                                              float* __restrict__ einj) {
  int idx = blockIdx.x * 256 + threadIdx.x;
  int b = idx >> 9, dp = idx & 511;
  float a = Bb[dp];
  const float inv = 1.f / 4096.f;
  for (int d = 0; d < 512; ++d)
    a = fmaf(esum[b * 512 + d] * inv, Bw[d * 512 + dp], a);
  einj[idx] = a;
}

// ---- h_lti = LN(-exp(log_A)*h + einj), segment-local output ----
__global__ __launch_bounds__(256) void k_lti(const float* __restrict__ h, const float* __restrict__ lA,
                                             const float* __restrict__ einj,
                                             const float* __restrict__ g, const float* __restrict__ be,
                                             float* __restrict__ out, int seg0) {
  __shared__ float sa[4], sb[4];
  int rowg = seg0 + blockIdx.x, b = rowg >> 10, tid = threadIdx.x;
  int d0 = tid, d1 = tid + 256;
  size_t gbase = (size_t)rowg * 512;
  size_t lbase = (size_t)blockIdx.x * 512;
  float v0 = -expf(lA[d0]) * h[gbase + d0] + einj[b * 512 + d0];
  float v1 = -expf(lA[d1]) * h[gbase + d1] + einj[b * 512 + d1];
  float s = v0 + v1, ss = v0 * v0 + v1 * v1;
  blockReduce2(s, ss, sa, sb);
  float mu = s * (1.f / 512.f);
  float var = fmaxf(ss * (1.f / 512.f) - mu * mu, 0.f);
  float r = rsqrtf(var + 1e-5f);
  out[lbase + d0] = (v0 - mu) * r * g[d0] + be[d0];
  out[lbase + d1] = (v1 - mu) * r * g[d1] + be[d1];
}

// ---- residual LN ----
__global__ __launch_bounds__(256) void k_ln_res(const float* __restrict__ A, const float* __restrict__ Bv,
                                                const float* __restrict__ g, const float* __restrict__ be,
                                                float* __restrict__ outf) {
  __shared__ float sa[4], sb[4];
  int tid = threadIdx.x, d0 = tid, d1 = tid + 256;
  size_t base = (size_t)blockIdx.x * 512;
  float v0 = A[base + d0] + Bv[base + d0];
  float v1 = A[base + d1] + Bv[base + d1];
  float s = v0 + v1, ss = v0 * v0 + v1 * v1;
  blockReduce2(s, ss, sa, sb);
  float mu = s * (1.f / 512.f);
  float var = fmaxf(ss * (1.f / 512.f) - mu * mu, 0.f);
  float r = rsqrtf(var + 1e-5f);
  outf[base + d0] = (v0 - mu) * r * g[d0] + be[d0];
  outf[base + d1] = (v1 - mu) * r * g[d1] + be[d1];
}

// ---- split-precision MFMA GEMM: C = X@W + b with hi/lo bf16 decomposition ----
// x = hi + lo (two bf16), A.B ~= Ah.Bh + Al.Bh + Ah.Bl  (3 MFMAs, f32 accumulate)
// rel. error ~2^-17 -- preserves routing-critical f32-level accuracy on the matrix pipe.
// 64x64 tile, BK=32, 4 waves, 16x16x32 frags. K=N=512 fixed.
// NOUT=3: blockIdx.z selects {q,k,v}; NOUT=1: single output.
template<int NOUT>
__global__ __launch_bounds__(256) void gemm_sp(
    const float* __restrict__ X,
    const float* __restrict__ W0, const float* __restrict__ b0c,
    const float* __restrict__ W1, const float* __restrict__ b1c,
    const float* __restrict__ W2, const float* __restrict__ b2c,
    float* __restrict__ C0, float* __restrict__ C1, float* __restrict__ C2) {
  const float* W = W0; const float* bias = b0c; float* C = C0;
  if (NOUT == 3) {
    int z = blockIdx.z;
    if (z == 1) { W = W1; bias = b1c; C = C1; }
    else if (z == 2) { W = W2; bias = b2c; C = C2; }
  }
  const int K = 512, N = 512;
  const int bm = blockIdx.y << 6, bn = blockIdx.x << 6;
  __shared__ u16 Ah[64][40];
  __shared__ u16 Al[64][40];
  __shared__ u16 Bh[64][40];
  __shared__ u16 Bl[64][40];
  const int tid = threadIdx.x;
  const int srow = tid >> 2;          // 0..63
  const int skg = (tid & 3) << 3;     // 0,8,16,24
  const int wv = tid >> 6, lane = tid & 63, q = lane >> 4, m16 = lane & 15;
  f32x4 acc[4];
  #pragma unroll
  for (int c = 0; c < 4; ++c)
    #pragma unroll
    for (int i = 0; i < 4; ++i) acc[c][i] = 0.f;

  for (int k0 = 0; k0 < K; k0 += 32) {
    __syncthreads();
    // stage A tile (64 rows x 32 k) as hi/lo bf16
    {
      const float* src = X + (size_t)(bm + srow) * K + k0 + skg;
      float4 x0 = *(const float4*)src;
      float4 x1 = *(const float4*)(src + 4);
      float xs[8] = {x0.x, x0.y, x0.z, x0.w, x1.x, x1.y, x1.z, x1.w};
      u16 h8[8] __attribute__((aligned(16)));
      u16 l8[8] __attribute__((aligned(16)));
      #pragma unroll
      for (int j = 0; j < 8; ++j) {
        h8[j] = f2b(xs[j]);
        l8[j] = f2b(xs[j] - b2f(h8[j]));
      }
      *(uint4*)&Ah[srow][skg] = *(uint4*)h8;
      *(uint4*)&Al[srow][skg] = *(uint4*)l8;
    }
    // stage B tile transposed: Bs[n][k] = W[k0+k][bn+n], hi/lo
    {
      const float* src = W + (size_t)(k0 + skg) * N + bn + srow;
      u16 h8[8] __attribute__((aligned(16)));
      u16 l8[8] __attribute__((aligned(16)));
      #pragma unroll
      for (int j = 0; j < 8; ++j) {
        float v = src[(size_t)j * N];
        h8[j] = f2b(v);
        l8[j] = f2b(v - b2f(h8[j]));
      }
      *(uint4*)&Bh[srow][skg] = *(uint4*)h8;
      *(uint4*)&Bl[srow][skg] = *(uint4*)l8;
    }
    __syncthreads();
    short8 afh = *(const short8*)&Ah[wv * 16 + m16][q * 8];
    short8 afl = *(const short8*)&Al[wv * 16 + m16][q * 8];
    #pragma unroll
    for (int c = 0; c < 4; ++c) {
      short8 bfh = *(const short8*)&Bh[c * 16 + m16][q * 8];
      short8 bfl = *(const short8*)&Bl[c * 16 + m16][q * 8];
      acc[c] = __builtin_amdgcn_mfma_f32_16x16x32_bf16(afh, bfh, acc[c], 0, 0, 0);
      acc[c] = __builtin_amdgcn_mfma_f32_16x16x32_bf16(afl, bfh, acc[c], 0, 0, 0);
      acc[c] = __builtin_amdgcn_mfma_f32_16x16x32_bf16(afh, bfl, acc[c], 0, 0, 0);
    }
  }
  // epilogue: lane holds D[row=q*4+i][col=c*16+m16], wave rows base wv*16
  #pragma unroll
  for (int c = 0; c < 4; ++c) {
    int col = bn + c * 16 + m16;
    float bb = bias[col];
    #pragma unroll
    for (int i = 0; i < 4; ++i) {
      int rl = bm + wv * 16 + q * 4 + i;
      C[(size_t)rl * N + col] = acc[c][i] + bb;
    }
  }
}

// ---- per-node head attention ----
__global__ __launch_bounds__(64) void k_attn(const float* __restrict__ q, const float* __restrict__ k,
                                             const float* __restrict__ v, float* __restrict__ ao) {
  __shared__ float qs[512], ks[512], vs[512], at[64];
  size_t t = blockIdx.x;
  int lane = threadIdx.x;
  for (int i = lane; i < 512; i += 64) {
    qs[i] = q[t * 512 + i]; ks[i] = k[t * 512 + i]; vs[i] = v[t * 512 + i];
  }
  __syncthreads();
  int h = lane >> 3, g = lane & 7;
  float s = 0.f;
  #pragma unroll 8
  for (int d = 0; d < 64; ++d) s = fmaf(qs[h * 64 + d], ks[g * 64 + d], s);
  s *= 0.125f;
  float m = s;
  #pragma unroll
  for (int off = 1; off < 8; off <<= 1) m = fmaxf(m, __shfl_xor(m, off));
  float ex = expf(s - m);
  float sum = ex;
  #pragma unroll
  for (int off = 1; off < 8; off <<= 1) sum += __shfl_xor(sum, off);
  at[lane] = ex / sum;
  __syncthreads();
  #pragma unroll
  for (int j = 0; j < 8; ++j) {
    int d = lane + j * 64, hh = d >> 6, hd = d & 63;
    float acc = 0.f;
    #pragma unroll
    for (int gg = 0; gg < 8; ++gg) acc = fmaf(at[hh * 8 + gg], vs[gg * 64 + hd], acc);
    ao[t * 512 + d] = acc;
  }
}

// ---- gate phase A: probs + top2 per token, NO atomics ----
__global__ __launch_bounds__(256) void k_gateA(const float* __restrict__ h2, const float* __restrict__ gw,
                                               const float* __restrict__ gb, float* __restrict__ probs,
                                               int* __restrict__ sel, float2* __restrict__ wpair) {
  int lane = threadIdx.x & 63, wid = threadIdx.x >> 6;
  int t = blockIdx.x * 4 + wid;
  const float* x = h2 + (size_t)t * 512;
  float acc[8] = {};
  for (int d = lane; d < 512; d += 64) {
    float xv = x[d];
    float4 g0 = *(const float4*)(gw + d * 8);
    float4 g1 = *(const float4*)(gw + d * 8 + 4);
    acc[0] = fmaf(xv, g0.x, acc[0]); acc[1] = fmaf(xv, g0.y, acc[1]);
    acc[2] = fmaf(xv, g0.z, acc[2]); acc[3] = fmaf(xv, g0.w, acc[3]);
    acc[4] = fmaf(xv, g1.x, acc[4]); acc[5] = fmaf(xv, g1.y, acc[5]);
    acc[6] = fmaf(xv, g1.z, acc[6]); acc[7] = fmaf(xv, g1.w, acc[7]);
  }
  #pragma unroll
  for (int off = 32; off; off >>= 1)
    #pragma unroll
    for (int e = 0; e < 8; ++e) acc[e] += __shfl_xor(acc[e], off);
  if (lane == 0) {
    float m = -1e30f;
    #pragma unroll
    for (int e = 0; e < 8; ++e) { acc[e] += gb[e]; m = fmaxf(m, acc[e]); }
    float p[8], sum = 0.f;
    #pragma unroll
    for (int e = 0; e < 8; ++e) { p[e] = expf(acc[e] - m); sum += p[e]; }
    float inv = 1.f / sum;
    #pragma unroll
    for (int e = 0; e < 8; ++e) { p[e] *= inv; probs[t * 8 + e] = p[e]; }
    int i1 = 0; float m1 = p[0];
    #pragma unroll
    for (int e = 1; e < 8; ++e) if (p[e] > m1) { m1 = p[e]; i1 = e; }
    int i2 = -1; float m2 = -1.f;
    #pragma unroll
    for (int e = 0; e < 8; ++e) if (e != i1 && p[e] > m2) { m2 = p[e]; i2 = e; }
    if (i2 < 0) i2 = (i1 + 1) & 7;
    float den = m1 + m2;
    float invs = (den > 0.f) ? 1.f / den : 0.f;
    sel[t] = i1 | (i2 << 4);
    wpair[t] = make_float2(m1 * invs, m2 * invs);
  }
}

// ---- gate phase B: per-expert compaction via ballot prefix scan (8 blocks) ----
__global__ __launch_bounds__(256) void k_gateB(const int* __restrict__ sel, const float2* __restrict__ wpair,
                                               int* __restrict__ toklist, float* __restrict__ wlist,
                                               int* __restrict__ cnt) {
  int e = blockIdx.x;
  int tid = threadIdx.x, lane = tid & 63, wv = tid >> 6;
  __shared__ int wsum[4];
  int base = 0;
  for (int t0 = 0; t0 < 8192; t0 += 256) {
    int t = t0 + tid;
    int s = sel[t];
    int i1 = s & 15, i2 = (s >> 4) & 15;
    bool f = (i1 == e) || (i2 == e);
    float wt = (i1 == e) ? wpair[t].x : ((i2 == e) ? wpair[t].y : 0.f);
    unsigned long long m = __ballot(f);
    int rank = __popcll(m & ((1ull << lane) - 1ull));
    int wtot = __popcll(m);
    if (lane == 0) wsum[wv] = wtot;
    __syncthreads();
    int prev = 0;
    for (int ww = 0; ww < wv; ++ww) prev += wsum[ww];
    int tot = wsum[0] + wsum[1] + wsum[2] + wsum[3];
    if (f) {
      int pos = base + prev + rank;
      toklist[e * 8192 + pos] = t;
      wlist[e * 8192 + pos] = wt;
    }
    base += tot;
    __syncthreads();
  }
  if (tid == 0) cnt[e] = base;
}

// ---- MFMA bf16 GEMM: 64x64 tile, BK=32, 4 waves, 16x16x32 frags ----
// XMODE: 0 dense f32, 1 dense bf16, 2 gathered f32 rows (toklist)
// ACT: 0 none, 1 silu, 2 tanh
// OUTMODE: 0 f32 store, 1 f32 +=, 2 bf16 store, 3 weighted scatter-atomicAdd (expertB)
// EXPERT: blockIdx.z = expert; W/bias strided; rows bounded by cnt[e]-chunk0;
//         Xb/C16 offset by e*hidstride (PER-EXPERT hid regions — fixes R5 race)
template<int XMODE, int ACT, int OUTMODE, int EXPERT>
__global__ __launch_bounds__(256) void mfma_gemm(
    const float* __restrict__ Xf, const u16* __restrict__ Xb,
    const float* __restrict__ Wg, const float* __restrict__ biasg,
    float* __restrict__ C, u16* __restrict__ C16,
    const int* __restrict__ toklist, const float* __restrict__ wlist,
    const int* __restrict__ cnt, int M, int K, int N, int chunk0,
    size_t hidstride, float* __restrict__ moe) {
  int e = EXPERT ? blockIdx.z : 0;
  const float* W = Wg + (size_t)e * K * N;
  const float* bias = biasg + (size_t)e * N;
  int Mloc = M;
  if (EXPERT) {
    int ce = cnt[e]; if (ce > 8192) ce = 8192;
    Mloc = ce - chunk0;
    if (XMODE == 1) Xb += (size_t)e * hidstride;     // per-expert hid region
    if (OUTMODE == 2) C16 += (size_t)e * hidstride;  // per-expert hid region
  }
  const int bm = blockIdx.y << 6, bn = blockIdx.x << 6;
  if (EXPERT && bm >= Mloc) return;
  __shared__ u16 As[64][40];
  __shared__ u16 Bs[64][40];
  __shared__ int rows[64];
  const int tid = threadIdx.x;
  if (EXPERT && XMODE == 2 && tid < 64) {
    int ce = cnt[e]; if (ce > 8192) ce = 8192;
    int r = chunk0 + bm + tid;
    rows[tid] = toklist[e * 8192 + (r < ce ? r : chunk0)] & 8191;
  }
  const int srow = tid >> 2;          // 0..63
  const int skg = (tid & 3) << 3;     // 0,8,16,24
  const int wv = tid >> 6, lane = tid & 63, q = lane >> 4, m16 = lane & 15;
  f32x4 acc[4];
  #pragma unroll
  for (int c = 0; c < 4; ++c)
    #pragma unroll
    for (int i = 0; i < 4; ++i) acc[c][i] = 0.f;

  for (int k0 = 0; k0 < K; k0 += 32) {
    __syncthreads();
    // stage A tile (64 rows x 32 k) as bf16
    {
      u16 a8[8] __attribute__((aligned(16)));
      if (XMODE == 1) {
        *(uint4*)a8 = *(const uint4*)(Xb + (size_t)(bm + srow) * K + k0 + skg);
      } else {
        const float* src = (XMODE == 2) ? (Xf + (size_t)rows[srow] * K + k0 + skg)
                                        : (Xf + (size_t)(bm + srow) * K + k0 + skg);
        float4 x0 = *(const float4*)(src);
        float4 x1 = *(const float4*)(src + 4);
        a8[0] = f2b(x0.x); a8[1] = f2b(x0.y); a8[2] = f2b(x0.z); a8[3] = f2b(x0.w);
        a8[4] = f2b(x1.x); a8[5] = f2b(x1.y); a8[6] = f2b(x1.z); a8[7] = f2b(x1.w);
      }
      *(uint4*)&As[srow][skg] = *(uint4*)a8;
    }
    // stage B tile transposed: Bs[n][k] = W[k0+k][bn+n]
    {
      u16 b8[8] __attribute__((aligned(16)));
      const float* src = W + (size_t)(k0 + skg) * N + bn + srow;
      #pragma unroll
      for (int j = 0; j < 8; ++j) b8[j] = f2b(src[(size_t)j * N]);
      *(uint4*)&Bs[srow][skg] = *(uint4*)b8;
    }
    __syncthreads();
    short8 af = *(const short8*)&As[wv * 16 + m16][q * 8];
    #pragma unroll
    for (int c = 0; c < 4; ++c) {
      short8 bf = *(const short8*)&Bs[c * 16 + m16][q * 8];
      acc[c] = __builtin_amdgcn_mfma_f32_16x16x32_bf16(af, bf, acc[c], 0, 0, 0);
    }
  }
  // epilogue: lane holds D[row=q*4+i][col=c*16+m16], wave rows base wv*16
  #pragma unroll
  for (int c = 0; c < 4; ++c) {
    int col = bn + c * 16 + m16;
    float bb = bias[col];
    #pragma unroll
    for (int i = 0; i < 4; ++i) {
      int rl = bm + wv * 16 + q * 4 + i;
      if (EXPERT && rl >= Mloc) continue;
      float v = acc[c][i] + bb;
      if (ACT == 1) v = v / (1.f + expf(-v));
      else if (ACT == 2) v = tanhf(v);
      if (OUTMODE == 0) C[(size_t)rl * N + col] = v;
      else if (OUTMODE == 1) C[(size_t)rl * N + col] += v;
      else if (OUTMODE == 2) C16[(size_t)rl * N + col] = f2b(v);
      else {  // weighted scatter into moe
        int rg = chunk0 + rl;
        int tok = toklist[e * 8192 + rg] & 8191;
        float wt = wlist[e * 8192 + rg];
        atomicAdd(&moe[(size_t)tok * 512 + col], v * wt);
      }
    }
  }
}

// ---- halt head ----
__global__ __launch_bounds__(256) void k_halt(const u16* __restrict__ hh, const float* __restrict__ hW2,
                                              const float* __restrict__ hb2, float* __restrict__ out) {
  int lane = threadIdx.x & 63, wid = threadIdx.x >> 6;
  int t = blockIdx.x * 4 + wid;
  const u16* x = hh + (size_t)t * 256;
  float a = b2f(x[lane]) * hW2[lane] + b2f(x[lane + 64]) * hW2[lane + 64] +
            b2f(x[lane + 128]) * hW2[lane + 128] + b2f(x[lane + 192]) * hW2[lane + 192];
  #pragma unroll
  for (int off = 32; off; off >>= 1) a += __shfl_xor(a, off);
  if (lane == 0) {
    float p = 1.f / (1.f + expf(-(a + hb2[0])));
    out[4194304 + t] = p;
    out[4194304 + 8192 + t] = p;
  }
}

// ---- scalar: stab + aux loss ----
__global__ __launch_bounds__(256) void k_final(const float* __restrict__ probs, const int* __restrict__ cnt,
                                               const float* __restrict__ lA, float* __restrict__ out) {
  __shared__ float sp[4][8];
  __shared__ float sm[4];
  int tid = threadIdx.x, lane = tid & 63, wid = tid >> 6;
  float part[8] = {};
  for (int i = tid; i < 8192; i += 256) {
    const float* p = probs + i * 8;
    #pragma unroll
    for (int e = 0; e < 8; ++e) part[e] += p[e];
  }
  #pragma unroll
  for (int off = 32; off; off >>= 1)
    #pragma unroll
    for (int e = 0; e < 8; ++e) part[e] += __shfl_xor(part[e], off);
  float mx = 0.f;
  for (int d = tid; d < 512; d += 256) mx = fmaxf(mx, expf(lA[d]));
  #pragma unroll
  for (int off = 32; off; off >>= 1) mx = fmaxf(mx, __shfl_xor(mx, off));
  if (lane == 0) {
    #pragma unroll
    for (int e = 0; e < 8; ++e) sp[wid][e] = part[e];
    sm[wid] = mx;
  }
  __syncthreads();
  if (tid == 0) {
    float loss = 0.f;
    for (int e = 0; e < 8; ++e) {
      float pm = (sp[0][e] + sp[1][e] + sp[2][e] + sp[3][e]) * (1.f / 8192.f);
      int c = cnt[e]; if (c > 8192) c = 8192;
      loss += (float)c * (1.f / 8192.f) * pm;
    }
    loss *= 0.01f * 8.f;
    float mall = fmaxf(fmaxf(sm[0], sm[1]), fmaxf(sm[2], sm[3]));
    out[4194304 + 16384] = fmaxf(mall - 0.95f, 0.f) + loss;
  }
}

extern "C" void kernel_launch(void* const* d_in, const int* in_sizes, int n_in,
                              void* d_out, int out_size, void* d_ws, size_t ws_size,
                              hipStream_t stream) {
  const float* h   = (const float*)d_in[0];
  const float* ef  = (const float*)d_in[1];
  const float* lA  = (const float*)d_in[2];
  const float* Bw  = (const float*)d_in[3];
  const float* Bb  = (const float*)d_in[4];
  const float* Wq  = (const float*)d_in[5];  const float* bq  = (const float*)d_in[6];
  const float* Wk  = (const float*)d_in[7];  const float* bk  = (const float*)d_in[8];
  const float* Wv  = (const float*)d_in[9];  const float* bv  = (const float*)d_in[10];
  const float* Wo  = (const float*)d_in[11]; const float* bo  = (const float*)d_in[12];
  const float* n1g = (const float*)d_in[13]; const float* n1b = (const float*)d_in[14];
  const float* n2g = (const float*)d_in[15]; const float* n2b = (const float*)d_in[16];
  const float* n3g = (const float*)d_in[17]; const float* n3b = (const float*)d_in[18];
  const float* gw  = (const float*)d_in[19]; const float* gb  = (const float*)d_in[20];
  const float* eW1 = (const float*)d_in[21]; const float* eb1 = (const float*)d_in[22];
  const float* eW2 = (const float*)d_in[23]; const float* eb2 = (const float*)d_in[24];
  const float* sW1 = (const float*)d_in[25]; const float* sb1 = (const float*)d_in[26];
  const float* sW2 = (const float*)d_in[27]; const float* sb2 = (const float*)d_in[28];
  const float* hW1 = (const float*)d_in[29]; const float* hb1 = (const float*)d_in[30];
  const float* hW2 = (const float*)d_in[31]; const float* hb2 = (const float*)d_in[32];
  float* out = (float*)d_out;
  float* ws = (float*)d_ws;

  // ---- tiered workspace layout (runtime-sized) ----
  // [0,R) h2 | [R,2R) moe | [2R,2R+ARENA) arena | small scratch
  // arena reused: attention (hlti|q|k|v, ao->q hp->k) -> hid bf16 [8][CAPE][1024] -> hh bf16
  const size_t R = (size_t)TT * DD;   // 4,194,304 floats
  const size_t SM = 155648 + 73744;   // floats + ints
  size_t wsf = ws_size / 4;
  int S; size_t ARENA;
  if (wsf >= 6 * R + SM)      { S = 8192; ARENA = 4 * R; }
  else if (wsf >= 3 * R + SM) { S = 2048; ARENA = R; }
  else                        { S = 512;  ARENA = 1048576; }
  // routed-expert per-expert chunk rows: 8*CAPE*1024 u16 == ARENA*4 bytes
  const int CAPE = (int)(ARENA / 4096);          // 4096 / 1024 / 256
  const int NCH  = 8192 / CAPE;                  // worst-case chunks (cnt[e] <= 8192)
  const size_t HIDSTRIDE = (size_t)CAPE * 1024;  // u16 elements per expert region
  // shared-expert chunk rows: CAPS*1024 u16 <= ARENA*4 bytes
  const int CAPS = (ARENA / 512 >= 8192) ? 8192 : (int)(ARENA / 512);  // 8192 / 8192 / 2048

  float* f_h2  = ws;
  float* f_moe = ws + R;
  float* arena = ws + 2 * R;
  const size_t SD = (size_t)S * 512;
  float* f_hlti = arena;
  float* f_q = arena + SD;
  float* f_k = arena + 2 * SD;
  float* f_v = arena + 3 * SD;
  float* f_ao = f_q;
  float* f_hp = f_k;
  u16* f_hid = (u16*)arena;
  u16* f_hh  = (u16*)arena;
  float* smr = ws + 2 * R + ARENA;
  float* f_esum = smr;
  float* f_einj = smr + 4096;
  float* f_probs = smr + 8192;
  float2* f_wpair = (float2*)(smr + 8192 + 65536);
  float* f_wlist = smr + 8192 + 65536 + 16384;
  int* ip = (int*)(smr + 8192 + 65536 + 16384 + 65536);
  int* sel = ip; int* cnt = ip + 8192; int* toklist = ip + 8192 + 16;

  // ---- LTI prep ----
  k_zero<<<16, 256, 0, stream>>>(f_esum);
  k_esum<<<dim3(8, 32), 256, 0, stream>>>(ef, f_esum);
  k_einj<<<16, 256, 0, stream>>>(f_esum, Bw, Bb, f_einj);

  // ---- LTI + attention (split-precision MFMA, routing-critical accuracy kept) ----
  for (int s = 0; s < TT / S; ++s) {
    int seg0 = s * S;
    k_lti<<<S, 256, 0, stream>>>(h, lA, f_einj, n1g, n1b, f_hlti, seg0);
    gemm_sp<3><<<dim3(8, S / 64, 3), 256, 0, stream>>>(
        f_hlti, Wq, bq, Wk, bk, Wv, bv, f_q, f_k, f_v);
    k_attn<<<S, 64, 0, stream>>>(f_q, f_k, f_v, f_ao);
    gemm_sp<1><<<dim3(8, S / 64, 1), 256, 0, stream>>>(
        f_ao, Wo, bo, nullptr, nullptr, nullptr, nullptr, f_hp, nullptr, nullptr);
    k_ln_res<<<S, 256, 0, stream>>>(f_hlti, f_hp, n2g, n2b, f_h2 + (size_t)seg0 * 512);
  }

  // ---- gate: two-phase, no contended atomics ----
  k_gateA<<<TT / 4, 256, 0, stream>>>(f_h2, gw, gb, f_probs, sel, f_wpair);
  k_gateB<<<8, 256, 0, stream>>>(sel, f_wpair, toklist, f_wlist, cnt);

  // ---- shared experts (MFMA), chunked by CAPS ----
  for (int sx = 0; sx < 2; ++sx)
    for (int c = 0; c < TT / CAPS; ++c) {
      const float* xs = f_h2 + (size_t)c * CAPS * 512;
      float* ms = f_moe + (size_t)c * CAPS * 512;
      mfma_gemm<0,1,2,0><<<dim3(16, CAPS / 64), 256, 0, stream>>>(
          xs, nullptr, sW1 + (size_t)sx * 524288, sb1 + sx * 1024,
          nullptr, f_hid, nullptr, nullptr, nullptr, CAPS, 512, 1024, 0, 0, nullptr);
      if (sx == 0)
        mfma_gemm<1,0,0,0><<<dim3(8, CAPS / 64), 256, 0, stream>>>(
            nullptr, f_hid, sW2, sb2, ms, nullptr, nullptr, nullptr, nullptr, CAPS, 1024, 512, 0, 0, nullptr);
      else
        mfma_gemm<1,0,1,0><<<dim3(8, CAPS / 64), 256, 0, stream>>>(
            nullptr, f_hid, sW2 + 524288, sb2 + 512, ms, nullptr, nullptr, nullptr, nullptr, CAPS, 1024, 512, 0, 0, nullptr);
    }

  // ---- routed experts (MFMA, gathered, grid.z=8, PER-EXPERT hid regions) ----
  for (int c = 0; c < NCH; ++c) {
    mfma_gemm<2,1,2,1><<<dim3(16, CAPE / 64, 8), 256, 0, stream>>>(
        f_h2, nullptr, eW1, eb1, nullptr, f_hid, toklist, nullptr, cnt,
        CAPE, 512, 1024, c * CAPE, HIDSTRIDE, nullptr);
    mfma_gemm<1,0,3,1><<<dim3(8, CAPE / 64, 8), 256, 0, stream>>>(
        nullptr, f_hid, eW2, eb2, nullptr, nullptr, toklist, f_wlist, cnt,
        CAPE, 1024, 512, c * CAPE, HIDSTRIDE, f_moe);
  }

  // ---- final LN -> out (h3 f32), halt head (MFMA), scalars ----
  k_ln_res<<<TT, 256, 0, stream>>>(f_h2, f_moe, n3g, n3b, out);
  mfma_gemm<0,2,2,0><<<dim3(4, 128), 256, 0, stream>>>(
      out, nullptr, hW1, hb1, nullptr, f_hh, nullptr, nullptr, nullptr, TT, 512, 256, 0, 0, nullptr);
  k_halt<<<TT / 4, 256, 0, stream>>>(f_hh, hW2, hb2, out);
  k_final<<<1, 256, 0, stream>>>(f_probs, cnt, lA, out);
}

// Round 3
// 883.222 us; speedup vs baseline: 1.1732x; 1.0718x over previous
//
#include <hip/hip_runtime.h>
#include <hip/hip_bf16.h>

// Problem constants (B=8, N=1024, D=512, H=8, HD=64, E=4096, NE=8, NSH=2, TOPK=2, DH=1024)
// ALL inputs/outputs are float32.
#define TT 8192
#define DD 512

typedef unsigned short u16;
typedef __attribute__((ext_vector_type(8))) short short8;
typedef __attribute__((ext_vector_type(4))) float f32x4;

__device__ __forceinline__ u16 f2b(float f) {
  union { float f; unsigned int i; } w; w.f = f;
  unsigned int x = w.i;
  unsigned int r = (x + 0x7FFFu + ((x >> 16) & 1u)) >> 16;
  if ((x & 0x7F800000u) == 0x7F800000u) r = x >> 16;
  return (u16)r;
}
__device__ __forceinline__ float b2f(u16 u) {
  union { unsigned int i; float f; } w; w.i = ((unsigned int)u) << 16; return w.f;
}

__device__ __forceinline__ void blockReduce2(float& a, float& b, float* s4a, float* s4b) {
  #pragma unroll
  for (int off = 32; off; off >>= 1) { a += __shfl_xor(a, off); b += __shfl_xor(b, off); }
  int wid = threadIdx.x >> 6;
  if ((threadIdx.x & 63) == 0) { s4a[wid] = a; s4b[wid] = b; }
  __syncthreads();
  a = s4a[0] + s4a[1] + s4a[2] + s4a[3];
  b = s4b[0] + s4b[1] + s4b[2] + s4b[3];
}

// ---- zero esum ----
__global__ __launch_bounds__(256) void k_zero(float* __restrict__ esum) {
  esum[blockIdx.x * 256 + threadIdx.x] = 0.f;
}

// ---- edge sum: [B,E,D] -> [B,D] ----
__global__ __launch_bounds__(256) void k_esum(const float* __restrict__ ef, float* __restrict__ esum) {
  int b = blockIdx.x, ec = blockIdx.y, tid = threadIdx.x;
  float a0 = 0.f, a1 = 0.f;
  const float* base = ef + ((size_t)b * 4096 + (size_t)ec * 128) * 512;
  for (int e = 0; e < 128; ++e) {
    a0 += base[(size_t)e * 512 + tid];
    a1 += base[(size_t)e * 512 + tid + 256];
  }
  atomicAdd(&esum[b * 512 + tid], a0);
  atomicAdd(&esum[b * 512 + tid + 256], a1);
}

// ---- einj[b,dp] = (esum[b,:]/E) @ B_w[:,dp] + B_b[dp] ----
__global__ __launch_bounds__(256) void k_einj(const float* __restrict__ esum,
                                              const float* __restrict__ Bw, const float* __restrict__ Bb,
                                              float* __restrict__ einj) {
  int idx = blockIdx.x * 256 + threadIdx.x;
  int b = idx >> 9, dp = idx & 511;
  float a = Bb[dp];
  const float inv = 1.f / 4096.f;
  for (int d = 0; d < 512; ++d)
    a = fmaf(esum[b * 512 + d] * inv, Bw[d * 512 + dp], a);
  einj[idx] = a;
}

// ---- weight transpose + hi/lo bf16 split: W[512][512] -> Wt{h,l}[z][n][k] ----
__global__ __launch_bounds__(256) void k_wsplit(const float* __restrict__ Wq, const float* __restrict__ Wk,
                                                const float* __restrict__ Wv, const float* __restrict__ Wo,
                                                u16* __restrict__ outh, u16* __restrict__ outl) {
  __shared__ float st[64][65];
  int z = blockIdx.z;
  const float* W = z == 0 ? Wq : (z == 1 ? Wk : (z == 2 ? Wv : Wo));
  int k0 = blockIdx.x << 6, n0 = blockIdx.y << 6;
  int tid = threadIdx.x;
  int r = tid >> 2, c4 = (tid & 3) << 4;
  #pragma unroll
  for (int j = 0; j < 16; j += 4) {
    float4 v = *(const float4*)(W + (size_t)(k0 + r) * 512 + n0 + c4 + j);
    st[c4 + j + 0][r] = v.x; st[c4 + j + 1][r] = v.y;
    st[c4 + j + 2][r] = v.z; st[c4 + j + 3][r] = v.w;
  }
  __syncthreads();
  int n = tid >> 2, kb = (tid & 3) << 4;
  u16 h8[8] __attribute__((aligned(16)));
  u16 l8[8] __attribute__((aligned(16)));
  size_t obase = (size_t)z * 262144 + (size_t)(n0 + n) * 512 + k0 + kb;
  #pragma unroll
  for (int half = 0; half < 2; ++half) {
    #pragma unroll
    for (int j = 0; j < 8; ++j) {
      float val = st[n][kb + half * 8 + j];
      h8[j] = f2b(val);
      l8[j] = f2b(val - b2f(h8[j]));
    }
    *(uint4*)(outh + obase + half * 8) = *(uint4*)h8;
    *(uint4*)(outl + obase + half * 8) = *(uint4*)l8;
  }
}

// ---- h_lti = LN(-exp(log_A)*h + einj) -> hi/lo bf16 (segment-local) ----
__global__ __launch_bounds__(256) void k_lti(const float* __restrict__ h, const float* __restrict__ lA,
                                             const float* __restrict__ einj,
                                             const float* __restrict__ g, const float* __restrict__ be,
                                             u16* __restrict__ Xh, u16* __restrict__ Xl, int seg0) {
  __shared__ float sa[4], sb[4];
  int rowg = seg0 + blockIdx.x, b = rowg >> 10, tid = threadIdx.x;
  int d0 = tid, d1 = tid + 256;
  size_t gbase = (size_t)rowg * 512;
  size_t lbase = (size_t)blockIdx.x * 512;
  float v0 = -expf(lA[d0]) * h[gbase + d0] + einj[b * 512 + d0];
  float v1 = -expf(lA[d1]) * h[gbase + d1] + einj[b * 512 + d1];
  float s = v0 + v1, ss = v0 * v0 + v1 * v1;
  blockReduce2(s, ss, sa, sb);
  float mu = s * (1.f / 512.f);
  float var = fmaxf(ss * (1.f / 512.f) - mu * mu, 0.f);
  float r = rsqrtf(var + 1e-5f);
  float o0 = (v0 - mu) * r * g[d0] + be[d0];
  float o1 = (v1 - mu) * r * g[d1] + be[d1];
  u16 h0 = f2b(o0), h1 = f2b(o1);
  Xh[lbase + d0] = h0; Xl[lbase + d0] = f2b(o0 - b2f(h0));
  Xh[lbase + d1] = h1; Xl[lbase + d1] = f2b(o1 - b2f(h1));
}

// ---- residual LN: LN(recon(Xh,Xl) + Bv) -> f32 ----
__global__ __launch_bounds__(256) void k_ln_res2(const u16* __restrict__ Xh, const u16* __restrict__ Xl,
                                                 const float* __restrict__ Bv,
                                                 const float* __restrict__ g, const float* __restrict__ be,
                                                 float* __restrict__ outf) {
  __shared__ float sa[4], sb[4];
  int tid = threadIdx.x, d0 = tid, d1 = tid + 256;
  size_t base = (size_t)blockIdx.x * 512;
  float v0 = b2f(Xh[base + d0]) + b2f(Xl[base + d0]) + Bv[base + d0];
  float v1 = b2f(Xh[base + d1]) + b2f(Xl[base + d1]) + Bv[base + d1];
  float s = v0 + v1, ss = v0 * v0 + v1 * v1;
  blockReduce2(s, ss, sa, sb);
  float mu = s * (1.f / 512.f);
  float var = fmaxf(ss * (1.f / 512.f) - mu * mu, 0.f);
  float r = rsqrtf(var + 1e-5f);
  outf[base + d0] = (v0 - mu) * r * g[d0] + be[d0];
  outf[base + d1] = (v1 - mu) * r * g[d1] + be[d1];
}

// ---- residual LN (both f32) ----
__global__ __launch_bounds__(256) void k_ln_res(const float* __restrict__ A, const float* __restrict__ Bv,
                                                const float* __restrict__ g, const float* __restrict__ be,
                                                float* __restrict__ outf) {
  __shared__ float sa[4], sb[4];
  int tid = threadIdx.x, d0 = tid, d1 = tid + 256;
  size_t base = (size_t)blockIdx.x * 512;
  float v0 = A[base + d0] + Bv[base + d0];
  float v1 = A[base + d1] + Bv[base + d1];
  float s = v0 + v1, ss = v0 * v0 + v1 * v1;
  blockReduce2(s, ss, sa, sb);
  float mu = s * (1.f / 512.f);
  float var = fmaxf(ss * (1.f / 512.f) - mu * mu, 0.f);
  float r = rsqrtf(var + 1e-5f);
  outf[base + d0] = (v0 - mu) * r * g[d0] + be[d0];
  outf[base + d1] = (v1 - mu) * r * g[d1] + be[d1];
}

// ---- split-precision MFMA GEMM v2: pre-split bf16 inputs, 128x128 tile ----
// C = X@W + b ~= Xh.Wh + Xl.Wh + Xh.Wl (3 MFMAs, f32 accumulate, rel err ~2^-17).
// 4 waves, each owns a 64x64 sub-tile (4x4 frags of 16x16x32). K=N=512 fixed.
// lda = X row stride in u16 (512 for packed planes, 1024 for per-row hi|lo).
// NOUT=3: blockIdx.z selects {q,k,v} weight region/out; NOUT=1: single.
template<int NOUT>
__global__ __launch_bounds__(256) void gemm_sp2(
    const u16* __restrict__ Xh, const u16* __restrict__ Xl, int lda,
    const u16* __restrict__ Wth, const u16* __restrict__ Wtl,
    const float* __restrict__ b0c, const float* __restrict__ b1c, const float* __restrict__ b2c,
    float* __restrict__ C0, float* __restrict__ C1, float* __restrict__ C2) {
  const float* bias = b0c; float* C = C0;
  const u16* Wh = Wth; const u16* Wl = Wtl;
  if (NOUT == 3) {
    int z = blockIdx.z;
    Wh += (size_t)z * 262144; Wl += (size_t)z * 262144;
    if (z == 1) { bias = b1c; C = C1; }
    else if (z == 2) { bias = b2c; C = C2; }
  }
  const int bm = blockIdx.y << 7, bn = blockIdx.x << 7;
  __shared__ u16 Ah[128][40];
  __shared__ u16 Al[128][40];
  __shared__ u16 Bh[128][40];
  __shared__ u16 Bl[128][40];
  const int tid = threadIdx.x;
  const int sr = tid >> 1, sk = (tid & 1) << 4;   // staging: row 0..127, k 0/16
  const int wv = tid >> 6, lane = tid & 63, q = lane >> 4, m16 = lane & 15;
  const int wr = (wv >> 1) << 6, wc = (wv & 1) << 6;
  f32x4 acc[4][4];
  #pragma unroll
  for (int m = 0; m < 4; ++m)
    #pragma unroll
    for (int n = 0; n < 4; ++n)
      #pragma unroll
      for (int i = 0; i < 4; ++i) acc[m][n][i] = 0.f;

  for (int k0 = 0; k0 < 512; k0 += 32) {
    __syncthreads();
    const size_t ao_ = (size_t)(bm + sr) * lda + k0 + sk;
    const size_t bo_ = (size_t)(bn + sr) * 512 + k0 + sk;
    *(uint4*)&Ah[sr][sk]     = *(const uint4*)(Xh + ao_);
    *(uint4*)&Ah[sr][sk + 8] = *(const uint4*)(Xh + ao_ + 8);
    *(uint4*)&Al[sr][sk]     = *(const uint4*)(Xl + ao_);
    *(uint4*)&Al[sr][sk + 8] = *(const uint4*)(Xl + ao_ + 8);
    *(uint4*)&Bh[sr][sk]     = *(const uint4*)(Wh + bo_);
    *(uint4*)&Bh[sr][sk + 8] = *(const uint4*)(Wh + bo_ + 8);
    *(uint4*)&Bl[sr][sk]     = *(const uint4*)(Wl + bo_);
    *(uint4*)&Bl[sr][sk + 8] = *(const uint4*)(Wl + bo_ + 8);
    __syncthreads();
    short8 ah[4], al[4];
    #pragma unroll
    for (int m = 0; m < 4; ++m) {
      ah[m] = *(const short8*)&Ah[wr + m * 16 + m16][q * 8];
      al[m] = *(const short8*)&Al[wr + m * 16 + m16][q * 8];
    }
    #pragma unroll
    for (int n = 0; n < 4; ++n) {
      short8 bh = *(const short8*)&Bh[wc + n * 16 + m16][q * 8];
      short8 bl = *(const short8*)&Bl[wc + n * 16 + m16][q * 8];
      #pragma unroll
      for (int m = 0; m < 4; ++m) {
        acc[m][n] = __builtin_amdgcn_mfma_f32_16x16x32_bf16(ah[m], bh, acc[m][n], 0, 0, 0);
        acc[m][n] = __builtin_amdgcn_mfma_f32_16x16x32_bf16(al[m], bh, acc[m][n], 0, 0, 0);
        acc[m][n] = __builtin_amdgcn_mfma_f32_16x16x32_bf16(ah[m], bl, acc[m][n], 0, 0, 0);
      }
    }
  }
  // epilogue: frag (m,n): D[row=q*4+i][col=m16] at tile offset (wr+m*16, wc+n*16)
  #pragma unroll
  for (int n = 0; n < 4; ++n) {
    int col = bn + wc + n * 16 + m16;
    float bb = bias[col];
    #pragma unroll
    for (int m = 0; m < 4; ++m) {
      #pragma unroll
      for (int i = 0; i < 4; ++i) {
        int rl = bm + wr + m * 16 + q * 4 + i;
        C[(size_t)rl * 512 + col] = acc[m][n][i] + bb;
      }
    }
  }
}

// ---- per-node head attention -> per-row packed [hi(512)|lo(512)] u16, IN PLACE over q row t ----
// Block t only writes its own q-row footprint (2 KB) => race-free (round-1 aliasing discipline).
__global__ __launch_bounds__(64) void k_attn(const float* __restrict__ q, const float* __restrict__ k,
                                             const float* __restrict__ v,
                                             u16* __restrict__ aohl) {
  __shared__ float qs[512], ks[512], vs[512], at[64];
  size_t t = blockIdx.x;
  int lane = threadIdx.x;
  for (int i = lane; i < 512; i += 64) {
    qs[i] = q[t * 512 + i]; ks[i] = k[t * 512 + i]; vs[i] = v[t * 512 + i];
  }
  __syncthreads();
  int h = lane >> 3, g = lane & 7;
  float s = 0.f;
  #pragma unroll 8
  for (int d = 0; d < 64; ++d) s = fmaf(qs[h * 64 + d], ks[g * 64 + d], s);
  s *= 0.125f;
  float m = s;
  #pragma unroll
  for (int off = 1; off < 8; off <<= 1) m = fmaxf(m, __shfl_xor(m, off));
  float ex = expf(s - m);
  float sum = ex;
  #pragma unroll
  for (int off = 1; off < 8; off <<= 1) sum += __shfl_xor(sum, off);
  at[lane] = ex / sum;
  __syncthreads();
  #pragma unroll
  for (int j = 0; j < 8; ++j) {
    int d = lane + j * 64, hh = d >> 6, hd = d & 63;
    float acc = 0.f;
    #pragma unroll
    for (int gg = 0; gg < 8; ++gg) acc = fmaf(at[hh * 8 + gg], vs[gg * 64 + hd], acc);
    u16 hi = f2b(acc);
    aohl[t * 1024 + d] = hi;
    aohl[t * 1024 + 512 + d] = f2b(acc - b2f(hi));
  }
}

// ---- gate phase A: probs + top2 per token, NO atomics ----
__global__ __launch_bounds__(256) void k_gateA(const float* __restrict__ h2, const float* __restrict__ gw,
                                               const float* __restrict__ gb, float* __restrict__ probs,
                                               int* __restrict__ sel, float2* __restrict__ wpair) {
  int lane = threadIdx.x & 63, wid = threadIdx.x >> 6;
  int t = blockIdx.x * 4 + wid;
  const float* x = h2 + (size_t)t * 512;
  float acc[8] = {};
  for (int d = lane; d < 512; d += 64) {
    float xv = x[d];
    float4 g0 = *(const float4*)(gw + d * 8);
    float4 g1 = *(const float4*)(gw + d * 8 + 4);
    acc[0] = fmaf(xv, g0.x, acc[0]); acc[1] = fmaf(xv, g0.y, acc[1]);
    acc[2] = fmaf(xv, g0.z, acc[2]); acc[3] = fmaf(xv, g0.w, acc[3]);
    acc[4] = fmaf(xv, g1.x, acc[4]); acc[5] = fmaf(xv, g1.y, acc[5]);
    acc[6] = fmaf(xv, g1.z, acc[6]); acc[7] = fmaf(xv, g1.w, acc[7]);
  }
  #pragma unroll
  for (int off = 32; off; off >>= 1)
    #pragma unroll
    for (int e = 0; e < 8; ++e) acc[e] += __shfl_xor(acc[e], off);
  if (lane == 0) {
    float m = -1e30f;
    #pragma unroll
    for (int e = 0; e < 8; ++e) { acc[e] += gb[e]; m = fmaxf(m, acc[e]); }
    float p[8], sum = 0.f;
    #pragma unroll
    for (int e = 0; e < 8; ++e) { p[e] = expf(acc[e] - m); sum += p[e]; }
    float inv = 1.f / sum;
    #pragma unroll
    for (int e = 0; e < 8; ++e) { p[e] *= inv; probs[t * 8 + e] = p[e]; }
    int i1 = 0; float m1 = p[0];
    #pragma unroll
    for (int e = 1; e < 8; ++e) if (p[e] > m1) { m1 = p[e]; i1 = e; }
    int i2 = -1; float m2 = -1.f;
    #pragma unroll
    for (int e = 0; e < 8; ++e) if (e != i1 && p[e] > m2) { m2 = p[e]; i2 = e; }
    if (i2 < 0) i2 = (i1 + 1) & 7;
    float den = m1 + m2;
    float invs = (den > 0.f) ? 1.f / den : 0.f;
    sel[t] = i1 | (i2 << 4);
    wpair[t] = make_float2(m1 * invs, m2 * invs);
  }
}

// ---- gate phase B: per-expert compaction via ballot prefix scan (8 blocks) ----
__global__ __launch_bounds__(256) void k_gateB(const int* __restrict__ sel, const float2* __restrict__ wpair,
                                               int* __restrict__ toklist, float* __restrict__ wlist,
                                               int* __restrict__ cnt) {
  int e = blockIdx.x;
  int tid = threadIdx.x, lane = tid & 63, wv = tid >> 6;
  __shared__ int wsum[4];
  int base = 0;
  for (int t0 = 0; t0 < 8192; t0 += 256) {
    int t = t0 + tid;
    int s = sel[t];
    int i1 = s & 15, i2 = (s >> 4) & 15;
    bool f = (i1 == e) || (i2 == e);
    float wt = (i1 == e) ? wpair[t].x : ((i2 == e) ? wpair[t].y : 0.f);
    unsigned long long m = __ballot(f);
    int rank = __popcll(m & ((1ull << lane) - 1ull));
    int wtot = __popcll(m);
    if (lane == 0) wsum[wv] = wtot;
    __syncthreads();
    int prev = 0;
    for (int ww = 0; ww < wv; ++ww) prev += wsum[ww];
    int tot = wsum[0] + wsum[1] + wsum[2] + wsum[3];
    if (f) {
      int pos = base + prev + rank;
      toklist[e * 8192 + pos] = t;
      wlist[e * 8192 + pos] = wt;
    }
    base += tot;
    __syncthreads();
  }
  if (tid == 0) cnt[e] = base;
}

// ---- MFMA bf16 GEMM: 64x64 tile, BK=32, 4 waves, 16x16x32 frags ----
// XMODE: 0 dense f32, 1 dense bf16, 2 gathered f32 rows (toklist)
// ACT: 0 none, 1 silu, 2 tanh
// OUTMODE: 0 f32 store, 1 f32 +=, 2 bf16 store, 3 weighted scatter-atomicAdd (expertB)
// EXPERT: blockIdx.z = expert; W/bias strided; rows bounded by cnt[e]-chunk0;
//         Xb/C16 offset by e*hidstride (PER-EXPERT hid regions)
template<int XMODE, int ACT, int OUTMODE, int EXPERT>
__global__ __launch_bounds__(256) void mfma_gemm(
    const float* __restrict__ Xf, const u16* __restrict__ Xb,
    const float* __restrict__ Wg, const float* __restrict__ biasg,
    float* __restrict__ C, u16* __restrict__ C16,
    const int* __restrict__ toklist, const float* __restrict__ wlist,
    const int* __restrict__ cnt, int M, int K, int N, int chunk0,
    size_t hidstride, float* __restrict__ moe) {
  int e = EXPERT ? blockIdx.z : 0;
  const float* W = Wg + (size_t)e * K * N;
  const float* bias = biasg + (size_t)e * N;
  int Mloc = M;
  if (EXPERT) {
    int ce = cnt[e]; if (ce > 8192) ce = 8192;
    Mloc = ce - chunk0;
    if (XMODE == 1) Xb += (size_t)e * hidstride;     // per-expert hid region
    if (OUTMODE == 2) C16 += (size_t)e * hidstride;  // per-expert hid region
  }
  const int bm = blockIdx.y << 6, bn = blockIdx.x << 6;
  if (EXPERT && bm >= Mloc) return;
  __shared__ u16 As[64][40];
  __shared__ u16 Bs[64][40];
  __shared__ int rows[64];
  const int tid = threadIdx.x;
  if (EXPERT && XMODE == 2 && tid < 64) {
    int ce = cnt[e]; if (ce > 8192) ce = 8192;
    int r = chunk0 + bm + tid;
    rows[tid] = toklist[e * 8192 + (r < ce ? r : chunk0)] & 8191;
  }
  const int srow = tid >> 2;          // 0..63
  const int skg = (tid & 3) << 3;     // 0,8,16,24
  const int wv = tid >> 6, lane = tid & 63, q = lane >> 4, m16 = lane & 15;
  f32x4 acc[4];
  #pragma unroll
  for (int c = 0; c < 4; ++c)
    #pragma unroll
    for (int i = 0; i < 4; ++i) acc[c][i] = 0.f;

  for (int k0 = 0; k0 < K; k0 += 32) {
    __syncthreads();
    // stage A tile (64 rows x 32 k) as bf16
    {
      u16 a8[8] __attribute__((aligned(16)));
      if (XMODE == 1) {
        *(uint4*)a8 = *(const uint4*)(Xb + (size_t)(bm + srow) * K + k0 + skg);
      } else {
        const float* src = (XMODE == 2) ? (Xf + (size_t)rows[srow] * K + k0 + skg)
                                        : (Xf + (size_t)(bm + srow) * K + k0 + skg);
        float4 x0 = *(const float4*)(src);
        float4 x1 = *(const float4*)(src + 4);
        a8[0] = f2b(x0.x); a8[1] = f2b(x0.y); a8[2] = f2b(x0.z); a8[3] = f2b(x0.w);
        a8[4] = f2b(x1.x); a8[5] = f2b(x1.y); a8[6] = f2b(x1.z); a8[7] = f2b(x1.w);
      }
      *(uint4*)&As[srow][skg] = *(uint4*)a8;
    }
    // stage B tile transposed: Bs[n][k] = W[k0+k][bn+n]
    {
      u16 b8[8] __attribute__((aligned(16)));
      const float* src = W + (size_t)(k0 + skg) * N + bn + srow;
      #pragma unroll
      for (int j = 0; j < 8; ++j) b8[j] = f2b(src[(size_t)j * N]);
      *(uint4*)&Bs[srow][skg] = *(uint4*)b8;
    }
    __syncthreads();
    short8 af = *(const short8*)&As[wv * 16 + m16][q * 8];
    #pragma unroll
    for (int c = 0; c < 4; ++c) {
      short8 bf = *(const short8*)&Bs[c * 16 + m16][q * 8];
      acc[c] = __builtin_amdgcn_mfma_f32_16x16x32_bf16(af, bf, acc[c], 0, 0, 0);
    }
  }
  // epilogue: lane holds D[row=q*4+i][col=c*16+m16], wave rows base wv*16
  #pragma unroll
  for (int c = 0; c < 4; ++c) {
    int col = bn + c * 16 + m16;
    float bb = bias[col];
    #pragma unroll
    for (int i = 0; i < 4; ++i) {
      int rl = bm + wv * 16 + q * 4 + i;
      if (EXPERT && rl >= Mloc) continue;
      float v = acc[c][i] + bb;
      if (ACT == 1) v = v / (1.f + expf(-v));
      else if (ACT == 2) v = tanhf(v);
      if (OUTMODE == 0) C[(size_t)rl * N + col] = v;
      else if (OUTMODE == 1) C[(size_t)rl * N + col] += v;
      else if (OUTMODE == 2) C16[(size_t)rl * N + col] = f2b(v);
      else {  // weighted scatter into moe
        int rg = chunk0 + rl;
        int tok = toklist[e * 8192 + rg] & 8191;
        float wt = wlist[e * 8192 + rg];
        atomicAdd(&moe[(size_t)tok * 512 + col], v * wt);
      }
    }
  }
}

// ---- halt head ----
__global__ __launch_bounds__(256) void k_halt(const u16* __restrict__ hh, const float* __restrict__ hW2,
                                              const float* __restrict__ hb2, float* __restrict__ out) {
  int lane = threadIdx.x & 63, wid = threadIdx.x >> 6;
  int t = blockIdx.x * 4 + wid;
  const u16* x = hh + (size_t)t * 256;
  float a = b2f(x[lane]) * hW2[lane] + b2f(x[lane + 64]) * hW2[lane + 64] +
            b2f(x[lane + 128]) * hW2[lane + 128] + b2f(x[lane + 192]) * hW2[lane + 192];
  #pragma unroll
  for (int off = 32; off; off >>= 1) a += __shfl_xor(a, off);
  if (lane == 0) {
    float p = 1.f / (1.f + expf(-(a + hb2[0])));
    out[4194304 + t] = p;
    out[4194304 + 8192 + t] = p;
  }
}

// ---- scalar: stab + aux loss ----
__global__ __launch_bounds__(256) void k_final(const float* __restrict__ probs, const int* __restrict__ cnt,
                                               const float* __restrict__ lA, float* __restrict__ out) {
  __shared__ float sp[4][8];
  __shared__ float sm[4];
  int tid = threadIdx.x, lane = tid & 63, wid = tid >> 6;
  float part[8] = {};
  for (int i = tid; i < 8192; i += 256) {
    const float* p = probs + i * 8;
    #pragma unroll
    for (int e = 0; e < 8; ++e) part[e] += p[e];
  }
  #pragma unroll
  for (int off = 32; off; off >>= 1)
    #pragma unroll
    for (int e = 0; e < 8; ++e) part[e] += __shfl_xor(part[e], off);
  float mx = 0.f;
  for (int d = tid; d < 512; d += 256) mx = fmaxf(mx, expf(lA[d]));
  #pragma unroll
  for (int off = 32; off; off >>= 1) mx = fmaxf(mx, __shfl_xor(mx, off));
  if (lane == 0) {
    #pragma unroll
    for (int e = 0; e < 8; ++e) sp[wid][e] = part[e];
    sm[wid] = mx;
  }
  __syncthreads();
  if (tid == 0) {
    float loss = 0.f;
    for (int e = 0; e < 8; ++e) {
      float pm = (sp[0][e] + sp[1][e] + sp[2][e] + sp[3][e]) * (1.f / 8192.f);
      int c = cnt[e]; if (c > 8192) c = 8192;
      loss += (float)c * (1.f / 8192.f) * pm;
    }
    loss *= 0.01f * 8.f;
    float mall = fmaxf(fmaxf(sm[0], sm[1]), fmaxf(sm[2], sm[3]));
    out[4194304 + 16384] = fmaxf(mall - 0.95f, 0.f) + loss;
  }
}

extern "C" void kernel_launch(void* const* d_in, const int* in_sizes, int n_in,
                              void* d_out, int out_size, void* d_ws, size_t ws_size,
                              hipStream_t stream) {
  const float* h   = (const float*)d_in[0];
  const float* ef  = (const float*)d_in[1];
  const float* lA  = (const float*)d_in[2];
  const float* Bw  = (const float*)d_in[3];
  const float* Bb  = (const float*)d_in[4];
  const float* Wq  = (const float*)d_in[5];  const float* bq  = (const float*)d_in[6];
  const float* Wk  = (const float*)d_in[7];  const float* bk  = (const float*)d_in[8];
  const float* Wv  = (const float*)d_in[9];  const float* bv  = (const float*)d_in[10];
  const float* Wo  = (const float*)d_in[11]; const float* bo  = (const float*)d_in[12];
  const float* n1g = (const float*)d_in[13]; const float* n1b = (const float*)d_in[14];
  const float* n2g = (const float*)d_in[15]; const float* n2b = (const float*)d_in[16];
  const float* n3g = (const float*)d_in[17]; const float* n3b = (const float*)d_in[18];
  const float* gw  = (const float*)d_in[19]; const float* gb  = (const float*)d_in[20];
  const float* eW1 = (const float*)d_in[21]; const float* eb1 = (const float*)d_in[22];
  const float* eW2 = (const float*)d_in[23]; const float* eb2 = (const float*)d_in[24];
  const float* sW1 = (const float*)d_in[25]; const float* sb1 = (const float*)d_in[26];
  const float* sW2 = (const float*)d_in[27]; const float* sb2 = (const float*)d_in[28];
  const float* hW1 = (const float*)d_in[29]; const float* hb1 = (const float*)d_in[30];
  const float* hW2 = (const float*)d_in[31]; const float* hb2 = (const float*)d_in[32];
  float* out = (float*)d_out;
  float* ws = (float*)d_ws;

  // ---- tiered workspace layout (runtime-sized) ----
  // [0,R) h2 | [R,2R) moe (also holds split QKV/Wo weights until expert phase)
  // [2R,2R+ARENA) arena | small scratch
  // arena per segment: Xh/Xl (SD floats) | q (SD) | k (SD) | v (SD)
  //   ao hi|lo packs per-row in place over q; hp aliases k.
  const size_t R = (size_t)TT * DD;   // 4,194,304 floats
  const size_t SM = 155648 + 73744;   // floats + ints
  size_t wsf = ws_size / 4;
  int S; size_t ARENA;
  if (wsf >= 6 * R + SM)      { S = 8192; ARENA = 4 * R; }
  else if (wsf >= 3 * R + SM) { S = 2048; ARENA = R; }
  else                        { S = 512;  ARENA = 1048576; }
  const int CAPE = (int)(ARENA / 4096);          // 4096 / 1024 / 256
  const int NCH  = 8192 / CAPE;
  const size_t HIDSTRIDE = (size_t)CAPE * 1024;
  const int CAPS = (ARENA / 512 >= 8192) ? 8192 : (int)(ARENA / 512);

  float* f_h2  = ws;
  float* f_moe = ws + R;
  float* arena = ws + 2 * R;
  const size_t SD = (size_t)S * 512;
  u16* f_xh = (u16*)arena;             // SD u16
  u16* f_xl = f_xh + SD;               // SD u16  (total SD floats)
  float* f_q = arena + SD;
  float* f_k = arena + 2 * SD;
  float* f_v = arena + 3 * SD;
  u16* f_aohl = (u16*)f_q;             // per-row [hi|lo] packed, in place over q rows
  float* f_hp = f_k;                   // alias k after Wo GEMM input consumed
  u16* f_wh = (u16*)f_moe;             // [4][512][512] split weights (hi)
  u16* f_wl = f_wh + 4 * 262144;       // (lo) — together 2.1M u16 < R floats
  u16* f_hid = (u16*)arena;
  u16* f_hh  = (u16*)arena;
  float* smr = ws + 2 * R + ARENA;
  float* f_esum = smr;
  float* f_einj = smr + 4096;
  float* f_probs = smr + 8192;
  float2* f_wpair = (float2*)(smr + 8192 + 65536);
  float* f_wlist = smr + 8192 + 65536 + 16384;
  int* ip = (int*)(smr + 8192 + 65536 + 16384 + 65536);
  int* sel = ip; int* cnt = ip + 8192; int* toklist = ip + 8192 + 16;

  // ---- LTI prep + weight split ----
  k_zero<<<16, 256, 0, stream>>>(f_esum);
  k_esum<<<dim3(8, 32), 256, 0, stream>>>(ef, f_esum);
  k_einj<<<16, 256, 0, stream>>>(f_esum, Bw, Bb, f_einj);
  k_wsplit<<<dim3(8, 8, 4), 256, 0, stream>>>(Wq, Wk, Wv, Wo, f_wh, f_wl);

  // ---- LTI + attention (split-precision MFMA on pre-split bf16) ----
  for (int s = 0; s < TT / S; ++s) {
    int seg0 = s * S;
    k_lti<<<S, 256, 0, stream>>>(h, lA, f_einj, n1g, n1b, f_xh, f_xl, seg0);
    gemm_sp2<3><<<dim3(4, S / 128, 3), 256, 0, stream>>>(
        f_xh, f_xl, 512, f_wh, f_wl, bq, bk, bv, f_q, f_k, f_v);
    k_attn<<<S, 64, 0, stream>>>(f_q, f_k, f_v, f_aohl);
    gemm_sp2<1><<<dim3(4, S / 128, 1), 256, 0, stream>>>(
        f_aohl, f_aohl + 512, 1024, f_wh + 3 * 262144, f_wl + 3 * 262144,
        bo, nullptr, nullptr, f_hp, nullptr, nullptr);
    k_ln_res2<<<S, 256, 0, stream>>>(f_xh, f_xl, f_hp, n2g, n2b, f_h2 + (size_t)seg0 * 512);
  }

  // ---- gate: two-phase, no contended atomics ----
  k_gateA<<<TT / 4, 256, 0, stream>>>(f_h2, gw, gb, f_probs, sel, f_wpair);
  k_gateB<<<8, 256, 0, stream>>>(sel, f_wpair, toklist, f_wlist, cnt);

  // ---- shared experts (MFMA), chunked by CAPS ----
  for (int sx = 0; sx < 2; ++sx)
    for (int c = 0; c < TT / CAPS; ++c) {
      const float* xs = f_h2 + (size_t)c * CAPS * 512;
      float* ms = f_moe + (size_t)c * CAPS * 512;
      mfma_gemm<0,1,2,0><<<dim3(16, CAPS / 64), 256, 0, stream>>>(
          xs, nullptr, sW1 + (size_t)sx * 524288, sb1 + sx * 1024,
          nullptr, f_hid, nullptr, nullptr, nullptr, CAPS, 512, 1024, 0, 0, nullptr);
      if (sx == 0)
        mfma_gemm<1,0,0,0><<<dim3(8, CAPS / 64), 256, 0, stream>>>(
            nullptr, f_hid, sW2, sb2, ms, nullptr, nullptr, nullptr, nullptr, CAPS, 1024, 512, 0, 0, nullptr);
      else
        mfma_gemm<1,0,1,0><<<dim3(8, CAPS / 64), 256, 0, stream>>>(
            nullptr, f_hid, sW2 + 524288, sb2 + 512, ms, nullptr, nullptr, nullptr, nullptr, CAPS, 1024, 512, 0, 0, nullptr);
    }

  // ---- routed experts (MFMA, gathered, grid.z=8, PER-EXPERT hid regions) ----
  for (int c = 0; c < NCH; ++c) {
    mfma_gemm<2,1,2,1><<<dim3(16, CAPE / 64, 8), 256, 0, stream>>>(
        f_h2, nullptr, eW1, eb1, nullptr, f_hid, toklist, nullptr, cnt,
        CAPE, 512, 1024, c * CAPE, HIDSTRIDE, nullptr);
    mfma_gemm<1,0,3,1><<<dim3(8, CAPE / 64, 8), 256, 0, stream>>>(
        nullptr, f_hid, eW2, eb2, nullptr, nullptr, toklist, f_wlist, cnt,
        CAPE, 1024, 512, c * CAPE, HIDSTRIDE, f_moe);
  }

  // ---- final LN -> out (h3 f32), halt head (MFMA), scalars ----
  k_ln_res<<<TT, 256, 0, stream>>>(f_h2, f_moe, n3g, n3b, out);
  mfma_gemm<0,2,2,0><<<dim3(4, 128), 256, 0, stream>>>(
      out, nullptr, hW1, hb1, nullptr, f_hh, nullptr, nullptr, nullptr, TT, 512, 256, 0, 0, nullptr);
  k_halt<<<TT / 4, 256, 0, stream>>>(f_hh, hW2, hb2, out);
  k_final<<<1, 256, 0, stream>>>(f_probs, cnt, lA, out);
}

// Round 4
// 875.795 us; speedup vs baseline: 1.1831x; 1.0085x over previous
//
#include <hip/hip_runtime.h>
#include <hip/hip_bf16.h>

// Problem constants (B=8, N=1024, D=512, H=8, HD=64, E=4096, NE=8, NSH=2, TOPK=2, DH=1024)
// ALL inputs/outputs are float32.
#define TT 8192
#define DD 512

typedef unsigned short u16;
typedef __attribute__((ext_vector_type(8))) short short8;
typedef __attribute__((ext_vector_type(4))) float f32x4;

__device__ __forceinline__ u16 f2b(float f) {
  union { float f; unsigned int i; } w; w.f = f;
  unsigned int x = w.i;
  unsigned int r = (x + 0x7FFFu + ((x >> 16) & 1u)) >> 16;
  if ((x & 0x7F800000u) == 0x7F800000u) r = x >> 16;
  return (u16)r;
}
__device__ __forceinline__ float b2f(u16 u) {
  union { unsigned int i; float f; } w; w.i = ((unsigned int)u) << 16; return w.f;
}

__device__ __forceinline__ void blockReduce2(float& a, float& b, float* s4a, float* s4b) {
  #pragma unroll
  for (int off = 32; off; off >>= 1) { a += __shfl_xor(a, off); b += __shfl_xor(b, off); }
  int wid = threadIdx.x >> 6;
  if ((threadIdx.x & 63) == 0) { s4a[wid] = a; s4b[wid] = b; }
  __syncthreads();
  a = s4a[0] + s4a[1] + s4a[2] + s4a[3];
  b = s4b[0] + s4b[1] + s4b[2] + s4b[3];
}

// ---- zero esum ----
__global__ __launch_bounds__(256) void k_zero(float* __restrict__ esum) {
  esum[blockIdx.x * 256 + threadIdx.x] = 0.f;
}

// ---- edge sum: [B,E,D] -> [B,D] ----
__global__ __launch_bounds__(256) void k_esum(const float* __restrict__ ef, float* __restrict__ esum) {
  int b = blockIdx.x, ec = blockIdx.y, tid = threadIdx.x;
  float a0 = 0.f, a1 = 0.f;
  const float* base = ef + ((size_t)b * 4096 + (size_t)ec * 128) * 512;
  for (int e = 0; e < 128; ++e) {
    a0 += base[(size_t)e * 512 + tid];
    a1 += base[(size_t)e * 512 + tid + 256];
  }
  atomicAdd(&esum[b * 512 + tid], a0);
  atomicAdd(&esum[b * 512 + tid + 256], a1);
}

// ---- einj[b,dp] = (esum[b,:]/E) @ B_w[:,dp] + B_b[dp] ----
__global__ __launch_bounds__(256) void k_einj(const float* __restrict__ esum,
                                              const float* __restrict__ Bw, const float* __restrict__ Bb,
                                              float* __restrict__ einj) {
  int idx = blockIdx.x * 256 + threadIdx.x;
  int b = idx >> 9, dp = idx & 511;
  float a = Bb[dp];
  const float inv = 1.f / 4096.f;
  for (int d = 0; d < 512; ++d)
    a = fmaf(esum[b * 512 + d] * inv, Bw[d * 512 + dp], a);
  einj[idx] = a;
}

// ---- weight transpose + hi/lo bf16 split: W[512][512] -> Wt{h,l}[z][n][k] ----
__global__ __launch_bounds__(256) void k_wsplit(const float* __restrict__ Wq, const float* __restrict__ Wk,
                                                const float* __restrict__ Wv, const float* __restrict__ Wo,
                                                u16* __restrict__ outh, u16* __restrict__ outl) {
  __shared__ float st[64][65];
  int z = blockIdx.z;
  const float* W = z == 0 ? Wq : (z == 1 ? Wk : (z == 2 ? Wv : Wo));
  int k0 = blockIdx.x << 6, n0 = blockIdx.y << 6;
  int tid = threadIdx.x;
  int r = tid >> 2, c4 = (tid & 3) << 4;
  #pragma unroll
  for (int j = 0; j < 16; j += 4) {
    float4 v = *(const float4*)(W + (size_t)(k0 + r) * 512 + n0 + c4 + j);
    st[c4 + j + 0][r] = v.x; st[c4 + j + 1][r] = v.y;
    st[c4 + j + 2][r] = v.z; st[c4 + j + 3][r] = v.w;
  }
  __syncthreads();
  int n = tid >> 2, kb = (tid & 3) << 4;
  u16 h8[8] __attribute__((aligned(16)));
  u16 l8[8] __attribute__((aligned(16)));
  size_t obase = (size_t)z * 262144 + (size_t)(n0 + n) * 512 + k0 + kb;
  #pragma unroll
  for (int half = 0; half < 2; ++half) {
    #pragma unroll
    for (int j = 0; j < 8; ++j) {
      float val = st[n][kb + half * 8 + j];
      h8[j] = f2b(val);
      l8[j] = f2b(val - b2f(h8[j]));
    }
    *(uint4*)(outh + obase + half * 8) = *(uint4*)h8;
    *(uint4*)(outl + obase + half * 8) = *(uint4*)l8;
  }
}

// ---- generic weight transpose -> bf16 [n][k] (per-expert via blockIdx.z) ----
__global__ __launch_bounds__(256) void k_wt(const float* __restrict__ W, u16* __restrict__ Wt,
                                            int K, int N) {
  __shared__ float st[64][65];
  int z = blockIdx.z;
  W += (size_t)z * K * N; Wt += (size_t)z * K * N;
  int k0 = blockIdx.x << 6, n0 = blockIdx.y << 6;
  int tid = threadIdx.x;
  int r = tid >> 2, c4 = (tid & 3) << 4;
  #pragma unroll
  for (int j = 0; j < 16; j += 4) {
    float4 v = *(const float4*)(W + (size_t)(k0 + r) * N + n0 + c4 + j);
    st[c4 + j + 0][r] = v.x; st[c4 + j + 1][r] = v.y;
    st[c4 + j + 2][r] = v.z; st[c4 + j + 3][r] = v.w;
  }
  __syncthreads();
  int n = tid >> 2, kb = (tid & 3) << 4;
  u16 h8[8] __attribute__((aligned(16)));
  size_t obase = (size_t)(n0 + n) * K + k0 + kb;
  #pragma unroll
  for (int half = 0; half < 2; ++half) {
    #pragma unroll
    for (int j = 0; j < 8; ++j) h8[j] = f2b(st[n][kb + half * 8 + j]);
    *(uint4*)(Wt + obase + half * 8) = *(uint4*)h8;
  }
}

// ---- h_lti = LN(-exp(log_A)*h + einj) -> hi/lo bf16 (segment-local) ----
__global__ __launch_bounds__(256) void k_lti(const float* __restrict__ h, const float* __restrict__ lA,
                                             const float* __restrict__ einj,
                                             const float* __restrict__ g, const float* __restrict__ be,
                                             u16* __restrict__ Xh, u16* __restrict__ Xl, int seg0) {
  __shared__ float sa[4], sb[4];
  int rowg = seg0 + blockIdx.x, b = rowg >> 10, tid = threadIdx.x;
  int d0 = tid, d1 = tid + 256;
  size_t gbase = (size_t)rowg * 512;
  size_t lbase = (size_t)blockIdx.x * 512;
  float v0 = -expf(lA[d0]) * h[gbase + d0] + einj[b * 512 + d0];
  float v1 = -expf(lA[d1]) * h[gbase + d1] + einj[b * 512 + d1];
  float s = v0 + v1, ss = v0 * v0 + v1 * v1;
  blockReduce2(s, ss, sa, sb);
  float mu = s * (1.f / 512.f);
  float var = fmaxf(ss * (1.f / 512.f) - mu * mu, 0.f);
  float r = rsqrtf(var + 1e-5f);
  float o0 = (v0 - mu) * r * g[d0] + be[d0];
  float o1 = (v1 - mu) * r * g[d1] + be[d1];
  u16 h0 = f2b(o0), h1 = f2b(o1);
  Xh[lbase + d0] = h0; Xl[lbase + d0] = f2b(o0 - b2f(h0));
  Xh[lbase + d1] = h1; Xl[lbase + d1] = f2b(o1 - b2f(h1));
}

// ---- residual LN: LN(recon(Xh,Xl) + Bv) -> f32 (+ optional bf16 copy) ----
__global__ __launch_bounds__(256) void k_ln_res2(const u16* __restrict__ Xh, const u16* __restrict__ Xl,
                                                 const float* __restrict__ Bv,
                                                 const float* __restrict__ g, const float* __restrict__ be,
                                                 float* __restrict__ outf, u16* __restrict__ outb) {
  __shared__ float sa[4], sb[4];
  int tid = threadIdx.x, d0 = tid, d1 = tid + 256;
  size_t base = (size_t)blockIdx.x * 512;
  float v0 = b2f(Xh[base + d0]) + b2f(Xl[base + d0]) + Bv[base + d0];
  float v1 = b2f(Xh[base + d1]) + b2f(Xl[base + d1]) + Bv[base + d1];
  float s = v0 + v1, ss = v0 * v0 + v1 * v1;
  blockReduce2(s, ss, sa, sb);
  float mu = s * (1.f / 512.f);
  float var = fmaxf(ss * (1.f / 512.f) - mu * mu, 0.f);
  float r = rsqrtf(var + 1e-5f);
  float o0 = (v0 - mu) * r * g[d0] + be[d0];
  float o1 = (v1 - mu) * r * g[d1] + be[d1];
  outf[base + d0] = o0;
  outf[base + d1] = o1;
  if (outb) { outb[base + d0] = f2b(o0); outb[base + d1] = f2b(o1); }
}

// ---- residual LN (both f32) ----
__global__ __launch_bounds__(256) void k_ln_res(const float* __restrict__ A, const float* __restrict__ Bv,
                                                const float* __restrict__ g, const float* __restrict__ be,
                                                float* __restrict__ outf) {
  __shared__ float sa[4], sb[4];
  int tid = threadIdx.x, d0 = tid, d1 = tid + 256;
  size_t base = (size_t)blockIdx.x * 512;
  float v0 = A[base + d0] + Bv[base + d0];
  float v1 = A[base + d1] + Bv[base + d1];
  float s = v0 + v1, ss = v0 * v0 + v1 * v1;
  blockReduce2(s, ss, sa, sb);
  float mu = s * (1.f / 512.f);
  float var = fmaxf(ss * (1.f / 512.f) - mu * mu, 0.f);
  float r = rsqrtf(var + 1e-5f);
  outf[base + d0] = (v0 - mu) * r * g[d0] + be[d0];
  outf[base + d1] = (v1 - mu) * r * g[d1] + be[d1];
}

// ---- split-precision MFMA GEMM v2: pre-split bf16 inputs, 128x128 tile ----
template<int NOUT>
__global__ __launch_bounds__(256) void gemm_sp2(
    const u16* __restrict__ Xh, const u16* __restrict__ Xl, int lda,
    const u16* __restrict__ Wth, const u16* __restrict__ Wtl,
    const float* __restrict__ b0c, const float* __restrict__ b1c, const float* __restrict__ b2c,
    float* __restrict__ C0, float* __restrict__ C1, float* __restrict__ C2) {
  const float* bias = b0c; float* C = C0;
  const u16* Wh = Wth; const u16* Wl = Wtl;
  if (NOUT == 3) {
    int z = blockIdx.z;
    Wh += (size_t)z * 262144; Wl += (size_t)z * 262144;
    if (z == 1) { bias = b1c; C = C1; }
    else if (z == 2) { bias = b2c; C = C2; }
  }
  const int bm = blockIdx.y << 7, bn = blockIdx.x << 7;
  __shared__ u16 Ah[128][40];
  __shared__ u16 Al[128][40];
  __shared__ u16 Bh[128][40];
  __shared__ u16 Bl[128][40];
  const int tid = threadIdx.x;
  const int sr = tid >> 1, sk = (tid & 1) << 4;
  const int wv = tid >> 6, lane = tid & 63, q = lane >> 4, m16 = lane & 15;
  const int wr = (wv >> 1) << 6, wc = (wv & 1) << 6;
  f32x4 acc[4][4];
  #pragma unroll
  for (int m = 0; m < 4; ++m)
    #pragma unroll
    for (int n = 0; n < 4; ++n)
      #pragma unroll
      for (int i = 0; i < 4; ++i) acc[m][n][i] = 0.f;

  for (int k0 = 0; k0 < 512; k0 += 32) {
    __syncthreads();
    const size_t ao_ = (size_t)(bm + sr) * lda + k0 + sk;
    const size_t bo_ = (size_t)(bn + sr) * 512 + k0 + sk;
    *(uint4*)&Ah[sr][sk]     = *(const uint4*)(Xh + ao_);
    *(uint4*)&Ah[sr][sk + 8] = *(const uint4*)(Xh + ao_ + 8);
    *(uint4*)&Al[sr][sk]     = *(const uint4*)(Xl + ao_);
    *(uint4*)&Al[sr][sk + 8] = *(const uint4*)(Xl + ao_ + 8);
    *(uint4*)&Bh[sr][sk]     = *(const uint4*)(Wh + bo_);
    *(uint4*)&Bh[sr][sk + 8] = *(const uint4*)(Wh + bo_ + 8);
    *(uint4*)&Bl[sr][sk]     = *(const uint4*)(Wl + bo_);
    *(uint4*)&Bl[sr][sk + 8] = *(const uint4*)(Wl + bo_ + 8);
    __syncthreads();
    short8 ah[4], al[4];
    #pragma unroll
    for (int m = 0; m < 4; ++m) {
      ah[m] = *(const short8*)&Ah[wr + m * 16 + m16][q * 8];
      al[m] = *(const short8*)&Al[wr + m * 16 + m16][q * 8];
    }
    #pragma unroll
    for (int n = 0; n < 4; ++n) {
      short8 bh = *(const short8*)&Bh[wc + n * 16 + m16][q * 8];
      short8 bl = *(const short8*)&Bl[wc + n * 16 + m16][q * 8];
      #pragma unroll
      for (int m = 0; m < 4; ++m) {
        acc[m][n] = __builtin_amdgcn_mfma_f32_16x16x32_bf16(ah[m], bh, acc[m][n], 0, 0, 0);
        acc[m][n] = __builtin_amdgcn_mfma_f32_16x16x32_bf16(al[m], bh, acc[m][n], 0, 0, 0);
        acc[m][n] = __builtin_amdgcn_mfma_f32_16x16x32_bf16(ah[m], bl, acc[m][n], 0, 0, 0);
      }
    }
  }
  #pragma unroll
  for (int n = 0; n < 4; ++n) {
    int col = bn + wc + n * 16 + m16;
    float bb = bias[col];
    #pragma unroll
    for (int m = 0; m < 4; ++m) {
      #pragma unroll
      for (int i = 0; i < 4; ++i) {
        int rl = bm + wr + m * 16 + q * 4 + i;
        C[(size_t)rl * 512 + col] = acc[m][n][i] + bb;
      }
    }
  }
}

// ---- per-node head attention -> per-row packed [hi(512)|lo(512)] u16, IN PLACE over q row t ----
__global__ __launch_bounds__(64) void k_attn(const float* __restrict__ q, const float* __restrict__ k,
                                             const float* __restrict__ v,
                                             u16* __restrict__ aohl) {
  __shared__ float qs[512], ks[512], vs[512], at[64];
  size_t t = blockIdx.x;
  int lane = threadIdx.x;
  for (int i = lane; i < 512; i += 64) {
    qs[i] = q[t * 512 + i]; ks[i] = k[t * 512 + i]; vs[i] = v[t * 512 + i];
  }
  __syncthreads();
  int h = lane >> 3, g = lane & 7;
  float s = 0.f;
  #pragma unroll 8
  for (int d = 0; d < 64; ++d) s = fmaf(qs[h * 64 + d], ks[g * 64 + d], s);
  s *= 0.125f;
  float m = s;
  #pragma unroll
  for (int off = 1; off < 8; off <<= 1) m = fmaxf(m, __shfl_xor(m, off));
  float ex = expf(s - m);
  float sum = ex;
  #pragma unroll
  for (int off = 1; off < 8; off <<= 1) sum += __shfl_xor(sum, off);
  at[lane] = ex / sum;
  __syncthreads();
  #pragma unroll
  for (int j = 0; j < 8; ++j) {
    int d = lane + j * 64, hh = d >> 6, hd = d & 63;
    float acc = 0.f;
    #pragma unroll
    for (int gg = 0; gg < 8; ++gg) acc = fmaf(at[hh * 8 + gg], vs[gg * 64 + hd], acc);
    u16 hi = f2b(acc);
    aohl[t * 1024 + d] = hi;
    aohl[t * 1024 + 512 + d] = f2b(acc - b2f(hi));
  }
}

// ---- gate phase A ----
__global__ __launch_bounds__(256) void k_gateA(const float* __restrict__ h2, const float* __restrict__ gw,
                                               const float* __restrict__ gb, float* __restrict__ probs,
                                               int* __restrict__ sel, float2* __restrict__ wpair) {
  int lane = threadIdx.x & 63, wid = threadIdx.x >> 6;
  int t = blockIdx.x * 4 + wid;
  const float* x = h2 + (size_t)t * 512;
  float acc[8] = {};
  for (int d = lane; d < 512; d += 64) {
    float xv = x[d];
    float4 g0 = *(const float4*)(gw + d * 8);
    float4 g1 = *(const float4*)(gw + d * 8 + 4);
    acc[0] = fmaf(xv, g0.x, acc[0]); acc[1] = fmaf(xv, g0.y, acc[1]);
    acc[2] = fmaf(xv, g0.z, acc[2]); acc[3] = fmaf(xv, g0.w, acc[3]);
    acc[4] = fmaf(xv, g1.x, acc[4]); acc[5] = fmaf(xv, g1.y, acc[5]);
    acc[6] = fmaf(xv, g1.z, acc[6]); acc[7] = fmaf(xv, g1.w, acc[7]);
  }
  #pragma unroll
  for (int off = 32; off; off >>= 1)
    #pragma unroll
    for (int e = 0; e < 8; ++e) acc[e] += __shfl_xor(acc[e], off);
  if (lane == 0) {
    float m = -1e30f;
    #pragma unroll
    for (int e = 0; e < 8; ++e) { acc[e] += gb[e]; m = fmaxf(m, acc[e]); }
    float p[8], sum = 0.f;
    #pragma unroll
    for (int e = 0; e < 8; ++e) { p[e] = expf(acc[e] - m); sum += p[e]; }
    float inv = 1.f / sum;
    #pragma unroll
    for (int e = 0; e < 8; ++e) { p[e] *= inv; probs[t * 8 + e] = p[e]; }
    int i1 = 0; float m1 = p[0];
    #pragma unroll
    for (int e = 1; e < 8; ++e) if (p[e] > m1) { m1 = p[e]; i1 = e; }
    int i2 = -1; float m2 = -1.f;
    #pragma unroll
    for (int e = 0; e < 8; ++e) if (e != i1 && p[e] > m2) { m2 = p[e]; i2 = e; }
    if (i2 < 0) i2 = (i1 + 1) & 7;
    float den = m1 + m2;
    float invs = (den > 0.f) ? 1.f / den : 0.f;
    sel[t] = i1 | (i2 << 4);
    wpair[t] = make_float2(m1 * invs, m2 * invs);
  }
}

// ---- gate phase B ----
__global__ __launch_bounds__(256) void k_gateB(const int* __restrict__ sel, const float2* __restrict__ wpair,
                                               int* __restrict__ toklist, float* __restrict__ wlist,
                                               int* __restrict__ cnt) {
  int e = blockIdx.x;
  int tid = threadIdx.x, lane = tid & 63, wv = tid >> 6;
  __shared__ int wsum[4];
  int base = 0;
  for (int t0 = 0; t0 < 8192; t0 += 256) {
    int t = t0 + tid;
    int s = sel[t];
    int i1 = s & 15, i2 = (s >> 4) & 15;
    bool f = (i1 == e) || (i2 == e);
    float wt = (i1 == e) ? wpair[t].x : ((i2 == e) ? wpair[t].y : 0.f);
    unsigned long long m = __ballot(f);
    int rank = __popcll(m & ((1ull << lane) - 1ull));
    int wtot = __popcll(m);
    if (lane == 0) wsum[wv] = wtot;
    __syncthreads();
    int prev = 0;
    for (int ww = 0; ww < wv; ++ww) prev += wsum[ww];
    int tot = wsum[0] + wsum[1] + wsum[2] + wsum[3];
    if (f) {
      int pos = base + prev + rank;
      toklist[e * 8192 + pos] = t;
      wlist[e * 8192 + pos] = wt;
    }
    base += tot;
    __syncthreads();
  }
  if (tid == 0) cnt[e] = base;
}

// ---- OLD MFMA bf16 GEMM: 64x64 tile (kept for small-workspace tiers + halt head) ----
template<int XMODE, int ACT, int OUTMODE, int EXPERT>
__global__ __launch_bounds__(256) void mfma_gemm(
    const float* __restrict__ Xf, const u16* __restrict__ Xb,
    const float* __restrict__ Wg, const float* __restrict__ biasg,
    float* __restrict__ C, u16* __restrict__ C16,
    const int* __restrict__ toklist, const float* __restrict__ wlist,
    const int* __restrict__ cnt, int M, int K, int N, int chunk0,
    size_t hidstride, float* __restrict__ moe) {
  int e = EXPERT ? blockIdx.z : 0;
  const float* W = Wg + (size_t)e * K * N;
  const float* bias = biasg + (size_t)e * N;
  int Mloc = M;
  if (EXPERT) {
    int ce = cnt[e]; if (ce > 8192) ce = 8192;
    Mloc = ce - chunk0;
    if (XMODE == 1) Xb += (size_t)e * hidstride;
    if (OUTMODE == 2) C16 += (size_t)e * hidstride;
  }
  const int bm = blockIdx.y << 6, bn = blockIdx.x << 6;
  if (EXPERT && bm >= Mloc) return;
  __shared__ u16 As[64][40];
  __shared__ u16 Bs[64][40];
  __shared__ int rows[64];
  const int tid = threadIdx.x;
  if (EXPERT && XMODE == 2 && tid < 64) {
    int ce = cnt[e]; if (ce > 8192) ce = 8192;
    int r = chunk0 + bm + tid;
    rows[tid] = toklist[e * 8192 + (r < ce ? r : chunk0)] & 8191;
  }
  const int srow = tid >> 2;
  const int skg = (tid & 3) << 3;
  const int wv = tid >> 6, lane = tid & 63, q = lane >> 4, m16 = lane & 15;
  f32x4 acc[4];
  #pragma unroll
  for (int c = 0; c < 4; ++c)
    #pragma unroll
    for (int i = 0; i < 4; ++i) acc[c][i] = 0.f;

  for (int k0 = 0; k0 < K; k0 += 32) {
    __syncthreads();
    {
      u16 a8[8] __attribute__((aligned(16)));
      if (XMODE == 1) {
        *(uint4*)a8 = *(const uint4*)(Xb + (size_t)(bm + srow) * K + k0 + skg);
      } else {
        const float* src = (XMODE == 2) ? (Xf + (size_t)rows[srow] * K + k0 + skg)
                                        : (Xf + (size_t)(bm + srow) * K + k0 + skg);
        float4 x0 = *(const float4*)(src);
        float4 x1 = *(const float4*)(src + 4);
        a8[0] = f2b(x0.x); a8[1] = f2b(x0.y); a8[2] = f2b(x0.z); a8[3] = f2b(x0.w);
        a8[4] = f2b(x1.x); a8[5] = f2b(x1.y); a8[6] = f2b(x1.z); a8[7] = f2b(x1.w);
      }
      *(uint4*)&As[srow][skg] = *(uint4*)a8;
    }
    {
      u16 b8[8] __attribute__((aligned(16)));
      const float* src = W + (size_t)(k0 + skg) * N + bn + srow;
      #pragma unroll
      for (int j = 0; j < 8; ++j) b8[j] = f2b(src[(size_t)j * N]);
      *(uint4*)&Bs[srow][skg] = *(uint4*)b8;
    }
    __syncthreads();
    short8 af = *(const short8*)&As[wv * 16 + m16][q * 8];
    #pragma unroll
    for (int c = 0; c < 4; ++c) {
      short8 bf = *(const short8*)&Bs[c * 16 + m16][q * 8];
      acc[c] = __builtin_amdgcn_mfma_f32_16x16x32_bf16(af, bf, acc[c], 0, 0, 0);
    }
  }
  #pragma unroll
  for (int c = 0; c < 4; ++c) {
    int col = bn + c * 16 + m16;
    float bb = bias[col];
    #pragma unroll
    for (int i = 0; i < 4; ++i) {
      int rl = bm + wv * 16 + q * 4 + i;
      if (EXPERT && rl >= Mloc) continue;
      float v = acc[c][i] + bb;
      if (ACT == 1) v = v / (1.f + expf(-v));
      else if (ACT == 2) v = tanhf(v);
      if (OUTMODE == 0) C[(size_t)rl * N + col] = v;
      else if (OUTMODE == 1) C[(size_t)rl * N + col] += v;
      else if (OUTMODE == 2) C16[(size_t)rl * N + col] = f2b(v);
      else {
        int rg = chunk0 + rl;
        int tok = toklist[e * 8192 + rg] & 8191;
        float wt = wlist[e * 8192 + rg];
        atomicAdd(&moe[(size_t)tok * 512 + col], v * wt);
      }
    }
  }
}

// ---- FAST MFMA bf16 GEMM: 128x128 tile, BK=32, 4 waves x (4x4 frags), pure-bf16 operands ----
// Xb: bf16 [row][K]; Wt: bf16 [n][K] (pre-transposed). 16 MFMA : 8 ds_read_b128 per wave/K-step.
// XMODE: 1 dense bf16, 2 gathered bf16 rows (toklist). ACT/OUTMODE/EXPERT as in mfma_gemm.
template<int XMODE, int ACT, int OUTMODE, int EXPERT>
__global__ __launch_bounds__(256) void mfma_gemm2(
    const u16* __restrict__ Xb, const u16* __restrict__ Wt, const float* __restrict__ biasg,
    float* __restrict__ C, u16* __restrict__ C16,
    const int* __restrict__ toklist, const float* __restrict__ wlist,
    const int* __restrict__ cnt, int M, int K, int N, int chunk0,
    size_t hidstride, float* __restrict__ moe) {
  int e = EXPERT ? blockIdx.z : 0;
  const u16* W = Wt + (size_t)e * K * N;
  const float* bias = biasg + (size_t)e * N;
  int Mloc = M;
  if (EXPERT) {
    int ce = cnt[e]; if (ce > 8192) ce = 8192;
    Mloc = ce - chunk0;
    if (XMODE == 1) Xb += (size_t)e * hidstride;
    if (OUTMODE == 2) C16 += (size_t)e * hidstride;
  }
  const int bm = blockIdx.y << 7, bn = blockIdx.x << 7;
  if (EXPERT && bm >= Mloc) return;
  __shared__ u16 As[128][40];
  __shared__ u16 Bs[128][40];
  __shared__ int rows[128];
  const int tid = threadIdx.x;
  if (XMODE == 2) {
    if (tid < 128) {
      int ce = cnt[e]; if (ce > 8192) ce = 8192;
      int r = chunk0 + bm + tid;
      rows[tid] = toklist[e * 8192 + (r < ce ? r : chunk0)] & 8191;
    }
    __syncthreads();
  }
  const int sr = tid >> 1, sk = (tid & 1) << 4;
  const int wv = tid >> 6, lane = tid & 63, q = lane >> 4, m16 = lane & 15;
  const int wr = (wv >> 1) << 6, wc = (wv & 1) << 6;
  const u16* arow = (XMODE == 2) ? (Xb + (size_t)rows[sr] * K) : (Xb + (size_t)(bm + sr) * K);
  const u16* brow = W + (size_t)(bn + sr) * K;
  f32x4 acc[4][4];
  #pragma unroll
  for (int m = 0; m < 4; ++m)
    #pragma unroll
    for (int n = 0; n < 4; ++n)
      #pragma unroll
      for (int i = 0; i < 4; ++i) acc[m][n][i] = 0.f;

  for (int k0 = 0; k0 < K; k0 += 32) {
    __syncthreads();
    *(uint4*)&As[sr][sk]     = *(const uint4*)(arow + k0 + sk);
    *(uint4*)&As[sr][sk + 8] = *(const uint4*)(arow + k0 + sk + 8);
    *(uint4*)&Bs[sr][sk]     = *(const uint4*)(brow + k0 + sk);
    *(uint4*)&Bs[sr][sk + 8] = *(const uint4*)(brow + k0 + sk + 8);
    __syncthreads();
    short8 ah[4];
    #pragma unroll
    for (int m = 0; m < 4; ++m)
      ah[m] = *(const short8*)&As[wr + m * 16 + m16][q * 8];
    #pragma unroll
    for (int n = 0; n < 4; ++n) {
      short8 bh = *(const short8*)&Bs[wc + n * 16 + m16][q * 8];
      #pragma unroll
      for (int m = 0; m < 4; ++m)
        acc[m][n] = __builtin_amdgcn_mfma_f32_16x16x32_bf16(ah[m], bh, acc[m][n], 0, 0, 0);
    }
  }
  #pragma unroll
  for (int n = 0; n < 4; ++n) {
    int col = bn + wc + n * 16 + m16;
    float bb = bias[col];
    #pragma unroll
    for (int m = 0; m < 4; ++m) {
      #pragma unroll
      for (int i = 0; i < 4; ++i) {
        int rl = bm + wr + m * 16 + q * 4 + i;
        if (EXPERT && rl >= Mloc) continue;
        float v = acc[m][n][i] + bb;
        if (ACT == 1) v = v / (1.f + expf(-v));
        else if (ACT == 2) v = tanhf(v);
        if (OUTMODE == 0) C[(size_t)rl * N + col] = v;
        else if (OUTMODE == 1) C[(size_t)rl * N + col] += v;
        else if (OUTMODE == 2) C16[(size_t)rl * N + col] = f2b(v);
        else {
          int rg = chunk0 + rl;
          int tok = toklist[e * 8192 + rg] & 8191;
          float wt = wlist[e * 8192 + rg];
          atomicAdd(&moe[(size_t)tok * 512 + col], v * wt);
        }
      }
    }
  }
}

// ---- halt head ----
__global__ __launch_bounds__(256) void k_halt(const u16* __restrict__ hh, const float* __restrict__ hW2,
                                              const float* __restrict__ hb2, float* __restrict__ out) {
  int lane = threadIdx.x & 63, wid = threadIdx.x >> 6;
  int t = blockIdx.x * 4 + wid;
  const u16* x = hh + (size_t)t * 256;
  float a = b2f(x[lane]) * hW2[lane] + b2f(x[lane + 64]) * hW2[lane + 64] +
            b2f(x[lane + 128]) * hW2[lane + 128] + b2f(x[lane + 192]) * hW2[lane + 192];
  #pragma unroll
  for (int off = 32; off; off >>= 1) a += __shfl_xor(a, off);
  if (lane == 0) {
    float p = 1.f / (1.f + expf(-(a + hb2[0])));
    out[4194304 + t] = p;
    out[4194304 + 8192 + t] = p;
  }
}

// ---- scalar: stab + aux loss ----
__global__ __launch_bounds__(256) void k_final(const float* __restrict__ probs, const int* __restrict__ cnt,
                                               const float* __restrict__ lA, float* __restrict__ out) {
  __shared__ float sp[4][8];
  __shared__ float sm[4];
  int tid = threadIdx.x, lane = tid & 63, wid = tid >> 6;
  float part[8] = {};
  for (int i = tid; i < 8192; i += 256) {
    const float* p = probs + i * 8;
    #pragma unroll
    for (int e = 0; e < 8; ++e) part[e] += p[e];
  }
  #pragma unroll
  for (int off = 32; off; off >>= 1)
    #pragma unroll
    for (int e = 0; e < 8; ++e) part[e] += __shfl_xor(part[e], off);
  float mx = 0.f;
  for (int d = tid; d < 512; d += 256) mx = fmaxf(mx, expf(lA[d]));
  #pragma unroll
  for (int off = 32; off; off >>= 1) mx = fmaxf(mx, __shfl_xor(mx, off));
  if (lane == 0) {
    #pragma unroll
    for (int e = 0; e < 8; ++e) sp[wid][e] = part[e];
    sm[wid] = mx;
  }
  __syncthreads();
  if (tid == 0) {
    float loss = 0.f;
    for (int e = 0; e < 8; ++e) {
      float pm = (sp[0][e] + sp[1][e] + sp[2][e] + sp[3][e]) * (1.f / 8192.f);
      int c = cnt[e]; if (c > 8192) c = 8192;
      loss += (float)c * (1.f / 8192.f) * pm;
    }
    loss *= 0.01f * 8.f;
    float mall = fmaxf(fmaxf(sm[0], sm[1]), fmaxf(sm[2], sm[3]));
    out[4194304 + 16384] = fmaxf(mall - 0.95f, 0.f) + loss;
  }
}

extern "C" void kernel_launch(void* const* d_in, const int* in_sizes, int n_in,
                              void* d_out, int out_size, void* d_ws, size_t ws_size,
                              hipStream_t stream) {
  const float* h   = (const float*)d_in[0];
  const float* ef  = (const float*)d_in[1];
  const float* lA  = (const float*)d_in[2];
  const float* Bw  = (const float*)d_in[3];
  const float* Bb  = (const float*)d_in[4];
  const float* Wq  = (const float*)d_in[5];  const float* bq  = (const float*)d_in[6];
  const float* Wk  = (const float*)d_in[7];  const float* bk  = (const float*)d_in[8];
  const float* Wv  = (const float*)d_in[9];  const float* bv  = (const float*)d_in[10];
  const float* Wo  = (const float*)d_in[11]; const float* bo  = (const float*)d_in[12];
  const float* n1g = (const float*)d_in[13]; const float* n1b = (const float*)d_in[14];
  const float* n2g = (const float*)d_in[15]; const float* n2b = (const float*)d_in[16];
  const float* n3g = (const float*)d_in[17]; const float* n3b = (const float*)d_in[18];
  const float* gw  = (const float*)d_in[19]; const float* gb  = (const float*)d_in[20];
  const float* eW1 = (const float*)d_in[21]; const float* eb1 = (const float*)d_in[22];
  const float* eW2 = (const float*)d_in[23]; const float* eb2 = (const float*)d_in[24];
  const float* sW1 = (const float*)d_in[25]; const float* sb1 = (const float*)d_in[26];
  const float* sW2 = (const float*)d_in[27]; const float* sb2 = (const float*)d_in[28];
  const float* hW1 = (const float*)d_in[29]; const float* hb1 = (const float*)d_in[30];
  const float* hW2 = (const float*)d_in[31]; const float* hb2 = (const float*)d_in[32];
  float* out = (float*)d_out;
  float* ws = (float*)d_ws;

  // ---- tiered workspace layout ----
  const size_t R = (size_t)TT * DD;   // 4,194,304 floats
  const size_t SM = 155648 + 73744;
  size_t wsf = ws_size / 4;
  int S; size_t ARENA;
  bool FAST;
  if (wsf >= 6 * R + SM)      { S = 8192; ARENA = 4 * R; FAST = true; }
  else if (wsf >= 3 * R + SM) { S = 2048; ARENA = R; FAST = false; }
  else                        { S = 512;  ARENA = 1048576; FAST = false; }
  const int CAPE = (int)(ARENA / 4096);
  const int NCH  = 8192 / CAPE;
  const size_t HIDSTRIDE = (size_t)CAPE * 1024;
  const int CAPS = (ARENA / 512 >= 8192) ? 8192 : (int)(ARENA / 512);

  float* f_h2  = ws;
  float* f_moe = ws + R;
  float* arena = ws + 2 * R;
  const size_t SD = (size_t)S * 512;
  u16* f_xh = (u16*)arena;
  u16* f_xl = f_xh + SD;
  float* f_q = arena + SD;
  float* f_k = arena + 2 * SD;
  float* f_v = arena + 3 * SD;
  u16* f_aohl = (u16*)f_q;
  float* f_hp = f_k;
  u16* f_wh = (u16*)f_moe;             // [4][512][512] split QKV/Wo weights (hi)
  u16* f_wl = f_wh + 4 * 262144;       // (lo)
  u16* f_hid = (u16*)arena;            // old-path hid
  u16* f_hh  = (u16*)arena;
  // FAST-path arena carve (u16 indices into arena; arena = 4R floats = 8R u16):
  //   hid   [0, 16777216)       = 8 experts x 2048 rows x 1024  (33.5 MB)
  //   eW1t  [16777216, 20971520) over dead hp region
  //   eW2t  [20971520, 25165824)
  //   h2b   [25165824, 29360128) over dead v region (written by ln_res2)
  //   sW1t  [29360128, 30408704)
  //   sW2t  [30408704, 31457280)
  u16* a16 = (u16*)arena;
  const int CAPE_F = 2048, NCH_F = 4;
  const size_t HSF = (size_t)CAPE_F * 1024;
  u16* f_hidF = a16;
  u16* f_eW1t = a16 + 16777216;
  u16* f_eW2t = a16 + 20971520;
  u16* f_h2b  = a16 + 25165824;
  u16* f_sW1t = a16 + 29360128;
  u16* f_sW2t = a16 + 30408704;
  float* smr = ws + 2 * R + ARENA;
  float* f_esum = smr;
  float* f_einj = smr + 4096;
  float* f_probs = smr + 8192;
  float2* f_wpair = (float2*)(smr + 8192 + 65536);
  float* f_wlist = smr + 8192 + 65536 + 16384;
  int* ip = (int*)(smr + 8192 + 65536 + 16384 + 65536);
  int* sel = ip; int* cnt = ip + 8192; int* toklist = ip + 8192 + 16;

  // ---- LTI prep + QKV weight split ----
  k_zero<<<16, 256, 0, stream>>>(f_esum);
  k_esum<<<dim3(8, 32), 256, 0, stream>>>(ef, f_esum);
  k_einj<<<16, 256, 0, stream>>>(f_esum, Bw, Bb, f_einj);
  k_wsplit<<<dim3(8, 8, 4), 256, 0, stream>>>(Wq, Wk, Wv, Wo, f_wh, f_wl);

  // ---- LTI + attention ----
  for (int s = 0; s < TT / S; ++s) {
    int seg0 = s * S;
    k_lti<<<S, 256, 0, stream>>>(h, lA, f_einj, n1g, n1b, f_xh, f_xl, seg0);
    gemm_sp2<3><<<dim3(4, S / 128, 3), 256, 0, stream>>>(
        f_xh, f_xl, 512, f_wh, f_wl, bq, bk, bv, f_q, f_k, f_v);
    k_attn<<<S, 64, 0, stream>>>(f_q, f_k, f_v, f_aohl);
    gemm_sp2<1><<<dim3(4, S / 128, 1), 256, 0, stream>>>(
        f_aohl, f_aohl + 512, 1024, f_wh + 3 * 262144, f_wl + 3 * 262144,
        bo, nullptr, nullptr, f_hp, nullptr, nullptr);
    k_ln_res2<<<S, 256, 0, stream>>>(f_xh, f_xl, f_hp, n2g, n2b,
                                     f_h2 + (size_t)seg0 * 512,
                                     FAST ? f_h2b + (size_t)seg0 * 512 : nullptr);
  }

  // ---- gate ----
  k_gateA<<<TT / 4, 256, 0, stream>>>(f_h2, gw, gb, f_probs, sel, f_wpair);
  k_gateB<<<8, 256, 0, stream>>>(sel, f_wpair, toklist, f_wlist, cnt);

  if (FAST) {
    // ---- convert MoE weights to bf16 [n][k] (hp/v regions are dead now) ----
    k_wt<<<dim3(8, 16, 8), 256, 0, stream>>>(eW1, f_eW1t, 512, 1024);
    k_wt<<<dim3(16, 8, 8), 256, 0, stream>>>(eW2, f_eW2t, 1024, 512);
    k_wt<<<dim3(8, 16, 2), 256, 0, stream>>>(sW1, f_sW1t, 512, 1024);
    k_wt<<<dim3(16, 8, 2), 256, 0, stream>>>(sW2, f_sW2t, 1024, 512);

    // ---- shared experts: 128^2-tile bf16 GEMMs ----
    for (int sx = 0; sx < 2; ++sx) {
      mfma_gemm2<1,1,2,0><<<dim3(8, 64), 256, 0, stream>>>(
          f_h2b, f_sW1t + (size_t)sx * 524288, sb1 + sx * 1024,
          nullptr, f_hidF, nullptr, nullptr, nullptr, TT, 512, 1024, 0, 0, nullptr);
      if (sx == 0)
        mfma_gemm2<1,0,0,0><<<dim3(4, 64), 256, 0, stream>>>(
            f_hidF, f_sW2t, sb2, f_moe, nullptr, nullptr, nullptr, nullptr,
            TT, 1024, 512, 0, 0, nullptr);
      else
        mfma_gemm2<1,0,1,0><<<dim3(4, 64), 256, 0, stream>>>(
            f_hidF, f_sW2t + 524288, sb2 + 512, f_moe, nullptr, nullptr, nullptr, nullptr,
            TT, 1024, 512, 0, 0, nullptr);
    }

    // ---- routed experts: gathered bf16 GEMMs, chunked by CAPE_F ----
    for (int c = 0; c < NCH_F; ++c) {
      mfma_gemm2<2,1,2,1><<<dim3(8, CAPE_F / 128, 8), 256, 0, stream>>>(
          f_h2b, f_eW1t, eb1, nullptr, f_hidF, toklist, nullptr, cnt,
          CAPE_F, 512, 1024, c * CAPE_F, HSF, nullptr);
      mfma_gemm2<1,0,3,1><<<dim3(4, CAPE_F / 128, 8), 256, 0, stream>>>(
          f_hidF, f_eW2t, eb2, nullptr, nullptr, toklist, f_wlist, cnt,
          CAPE_F, 1024, 512, c * CAPE_F, HSF, f_moe);
    }
  } else {
    // ---- old path (small workspace tiers) ----
    for (int sx = 0; sx < 2; ++sx)
      for (int c = 0; c < TT / CAPS; ++c) {
        const float* xs = f_h2 + (size_t)c * CAPS * 512;
        float* ms = f_moe + (size_t)c * CAPS * 512;
        mfma_gemm<0,1,2,0><<<dim3(16, CAPS / 64), 256, 0, stream>>>(
            xs, nullptr, sW1 + (size_t)sx * 524288, sb1 + sx * 1024,
            nullptr, f_hid, nullptr, nullptr, nullptr, CAPS, 512, 1024, 0, 0, nullptr);
        if (sx == 0)
          mfma_gemm<1,0,0,0><<<dim3(8, CAPS / 64), 256, 0, stream>>>(
              nullptr, f_hid, sW2, sb2, ms, nullptr, nullptr, nullptr, nullptr, CAPS, 1024, 512, 0, 0, nullptr);
        else
          mfma_gemm<1,0,1,0><<<dim3(8, CAPS / 64), 256, 0, stream>>>(
              nullptr, f_hid, sW2 + 524288, sb2 + 512, ms, nullptr, nullptr, nullptr, nullptr, CAPS, 1024, 512, 0, 0, nullptr);
      }
    for (int c = 0; c < NCH; ++c) {
      mfma_gemm<2,1,2,1><<<dim3(16, CAPE / 64, 8), 256, 0, stream>>>(
          f_h2, nullptr, eW1, eb1, nullptr, f_hid, toklist, nullptr, cnt,
          CAPE, 512, 1024, c * CAPE, HIDSTRIDE, nullptr);
      mfma_gemm<1,0,3,1><<<dim3(8, CAPE / 64, 8), 256, 0, stream>>>(
          nullptr, f_hid, eW2, eb2, nullptr, nullptr, toklist, f_wlist, cnt,
          CAPE, 1024, 512, c * CAPE, HIDSTRIDE, f_moe);
    }
  }

  // ---- final LN -> out (h3 f32), halt head, scalars ----
  k_ln_res<<<TT, 256, 0, stream>>>(f_h2, f_moe, n3g, n3b, out);
  mfma_gemm<0,2,2,0><<<dim3(4, 128), 256, 0, stream>>>(
      out, nullptr, hW1, hb1, nullptr, f_hh, nullptr, nullptr, nullptr, TT, 512, 256, 0, 0, nullptr);
  k_halt<<<TT / 4, 256, 0, stream>>>(f_hh, hW2, hb2, out);
  k_final<<<1, 256, 0, stream>>>(f_probs, cnt, lA, out);
}

// Round 6
// 713.733 us; speedup vs baseline: 1.4518x; 1.2271x over previous
//
#include <hip/hip_runtime.h>
#include <hip/hip_bf16.h>

// Problem constants (B=8, N=1024, D=512, H=8, HD=64, E=4096, NE=8, NSH=2, TOPK=2, DH=1024)
// ALL inputs/outputs are float32.
#define TT 8192
#define DD 512

typedef unsigned short u16;
typedef __attribute__((ext_vector_type(8))) short short8;
typedef __attribute__((ext_vector_type(4))) float f32x4;

__device__ __forceinline__ u16 f2b(float f) {
  union { float f; unsigned int i; } w; w.f = f;
  unsigned int x = w.i;
  unsigned int r = (x + 0x7FFFu + ((x >> 16) & 1u)) >> 16;
  if ((x & 0x7F800000u) == 0x7F800000u) r = x >> 16;
  return (u16)r;
}
__device__ __forceinline__ float b2f(u16 u) {
  union { unsigned int i; float f; } w; w.i = ((unsigned int)u) << 16; return w.f;
}

__device__ __forceinline__ void blockReduce2(float& a, float& b, float* s4a, float* s4b) {
  #pragma unroll
  for (int off = 32; off; off >>= 1) { a += __shfl_xor(a, off); b += __shfl_xor(b, off); }
  int wid = threadIdx.x >> 6;
  if ((threadIdx.x & 63) == 0) { s4a[wid] = a; s4b[wid] = b; }
  __syncthreads();
  a = s4a[0] + s4a[1] + s4a[2] + s4a[3];
  b = s4b[0] + s4b[1] + s4b[2] + s4b[3];
}

// ---- zero esum ----
__global__ __launch_bounds__(256) void k_zero(float* __restrict__ esum) {
  esum[blockIdx.x * 256 + threadIdx.x] = 0.f;
}

// ---- zero float4 (big buffers) ----
__global__ __launch_bounds__(256) void k_zero4(float4* __restrict__ p) {
  p[(size_t)blockIdx.x * 256 + threadIdx.x] = make_float4(0.f, 0.f, 0.f, 0.f);
}

// ---- edge sum: [B,E,D] -> [B,D] ----
__global__ __launch_bounds__(256) void k_esum(const float* __restrict__ ef, float* __restrict__ esum) {
  int b = blockIdx.x, ec = blockIdx.y, tid = threadIdx.x;
  float a0 = 0.f, a1 = 0.f;
  const float* base = ef + ((size_t)b * 4096 + (size_t)ec * 128) * 512;
  for (int e = 0; e < 128; ++e) {
    a0 += base[(size_t)e * 512 + tid];
    a1 += base[(size_t)e * 512 + tid + 256];
  }
  atomicAdd(&esum[b * 512 + tid], a0);
  atomicAdd(&esum[b * 512 + tid + 256], a1);
}

// ---- einj[b,dp] = (esum[b,:]/E) @ B_w[:,dp] + B_b[dp] ----
__global__ __launch_bounds__(256) void k_einj(const float* __restrict__ esum,
                                              const float* __restrict__ Bw, const float* __restrict__ Bb,
                                              float* __restrict__ einj) {
  int idx = blockIdx.x * 256 + threadIdx.x;
  int b = idx >> 9, dp = idx & 511;
  float a = Bb[dp];
  const float inv = 1.f / 4096.f;
  for (int d = 0; d < 512; ++d)
    a = fmaf(esum[b * 512 + d] * inv, Bw[d * 512 + dp], a);
  einj[idx] = a;
}

// ---- weight transpose + hi/lo bf16 split: W[512][512] -> Wt{h,l}[z][n][k] ----
__global__ __launch_bounds__(256) void k_wsplit(const float* __restrict__ Wq, const float* __restrict__ Wk,
                                                const float* __restrict__ Wv, const float* __restrict__ Wo,
                                                u16* __restrict__ outh, u16* __restrict__ outl) {
  __shared__ float st[64][65];
  int z = blockIdx.z;
  const float* W = z == 0 ? Wq : (z == 1 ? Wk : (z == 2 ? Wv : Wo));
  int k0 = blockIdx.x << 6, n0 = blockIdx.y << 6;
  int tid = threadIdx.x;
  int r = tid >> 2, c4 = (tid & 3) << 4;
  #pragma unroll
  for (int j = 0; j < 16; j += 4) {
    float4 v = *(const float4*)(W + (size_t)(k0 + r) * 512 + n0 + c4 + j);
    st[c4 + j + 0][r] = v.x; st[c4 + j + 1][r] = v.y;
    st[c4 + j + 2][r] = v.z; st[c4 + j + 3][r] = v.w;
  }
  __syncthreads();
  int n = tid >> 2, kb = (tid & 3) << 4;
  u16 h8[8] __attribute__((aligned(16)));
  u16 l8[8] __attribute__((aligned(16)));
  size_t obase = (size_t)z * 262144 + (size_t)(n0 + n) * 512 + k0 + kb;
  #pragma unroll
  for (int half = 0; half < 2; ++half) {
    #pragma unroll
    for (int j = 0; j < 8; ++j) {
      float val = st[n][kb + half * 8 + j];
      h8[j] = f2b(val);
      l8[j] = f2b(val - b2f(h8[j]));
    }
    *(uint4*)(outh + obase + half * 8) = *(uint4*)h8;
    *(uint4*)(outl + obase + half * 8) = *(uint4*)l8;
  }
}

// ---- generic weight transpose -> bf16 [n][k] (per-expert via blockIdx.z) ----
__global__ __launch_bounds__(256) void k_wt(const float* __restrict__ W, u16* __restrict__ Wt,
                                            int K, int N) {
  __shared__ float st[64][65];
  int z = blockIdx.z;
  W += (size_t)z * K * N; Wt += (size_t)z * K * N;
  int k0 = blockIdx.x << 6, n0 = blockIdx.y << 6;
  int tid = threadIdx.x;
  int r = tid >> 2, c4 = (tid & 3) << 4;
  #pragma unroll
  for (int j = 0; j < 16; j += 4) {
    float4 v = *(const float4*)(W + (size_t)(k0 + r) * N + n0 + c4 + j);
    st[c4 + j + 0][r] = v.x; st[c4 + j + 1][r] = v.y;
    st[c4 + j + 2][r] = v.z; st[c4 + j + 3][r] = v.w;
  }
  __syncthreads();
  int n = tid >> 2, kb = (tid & 3) << 4;
  u16 h8[8] __attribute__((aligned(16)));
  size_t obase = (size_t)(n0 + n) * K + k0 + kb;
  #pragma unroll
  for (int half = 0; half < 2; ++half) {
    #pragma unroll
    for (int j = 0; j < 8; ++j) h8[j] = f2b(st[n][kb + half * 8 + j]);
    *(uint4*)(Wt + obase + half * 8) = *(uint4*)h8;
  }
}

// ---- h_lti = LN(-exp(log_A)*h + einj) -> hi/lo bf16 (segment-local) ----
__global__ __launch_bounds__(256) void k_lti(const float* __restrict__ h, const float* __restrict__ lA,
                                             const float* __restrict__ einj,
                                             const float* __restrict__ g, const float* __restrict__ be,
                                             u16* __restrict__ Xh, u16* __restrict__ Xl, int seg0) {
  __shared__ float sa[4], sb[4];
  int rowg = seg0 + blockIdx.x, b = rowg >> 10, tid = threadIdx.x;
  int d0 = tid, d1 = tid + 256;
  size_t gbase = (size_t)rowg * 512;
  size_t lbase = (size_t)blockIdx.x * 512;
  float v0 = -expf(lA[d0]) * h[gbase + d0] + einj[b * 512 + d0];
  float v1 = -expf(lA[d1]) * h[gbase + d1] + einj[b * 512 + d1];
  float s = v0 + v1, ss = v0 * v0 + v1 * v1;
  blockReduce2(s, ss, sa, sb);
  float mu = s * (1.f / 512.f);
  float var = fmaxf(ss * (1.f / 512.f) - mu * mu, 0.f);
  float r = rsqrtf(var + 1e-5f);
  float o0 = (v0 - mu) * r * g[d0] + be[d0];
  float o1 = (v1 - mu) * r * g[d1] + be[d1];
  u16 h0 = f2b(o0), h1 = f2b(o1);
  Xh[lbase + d0] = h0; Xl[lbase + d0] = f2b(o0 - b2f(h0));
  Xh[lbase + d1] = h1; Xl[lbase + d1] = f2b(o1 - b2f(h1));
}

// ---- residual LN: LN(recon(Xh,Xl) + Bv) -> f32 (+ optional bf16 copy) ----
__global__ __launch_bounds__(256) void k_ln_res2(const u16* __restrict__ Xh, const u16* __restrict__ Xl,
                                                 const float* __restrict__ Bv,
                                                 const float* __restrict__ g, const float* __restrict__ be,
                                                 float* __restrict__ outf, u16* __restrict__ outb) {
  __shared__ float sa[4], sb[4];
  int tid = threadIdx.x, d0 = tid, d1 = tid + 256;
  size_t base = (size_t)blockIdx.x * 512;
  float v0 = b2f(Xh[base + d0]) + b2f(Xl[base + d0]) + Bv[base + d0];
  float v1 = b2f(Xh[base + d1]) + b2f(Xl[base + d1]) + Bv[base + d1];
  float s = v0 + v1, ss = v0 * v0 + v1 * v1;
  blockReduce2(s, ss, sa, sb);
  float mu = s * (1.f / 512.f);
  float var = fmaxf(ss * (1.f / 512.f) - mu * mu, 0.f);
  float r = rsqrtf(var + 1e-5f);
  float o0 = (v0 - mu) * r * g[d0] + be[d0];
  float o1 = (v1 - mu) * r * g[d1] + be[d1];
  outf[base + d0] = o0;
  outf[base + d1] = o1;
  if (outb) { outb[base + d0] = f2b(o0); outb[base + d1] = f2b(o1); }
}

// ---- residual LN (both f32) ----
__global__ __launch_bounds__(256) void k_ln_res(const float* __restrict__ A, const float* __restrict__ Bv,
                                                const float* __restrict__ g, const float* __restrict__ be,
                                                float* __restrict__ outf) {
  __shared__ float sa[4], sb[4];
  int tid = threadIdx.x, d0 = tid, d1 = tid + 256;
  size_t base = (size_t)blockIdx.x * 512;
  float v0 = A[base + d0] + Bv[base + d0];
  float v1 = A[base + d1] + Bv[base + d1];
  float s = v0 + v1, ss = v0 * v0 + v1 * v1;
  blockReduce2(s, ss, sa, sb);
  float mu = s * (1.f / 512.f);
  float var = fmaxf(ss * (1.f / 512.f) - mu * mu, 0.f);
  float r = rsqrtf(var + 1e-5f);
  outf[base + d0] = (v0 - mu) * r * g[d0] + be[d0];
  outf[base + d1] = (v1 - mu) * r * g[d1] + be[d1];
}

// ---- split-precision MFMA GEMM v2: pre-split bf16 inputs, 128x128 tile ----
template<int NOUT>
__global__ __launch_bounds__(256) void gemm_sp2(
    const u16* __restrict__ Xh, const u16* __restrict__ Xl, int lda,
    const u16* __restrict__ Wth, const u16* __restrict__ Wtl,
    const float* __restrict__ b0c, const float* __restrict__ b1c, const float* __restrict__ b2c,
    float* __restrict__ C0, float* __restrict__ C1, float* __restrict__ C2) {
  const float* bias = b0c; float* C = C0;
  const u16* Wh = Wth; const u16* Wl = Wtl;
  if (NOUT == 3) {
    int z = blockIdx.z;
    Wh += (size_t)z * 262144; Wl += (size_t)z * 262144;
    if (z == 1) { bias = b1c; C = C1; }
    else if (z == 2) { bias = b2c; C = C2; }
  }
  const int bm = blockIdx.y << 7, bn = blockIdx.x << 7;
  __shared__ u16 Ah[128][40];
  __shared__ u16 Al[128][40];
  __shared__ u16 Bh[128][40];
  __shared__ u16 Bl[128][40];
  const int tid = threadIdx.x;
  const int sr = tid >> 1, sk = (tid & 1) << 4;
  const int wv = tid >> 6, lane = tid & 63, q = lane >> 4, m16 = lane & 15;
  const int wr = (wv >> 1) << 6, wc = (wv & 1) << 6;
  f32x4 acc[4][4];
  #pragma unroll
  for (int m = 0; m < 4; ++m)
    #pragma unroll
    for (int n = 0; n < 4; ++n)
      #pragma unroll
      for (int i = 0; i < 4; ++i) acc[m][n][i] = 0.f;

  for (int k0 = 0; k0 < 512; k0 += 32) {
    __syncthreads();
    const size_t ao_ = (size_t)(bm + sr) * lda + k0 + sk;
    const size_t bo_ = (size_t)(bn + sr) * 512 + k0 + sk;
    *(uint4*)&Ah[sr][sk]     = *(const uint4*)(Xh + ao_);
    *(uint4*)&Ah[sr][sk + 8] = *(const uint4*)(Xh + ao_ + 8);
    *(uint4*)&Al[sr][sk]     = *(const uint4*)(Xl + ao_);
    *(uint4*)&Al[sr][sk + 8] = *(const uint4*)(Xl + ao_ + 8);
    *(uint4*)&Bh[sr][sk]     = *(const uint4*)(Wh + bo_);
    *(uint4*)&Bh[sr][sk + 8] = *(const uint4*)(Wh + bo_ + 8);
    *(uint4*)&Bl[sr][sk]     = *(const uint4*)(Wl + bo_);
    *(uint4*)&Bl[sr][sk + 8] = *(const uint4*)(Wl + bo_ + 8);
    __syncthreads();
    short8 ah[4], al[4];
    #pragma unroll
    for (int m = 0; m < 4; ++m) {
      ah[m] = *(const short8*)&Ah[wr + m * 16 + m16][q * 8];
      al[m] = *(const short8*)&Al[wr + m * 16 + m16][q * 8];
    }
    #pragma unroll
    for (int n = 0; n < 4; ++n) {
      short8 bh = *(const short8*)&Bh[wc + n * 16 + m16][q * 8];
      short8 bl = *(const short8*)&Bl[wc + n * 16 + m16][q * 8];
      #pragma unroll
      for (int m = 0; m < 4; ++m) {
        acc[m][n] = __builtin_amdgcn_mfma_f32_16x16x32_bf16(ah[m], bh, acc[m][n], 0, 0, 0);
        acc[m][n] = __builtin_amdgcn_mfma_f32_16x16x32_bf16(al[m], bh, acc[m][n], 0, 0, 0);
        acc[m][n] = __builtin_amdgcn_mfma_f32_16x16x32_bf16(ah[m], bl, acc[m][n], 0, 0, 0);
      }
    }
  }
  #pragma unroll
  for (int n = 0; n < 4; ++n) {
    int col = bn + wc + n * 16 + m16;
    float bb = bias[col];
    #pragma unroll
    for (int m = 0; m < 4; ++m) {
      #pragma unroll
      for (int i = 0; i < 4; ++i) {
        int rl = bm + wr + m * 16 + q * 4 + i;
        C[(size_t)rl * 512 + col] = acc[m][n][i] + bb;
      }
    }
  }
}

// ---- per-node head attention -> per-row packed [hi(512)|lo(512)] u16, IN PLACE over q row t ----
__global__ __launch_bounds__(64) void k_attn(const float* __restrict__ q, const float* __restrict__ k,
                                             const float* __restrict__ v,
                                             u16* __restrict__ aohl) {
  __shared__ float qs[512], ks[512], vs[512], at[64];
  size_t t = blockIdx.x;
  int lane = threadIdx.x;
  for (int i = lane; i < 512; i += 64) {
    qs[i] = q[t * 512 + i]; ks[i] = k[t * 512 + i]; vs[i] = v[t * 512 + i];
  }
  __syncthreads();
  int h = lane >> 3, g = lane & 7;
  float s = 0.f;
  #pragma unroll 8
  for (int d = 0; d < 64; ++d) s = fmaf(qs[h * 64 + d], ks[g * 64 + d], s);
  s *= 0.125f;
  float m = s;
  #pragma unroll
  for (int off = 1; off < 8; off <<= 1) m = fmaxf(m, __shfl_xor(m, off));
  float ex = expf(s - m);
  float sum = ex;
  #pragma unroll
  for (int off = 1; off < 8; off <<= 1) sum += __shfl_xor(sum, off);
  at[lane] = ex / sum;
  __syncthreads();
  #pragma unroll
  for (int j = 0; j < 8; ++j) {
    int d = lane + j * 64, hh = d >> 6, hd = d & 63;
    float acc = 0.f;
    #pragma unroll
    for (int gg = 0; gg < 8; ++gg) acc = fmaf(at[hh * 8 + gg], vs[gg * 64 + hd], acc);
    u16 hi = f2b(acc);
    aohl[t * 1024 + d] = hi;
    aohl[t * 1024 + 512 + d] = f2b(acc - b2f(hi));
  }
}

// ---- gate phase A ----
__global__ __launch_bounds__(256) void k_gateA(const float* __restrict__ h2, const float* __restrict__ gw,
                                               const float* __restrict__ gb, float* __restrict__ probs,
                                               int* __restrict__ sel, float2* __restrict__ wpair) {
  int lane = threadIdx.x & 63, wid = threadIdx.x >> 6;
  int t = blockIdx.x * 4 + wid;
  const float* x = h2 + (size_t)t * 512;
  float acc[8] = {};
  for (int d = lane; d < 512; d += 64) {
    float xv = x[d];
    float4 g0 = *(const float4*)(gw + d * 8);
    float4 g1 = *(const float4*)(gw + d * 8 + 4);
    acc[0] = fmaf(xv, g0.x, acc[0]); acc[1] = fmaf(xv, g0.y, acc[1]);
    acc[2] = fmaf(xv, g0.z, acc[2]); acc[3] = fmaf(xv, g0.w, acc[3]);
    acc[4] = fmaf(xv, g1.x, acc[4]); acc[5] = fmaf(xv, g1.y, acc[5]);
    acc[6] = fmaf(xv, g1.z, acc[6]); acc[7] = fmaf(xv, g1.w, acc[7]);
  }
  #pragma unroll
  for (int off = 32; off; off >>= 1)
    #pragma unroll
    for (int e = 0; e < 8; ++e) acc[e] += __shfl_xor(acc[e], off);
  if (lane == 0) {
    float m = -1e30f;
    #pragma unroll
    for (int e = 0; e < 8; ++e) { acc[e] += gb[e]; m = fmaxf(m, acc[e]); }
    float p[8], sum = 0.f;
    #pragma unroll
    for (int e = 0; e < 8; ++e) { p[e] = expf(acc[e] - m); sum += p[e]; }
    float inv = 1.f / sum;
    #pragma unroll
    for (int e = 0; e < 8; ++e) { p[e] *= inv; probs[t * 8 + e] = p[e]; }
    int i1 = 0; float m1 = p[0];
    #pragma unroll
    for (int e = 1; e < 8; ++e) if (p[e] > m1) { m1 = p[e]; i1 = e; }
    int i2 = -1; float m2 = -1.f;
    #pragma unroll
    for (int e = 0; e < 8; ++e) if (e != i1 && p[e] > m2) { m2 = p[e]; i2 = e; }
    if (i2 < 0) i2 = (i1 + 1) & 7;
    float den = m1 + m2;
    float invs = (den > 0.f) ? 1.f / den : 0.f;
    sel[t] = i1 | (i2 << 4);
    wpair[t] = make_float2(m1 * invs, m2 * invs);
  }
}

// ---- gate phase B ----
__global__ __launch_bounds__(256) void k_gateB(const int* __restrict__ sel, const float2* __restrict__ wpair,
                                               int* __restrict__ toklist, float* __restrict__ wlist,
                                               int* __restrict__ cnt) {
  int e = blockIdx.x;
  int tid = threadIdx.x, lane = tid & 63, wv = tid >> 6;
  __shared__ int wsum[4];
  int base = 0;
  for (int t0 = 0; t0 < 8192; t0 += 256) {
    int t = t0 + tid;
    int s = sel[t];
    int i1 = s & 15, i2 = (s >> 4) & 15;
    bool f = (i1 == e) || (i2 == e);
    float wt = (i1 == e) ? wpair[t].x : ((i2 == e) ? wpair[t].y : 0.f);
    unsigned long long m = __ballot(f);
    int rank = __popcll(m & ((1ull << lane) - 1ull));
    int wtot = __popcll(m);
    if (lane == 0) wsum[wv] = wtot;
    __syncthreads();
    int prev = 0;
    for (int ww = 0; ww < wv; ++ww) prev += wsum[ww];
    int tot = wsum[0] + wsum[1] + wsum[2] + wsum[3];
    if (f) {
      int pos = base + prev + rank;
      toklist[e * 8192 + pos] = t;
      wlist[e * 8192 + pos] = wt;
    }
    base += tot;
    __syncthreads();
  }
  if (tid == 0) cnt[e] = base;
}

// ---- OLD MFMA bf16 GEMM: 64x64 tile (kept for small-workspace tiers + halt head) ----
template<int XMODE, int ACT, int OUTMODE, int EXPERT>
__global__ __launch_bounds__(256) void mfma_gemm(
    const float* __restrict__ Xf, const u16* __restrict__ Xb,
    const float* __restrict__ Wg, const float* __restrict__ biasg,
    float* __restrict__ C, u16* __restrict__ C16,
    const int* __restrict__ toklist, const float* __restrict__ wlist,
    const int* __restrict__ cnt, int M, int K, int N, int chunk0,
    size_t hidstride, float* __restrict__ moe) {
  int e = EXPERT ? blockIdx.z : 0;
  const float* W = Wg + (size_t)e * K * N;
  const float* bias = biasg + (size_t)e * N;
  int Mloc = M;
  if (EXPERT) {
    int ce = cnt[e]; if (ce > 8192) ce = 8192;
    Mloc = ce - chunk0;
    if (XMODE == 1) Xb += (size_t)e * hidstride;
    if (OUTMODE == 2) C16 += (size_t)e * hidstride;
  }
  const int bm = blockIdx.y << 6, bn = blockIdx.x << 6;
  if (EXPERT && bm >= Mloc) return;
  __shared__ u16 As[64][40];
  __shared__ u16 Bs[64][40];
  __shared__ int rows[64];
  const int tid = threadIdx.x;
  if (EXPERT && XMODE == 2 && tid < 64) {
    int ce = cnt[e]; if (ce > 8192) ce = 8192;
    int r = chunk0 + bm + tid;
    rows[tid] = toklist[e * 8192 + (r < ce ? r : chunk0)] & 8191;
  }
  const int srow = tid >> 2;
  const int skg = (tid & 3) << 3;
  const int wv = tid >> 6, lane = tid & 63, q = lane >> 4, m16 = lane & 15;
  f32x4 acc[4];
  #pragma unroll
  for (int c = 0; c < 4; ++c)
    #pragma unroll
    for (int i = 0; i < 4; ++i) acc[c][i] = 0.f;

  for (int k0 = 0; k0 < K; k0 += 32) {
    __syncthreads();
    {
      u16 a8[8] __attribute__((aligned(16)));
      if (XMODE == 1) {
        *(uint4*)a8 = *(const uint4*)(Xb + (size_t)(bm + srow) * K + k0 + skg);
      } else {
        const float* src = (XMODE == 2) ? (Xf + (size_t)rows[srow] * K + k0 + skg)
                                        : (Xf + (size_t)(bm + srow) * K + k0 + skg);
        float4 x0 = *(const float4*)(src);
        float4 x1 = *(const float4*)(src + 4);
        a8[0] = f2b(x0.x); a8[1] = f2b(x0.y); a8[2] = f2b(x0.z); a8[3] = f2b(x0.w);
        a8[4] = f2b(x1.x); a8[5] = f2b(x1.y); a8[6] = f2b(x1.z); a8[7] = f2b(x1.w);
      }
      *(uint4*)&As[srow][skg] = *(uint4*)a8;
    }
    {
      u16 b8[8] __attribute__((aligned(16)));
      const float* src = W + (size_t)(k0 + skg) * N + bn + srow;
      #pragma unroll
      for (int j = 0; j < 8; ++j) b8[j] = f2b(src[(size_t)j * N]);
      *(uint4*)&Bs[srow][skg] = *(uint4*)b8;
    }
    __syncthreads();
    short8 af = *(const short8*)&As[wv * 16 + m16][q * 8];
    #pragma unroll
    for (int c = 0; c < 4; ++c) {
      short8 bf = *(const short8*)&Bs[c * 16 + m16][q * 8];
      acc[c] = __builtin_amdgcn_mfma_f32_16x16x32_bf16(af, bf, acc[c], 0, 0, 0);
    }
  }
  #pragma unroll
  for (int c = 0; c < 4; ++c) {
    int col = bn + c * 16 + m16;
    float bb = bias[col];
    #pragma unroll
    for (int i = 0; i < 4; ++i) {
      int rl = bm + wv * 16 + q * 4 + i;
      if (EXPERT && rl >= Mloc) continue;
      float v = acc[c][i] + bb;
      if (ACT == 1) v = v / (1.f + expf(-v));
      else if (ACT == 2) v = tanhf(v);
      if (OUTMODE == 0) C[(size_t)rl * N + col] = v;
      else if (OUTMODE == 1) C[(size_t)rl * N + col] += v;
      else if (OUTMODE == 2) C16[(size_t)rl * N + col] = f2b(v);
      else {
        int rg = chunk0 + rl;
        int tok = toklist[e * 8192 + rg] & 8191;
        float wt = wlist[e * 8192 + rg];
        atomicAdd(&moe[(size_t)tok * 512 + col], v * wt);
      }
    }
  }
}

// ---- FAST MFMA bf16 GEMM v3: 128x128 tile, 8 waves (512 thr), double-buffered LDS,
//      register prefetch, ONE barrier per K-step. Wave owns 64x32 (4x2 frags).
// XMODE: 1 dense bf16 (NO per-expert input offset), 2 gathered bf16 rows (toklist),
//        3 per-expert bf16 (Xb += e*hidstride)  [R5 NaN fix: shared-W1 must use 1]
// ACT: 0 none, 1 silu
// OUTMODE: 0 f32 store, 1 f32 +=, 2 bf16 store (+e*hidstride), 3 weighted scatter-atomicAdd,
//          4 dense atomicAdd
// EXPERT: 0 none; 1 routed (cnt-bounded, z=expert); 2 dense-z (z offsets W/bias/hid only)
template<int XMODE, int ACT, int OUTMODE, int EXPERT>
__global__ __launch_bounds__(512, 4) void mfma_gemm3(
    const u16* __restrict__ Xb, const u16* __restrict__ Wt, const float* __restrict__ biasg,
    float* __restrict__ C, u16* __restrict__ C16,
    const int* __restrict__ toklist, const float* __restrict__ wlist,
    const int* __restrict__ cnt, int M, int K, int N, int chunk0,
    size_t hidstride, float* __restrict__ moe) {
  int e = EXPERT ? blockIdx.z : 0;
  const u16* W = Wt + (size_t)e * K * N;
  const float* bias = biasg + (size_t)e * N;
  int Mloc = M;
  if (EXPERT == 1) {
    int ce = cnt[e]; if (ce > 8192) ce = 8192;
    Mloc = ce - chunk0;
  }
  if (EXPERT) {
    if (XMODE == 3) Xb += (size_t)e * hidstride;     // per-expert input region ONLY for XMODE 3
    if (OUTMODE == 2) C16 += (size_t)e * hidstride;
  }
  const int bm = blockIdx.y << 7, bn = blockIdx.x << 7;
  if (EXPERT == 1 && bm >= Mloc) return;
  __shared__ u16 As[2][128][40];
  __shared__ u16 Bs[2][128][40];
  __shared__ int rows[128];
  const int tid = threadIdx.x;
  if (EXPERT == 1 && XMODE == 2) {
    if (tid < 128) {
      int ce = cnt[e]; if (ce > 8192) ce = 8192;
      int r = chunk0 + bm + tid;
      rows[tid] = toklist[e * 8192 + (r < ce ? r : chunk0)] & 8191;
    }
    __syncthreads();
  }
  const int sr = tid >> 2, sk = (tid & 3) << 3;       // each thread stages 16B of A and B
  const int wv = tid >> 6, lane = tid & 63, q = lane >> 4, m16 = lane & 15;
  const int wr = (wv >> 2) << 6;        // 0 / 64
  const int wc = (wv & 3) << 5;         // 0,32,64,96
  const u16* arow = (XMODE == 2) ? (Xb + (size_t)rows[sr] * K) : (Xb + (size_t)(bm + sr) * K);
  const u16* brow = W + (size_t)(bn + sr) * K;
  f32x4 acc[4][2];
  #pragma unroll
  for (int m = 0; m < 4; ++m)
    #pragma unroll
    for (int n = 0; n < 2; ++n)
      #pragma unroll
      for (int i = 0; i < 4; ++i) acc[m][n][i] = 0.f;

  // prologue: stage tile 0
  uint4 ar = *(const uint4*)(arow + sk);
  uint4 br = *(const uint4*)(brow + sk);
  *(uint4*)&As[0][sr][sk] = ar;
  *(uint4*)&Bs[0][sr][sk] = br;
  __syncthreads();
  int cur = 0;
  for (int k0 = 0; k0 < K; k0 += 32) {
    if (k0 + 32 < K) {               // prefetch next tile into regs (overlaps compute)
      ar = *(const uint4*)(arow + k0 + 32 + sk);
      br = *(const uint4*)(brow + k0 + 32 + sk);
    }
    short8 af[4];
    #pragma unroll
    for (int m = 0; m < 4; ++m)
      af[m] = *(const short8*)&As[cur][wr + m * 16 + m16][q * 8];
    short8 bf[2];
    #pragma unroll
    for (int n = 0; n < 2; ++n)
      bf[n] = *(const short8*)&Bs[cur][wc + n * 16 + m16][q * 8];
    #pragma unroll
    for (int n = 0; n < 2; ++n)
      #pragma unroll
      for (int m = 0; m < 4; ++m)
        acc[m][n] = __builtin_amdgcn_mfma_f32_16x16x32_bf16(af[m], bf[n], acc[m][n], 0, 0, 0);
    if (k0 + 32 < K) {
      *(uint4*)&As[cur ^ 1][sr][sk] = ar;
      *(uint4*)&Bs[cur ^ 1][sr][sk] = br;
      __syncthreads();
      cur ^= 1;
    }
  }
  // epilogue: frag (m,n): D[row=q*4+i][col=m16] at tile offset (wr+m*16, wc+n*16)
  #pragma unroll
  for (int n = 0; n < 2; ++n) {
    int col = bn + wc + n * 16 + m16;
    float bb = bias[col];
    #pragma unroll
    for (int m = 0; m < 4; ++m) {
      #pragma unroll
      for (int i = 0; i < 4; ++i) {
        int rl = bm + wr + m * 16 + q * 4 + i;
        if (EXPERT == 1 && rl >= Mloc) continue;
        float v = acc[m][n][i] + bb;
        if (ACT == 1) v = v / (1.f + expf(-v));
        if (OUTMODE == 0) C[(size_t)rl * N + col] = v;
        else if (OUTMODE == 1) C[(size_t)rl * N + col] += v;
        else if (OUTMODE == 2) C16[(size_t)rl * N + col] = f2b(v);
        else if (OUTMODE == 3) {
          int rg = chunk0 + rl;
          int tok = toklist[e * 8192 + rg] & 8191;
          float wt = wlist[e * 8192 + rg];
          atomicAdd(&moe[(size_t)tok * 512 + col], v * wt);
        } else {  // OUTMODE == 4: dense atomic accumulate
          atomicAdd(&C[(size_t)rl * N + col], v);
        }
      }
    }
  }
}

// ---- halt head ----
__global__ __launch_bounds__(256) void k_halt(const u16* __restrict__ hh, const float* __restrict__ hW2,
                                              const float* __restrict__ hb2, float* __restrict__ out) {
  int lane = threadIdx.x & 63, wid = threadIdx.x >> 6;
  int t = blockIdx.x * 4 + wid;
  const u16* x = hh + (size_t)t * 256;
  float a = b2f(x[lane]) * hW2[lane] + b2f(x[lane + 64]) * hW2[lane + 64] +
            b2f(x[lane + 128]) * hW2[lane + 128] + b2f(x[lane + 192]) * hW2[lane + 192];
  #pragma unroll
  for (int off = 32; off; off >>= 1) a += __shfl_xor(a, off);
  if (lane == 0) {
    float p = 1.f / (1.f + expf(-(a + hb2[0])));
    out[4194304 + t] = p;
    out[4194304 + 8192 + t] = p;
  }
}

// ---- scalar: stab + aux loss ----
__global__ __launch_bounds__(256) void k_final(const float* __restrict__ probs, const int* __restrict__ cnt,
                                               const float* __restrict__ lA, float* __restrict__ out) {
  __shared__ float sp[4][8];
  __shared__ float sm[4];
  int tid = threadIdx.x, lane = tid & 63, wid = tid >> 6;
  float part[8] = {};
  for (int i = tid; i < 8192; i += 256) {
    const float* p = probs + i * 8;
    #pragma unroll
    for (int e = 0; e < 8; ++e) part[e] += p[e];
  }
  #pragma unroll
  for (int off = 32; off; off >>= 1)
    #pragma unroll
    for (int e = 0; e < 8; ++e) part[e] += __shfl_xor(part[e], off);
  float mx = 0.f;
  for (int d = tid; d < 512; d += 256) mx = fmaxf(mx, expf(lA[d]));
  #pragma unroll
  for (int off = 32; off; off >>= 1) mx = fmaxf(mx, __shfl_xor(mx, off));
  if (lane == 0) {
    #pragma unroll
    for (int e = 0; e < 8; ++e) sp[wid][e] = part[e];
    sm[wid] = mx;
  }
  __syncthreads();
  if (tid == 0) {
    float loss = 0.f;
    for (int e = 0; e < 8; ++e) {
      float pm = (sp[0][e] + sp[1][e] + sp[2][e] + sp[3][e]) * (1.f / 8192.f);
      int c = cnt[e]; if (c > 8192) c = 8192;
      loss += (float)c * (1.f / 8192.f) * pm;
    }
    loss *= 0.01f * 8.f;
    float mall = fmaxf(fmaxf(sm[0], sm[1]), fmaxf(sm[2], sm[3]));
    out[4194304 + 16384] = fmaxf(mall - 0.95f, 0.f) + loss;
  }
}

extern "C" void kernel_launch(void* const* d_in, const int* in_sizes, int n_in,
                              void* d_out, int out_size, void* d_ws, size_t ws_size,
                              hipStream_t stream) {
  const float* h   = (const float*)d_in[0];
  const float* ef  = (const float*)d_in[1];
  const float* lA  = (const float*)d_in[2];
  const float* Bw  = (const float*)d_in[3];
  const float* Bb  = (const float*)d_in[4];
  const float* Wq  = (const float*)d_in[5];  const float* bq  = (const float*)d_in[6];
  const float* Wk  = (const float*)d_in[7];  const float* bk  = (const float*)d_in[8];
  const float* Wv  = (const float*)d_in[9];  const float* bv  = (const float*)d_in[10];
  const float* Wo  = (const float*)d_in[11]; const float* bo  = (const float*)d_in[12];
  const float* n1g = (const float*)d_in[13]; const float* n1b = (const float*)d_in[14];
  const float* n2g = (const float*)d_in[15]; const float* n2b = (const float*)d_in[16];
  const float* n3g = (const float*)d_in[17]; const float* n3b = (const float*)d_in[18];
  const float* gw  = (const float*)d_in[19]; const float* gb  = (const float*)d_in[20];
  const float* eW1 = (const float*)d_in[21]; const float* eb1 = (const float*)d_in[22];
  const float* eW2 = (const float*)d_in[23]; const float* eb2 = (const float*)d_in[24];
  const float* sW1 = (const float*)d_in[25]; const float* sb1 = (const float*)d_in[26];
  const float* sW2 = (const float*)d_in[27]; const float* sb2 = (const float*)d_in[28];
  const float* hW1 = (const float*)d_in[29]; const float* hb1 = (const float*)d_in[30];
  const float* hW2 = (const float*)d_in[31]; const float* hb2 = (const float*)d_in[32];
  float* out = (float*)d_out;
  float* ws = (float*)d_ws;

  // ---- tiered workspace layout ----
  const size_t R = (size_t)TT * DD;   // 4,194,304 floats
  const size_t SM = 155648 + 73744;
  size_t wsf = ws_size / 4;
  int S; size_t ARENA;
  bool FAST;
  if (wsf >= 6 * R + SM)      { S = 8192; ARENA = 4 * R; FAST = true; }
  else if (wsf >= 3 * R + SM) { S = 2048; ARENA = R; FAST = false; }
  else                        { S = 512;  ARENA = 1048576; FAST = false; }
  const int CAPE = (int)(ARENA / 4096);
  const int NCH  = 8192 / CAPE;
  const size_t HIDSTRIDE = (size_t)CAPE * 1024;
  const int CAPS = (ARENA / 512 >= 8192) ? 8192 : (int)(ARENA / 512);

  float* f_h2  = ws;
  float* f_moe = ws + R;
  float* arena = ws + 2 * R;
  const size_t SD = (size_t)S * 512;
  u16* f_xh = (u16*)arena;
  u16* f_xl = f_xh + SD;
  float* f_q = arena + SD;
  float* f_k = arena + 2 * SD;
  float* f_v = arena + 3 * SD;
  u16* f_aohl = (u16*)f_q;
  float* f_hp = f_k;
  u16* f_wh = (u16*)f_moe;             // [4][512][512] split QKV/Wo weights (hi)
  u16* f_wl = f_wh + 4 * 262144;       // (lo)
  u16* f_hid = (u16*)arena;            // old-path hid
  u16* f_hh  = (u16*)arena;
  // FAST-path arena carve (u16 indices into arena; arena = 4R floats = 8R u16):
  //   hid   [0, 16777216)        shared: 2 x [8192][1024]; routed: 8 x [2048][1024]
  //   eW1t  [16777216, 20971520) over dead hp region
  //   eW2t  [20971520, 25165824)
  //   h2b   [25165824, 29360128) over dead v region (written by ln_res2)
  //   sW1t  [29360128, 30408704)
  //   sW2t  [30408704, 31457280)
  u16* a16 = (u16*)arena;
  const int CAPE_F = 2048, NCH_F = 4;
  const size_t HSF = (size_t)CAPE_F * 1024;
  u16* f_hidF = a16;
  u16* f_eW1t = a16 + 16777216;
  u16* f_eW2t = a16 + 20971520;
  u16* f_h2b  = a16 + 25165824;
  u16* f_sW1t = a16 + 29360128;
  u16* f_sW2t = a16 + 30408704;
  float* smr = ws + 2 * R + ARENA;
  float* f_esum = smr;
  float* f_einj = smr + 4096;
  float* f_probs = smr + 8192;
  float2* f_wpair = (float2*)(smr + 8192 + 65536);
  float* f_wlist = smr + 8192 + 65536 + 16384;
  int* ip = (int*)(smr + 8192 + 65536 + 16384 + 65536);
  int* sel = ip; int* cnt = ip + 8192; int* toklist = ip + 8192 + 16;

  // ---- LTI prep + QKV weight split ----
  k_zero<<<16, 256, 0, stream>>>(f_esum);
  k_esum<<<dim3(8, 32), 256, 0, stream>>>(ef, f_esum);
  k_einj<<<16, 256, 0, stream>>>(f_esum, Bw, Bb, f_einj);
  k_wsplit<<<dim3(8, 8, 4), 256, 0, stream>>>(Wq, Wk, Wv, Wo, f_wh, f_wl);

  // ---- LTI + attention ----
  for (int s = 0; s < TT / S; ++s) {
    int seg0 = s * S;
    k_lti<<<S, 256, 0, stream>>>(h, lA, f_einj, n1g, n1b, f_xh, f_xl, seg0);
    gemm_sp2<3><<<dim3(4, S / 128, 3), 256, 0, stream>>>(
        f_xh, f_xl, 512, f_wh, f_wl, bq, bk, bv, f_q, f_k, f_v);
    k_attn<<<S, 64, 0, stream>>>(f_q, f_k, f_v, f_aohl);
    gemm_sp2<1><<<dim3(4, S / 128, 1), 256, 0, stream>>>(
        f_aohl, f_aohl + 512, 1024, f_wh + 3 * 262144, f_wl + 3 * 262144,
        bo, nullptr, nullptr, f_hp, nullptr, nullptr);
    k_ln_res2<<<S, 256, 0, stream>>>(f_xh, f_xl, f_hp, n2g, n2b,
                                     f_h2 + (size_t)seg0 * 512,
                                     FAST ? f_h2b + (size_t)seg0 * 512 : nullptr);
  }

  // ---- gate ----
  k_gateA<<<TT / 4, 256, 0, stream>>>(f_h2, gw, gb, f_probs, sel, f_wpair);
  k_gateB<<<8, 256, 0, stream>>>(sel, f_wpair, toklist, f_wlist, cnt);

  if (FAST) {
    // ---- zero moe (all expert outputs accumulate atomically) + convert weights ----
    k_zero4<<<4096, 256, 0, stream>>>((float4*)f_moe);
    k_wt<<<dim3(8, 16, 8), 256, 0, stream>>>(eW1, f_eW1t, 512, 1024);
    k_wt<<<dim3(16, 8, 8), 256, 0, stream>>>(eW2, f_eW2t, 1024, 512);
    k_wt<<<dim3(8, 16, 2), 256, 0, stream>>>(sW1, f_sW1t, 512, 1024);
    k_wt<<<dim3(16, 8, 2), 256, 0, stream>>>(sW2, f_sW2t, 1024, 512);

    // ---- shared experts: both in one dispatch via z (dense-z mode) ----
    // W1: input is DENSE h2b (XMODE=1, no input offset); hid output per-z (OUTMODE=2 offset)
    mfma_gemm3<1,1,2,2><<<dim3(8, 64, 2), 512, 0, stream>>>(
        f_h2b, f_sW1t, sb1, nullptr, f_hidF, nullptr, nullptr, nullptr,
        TT, 512, 1024, 0, (size_t)TT * 1024, nullptr);
    // W2: input is PER-Z hid (XMODE=3 offset); dense atomic accumulate into moe
    mfma_gemm3<3,0,4,2><<<dim3(4, 64, 2), 512, 0, stream>>>(
        f_hidF, f_sW2t, sb2, f_moe, nullptr, nullptr, nullptr, nullptr,
        TT, 1024, 512, 0, (size_t)TT * 1024, nullptr);

    // ---- routed experts: gathered bf16 GEMMs, chunked by CAPE_F ----
    for (int c = 0; c < NCH_F; ++c) {
      mfma_gemm3<2,1,2,1><<<dim3(8, CAPE_F / 128, 8), 512, 0, stream>>>(
          f_h2b, f_eW1t, eb1, nullptr, f_hidF, toklist, nullptr, cnt,
          CAPE_F, 512, 1024, c * CAPE_F, HSF, nullptr);
      mfma_gemm3<3,0,3,1><<<dim3(4, CAPE_F / 128, 8), 512, 0, stream>>>(
          f_hidF, f_eW2t, eb2, nullptr, nullptr, toklist, f_wlist, cnt,
          CAPE_F, 1024, 512, c * CAPE_F, HSF, f_moe);
    }
  } else {
    // ---- old path (small workspace tiers) ----
    for (int sx = 0; sx < 2; ++sx)
      for (int c = 0; c < TT / CAPS; ++c) {
        const float* xs = f_h2 + (size_t)c * CAPS * 512;
        float* ms = f_moe + (size_t)c * CAPS * 512;
        mfma_gemm<0,1,2,0><<<dim3(16, CAPS / 64), 256, 0, stream>>>(
            xs, nullptr, sW1 + (size_t)sx * 524288, sb1 + sx * 1024,
            nullptr, f_hid, nullptr, nullptr, nullptr, CAPS, 512, 1024, 0, 0, nullptr);
        if (sx == 0)
          mfma_gemm<1,0,0,0><<<dim3(8, CAPS / 64), 256, 0, stream>>>(
              nullptr, f_hid, sW2, sb2, ms, nullptr, nullptr, nullptr, nullptr, CAPS, 1024, 512, 0, 0, nullptr);
        else
          mfma_gemm<1,0,1,0><<<dim3(8, CAPS / 64), 256, 0, stream>>>(
              nullptr, f_hid, sW2 + 524288, sb2 + 512, ms, nullptr, nullptr, nullptr, nullptr, CAPS, 1024, 512, 0, 0, nullptr);
      }
    for (int c = 0; c < NCH; ++c) {
      mfma_gemm<2,1,2,1><<<dim3(16, CAPE / 64, 8), 256, 0, stream>>>(
          f_h2, nullptr, eW1, eb1, nullptr, f_hid, toklist, nullptr, cnt,
          CAPE, 512, 1024, c * CAPE, HIDSTRIDE, nullptr);
      mfma_gemm<1,0,3,1><<<dim3(8, CAPE / 64, 8), 256, 0, stream>>>(
          nullptr, f_hid, eW2, eb2, nullptr, nullptr, toklist, f_wlist, cnt,
          CAPE, 1024, 512, c * CAPE, HIDSTRIDE, f_moe);
    }
  }

  // ---- final LN -> out (h3 f32), halt head, scalars ----
  k_ln_res<<<TT, 256, 0, stream>>>(f_h2, f_moe, n3g, n3b, out);
  mfma_gemm<0,2,2,0><<<dim3(4, 128), 256, 0, stream>>>(
      out, nullptr, hW1, hb1, nullptr, f_hh, nullptr, nullptr, nullptr, TT, 512, 256, 0, 0, nullptr);
  k_halt<<<TT / 4, 256, 0, stream>>>(f_hh, hW2, hb2, out);
  k_final<<<1, 256, 0, stream>>>(f_probs, cnt, lA, out);
}

// Round 7
// 691.060 us; speedup vs baseline: 1.4994x; 1.0328x over previous
//
#include <hip/hip_runtime.h>
#include <hip/hip_bf16.h>

// Problem constants (B=8, N=1024, D=512, H=8, HD=64, E=4096, NE=8, NSH=2, TOPK=2, DH=1024)
// ALL inputs/outputs are float32.
#define TT 8192
#define DD 512

typedef unsigned short u16;
typedef __attribute__((ext_vector_type(8))) short short8;
typedef __attribute__((ext_vector_type(4))) float f32x4;

__device__ __forceinline__ u16 f2b(float f) {
  union { float f; unsigned int i; } w; w.f = f;
  unsigned int x = w.i;
  unsigned int r = (x + 0x7FFFu + ((x >> 16) & 1u)) >> 16;
  if ((x & 0x7F800000u) == 0x7F800000u) r = x >> 16;
  return (u16)r;
}
__device__ __forceinline__ float b2f(u16 u) {
  union { unsigned int i; float f; } w; w.i = ((unsigned int)u) << 16; return w.f;
}

__device__ __forceinline__ void blockReduce2(float& a, float& b, float* s4a, float* s4b) {
  #pragma unroll
  for (int off = 32; off; off >>= 1) { a += __shfl_xor(a, off); b += __shfl_xor(b, off); }
  int wid = threadIdx.x >> 6;
  if ((threadIdx.x & 63) == 0) { s4a[wid] = a; s4b[wid] = b; }
  __syncthreads();
  a = s4a[0] + s4a[1] + s4a[2] + s4a[3];
  b = s4b[0] + s4b[1] + s4b[2] + s4b[3];
}

// ---- zero esum ----
__global__ __launch_bounds__(256) void k_zero(float* __restrict__ esum) {
  esum[blockIdx.x * 256 + threadIdx.x] = 0.f;
}

// ---- zero float4 (big buffers) ----
__global__ __launch_bounds__(256) void k_zero4(float4* __restrict__ p) {
  p[(size_t)blockIdx.x * 256 + threadIdx.x] = make_float4(0.f, 0.f, 0.f, 0.f);
}

// ---- edge sum: [B,E,D] -> [B,D] ----
__global__ __launch_bounds__(256) void k_esum(const float* __restrict__ ef, float* __restrict__ esum) {
  int b = blockIdx.x, ec = blockIdx.y, tid = threadIdx.x;
  float a0 = 0.f, a1 = 0.f;
  const float* base = ef + ((size_t)b * 4096 + (size_t)ec * 128) * 512;
  for (int e = 0; e < 128; ++e) {
    a0 += base[(size_t)e * 512 + tid];
    a1 += base[(size_t)e * 512 + tid + 256];
  }
  atomicAdd(&esum[b * 512 + tid], a0);
  atomicAdd(&esum[b * 512 + tid + 256], a1);
}

// ---- einj[b,dp] = (esum[b,:]/E) @ B_w[:,dp] + B_b[dp] ----
__global__ __launch_bounds__(256) void k_einj(const float* __restrict__ esum,
                                              const float* __restrict__ Bw, const float* __restrict__ Bb,
                                              float* __restrict__ einj) {
  int idx = blockIdx.x * 256 + threadIdx.x;
  int b = idx >> 9, dp = idx & 511;
  float a = Bb[dp];
  const float inv = 1.f / 4096.f;
  for (int d = 0; d < 512; ++d)
    a = fmaf(esum[b * 512 + d] * inv, Bw[d * 512 + dp], a);
  einj[idx] = a;
}

// ---- weight transpose + hi/lo bf16 split: W[512][512] -> Wt{h,l}[z][n][k] ----
__global__ __launch_bounds__(256) void k_wsplit(const float* __restrict__ Wq, const float* __restrict__ Wk,
                                                const float* __restrict__ Wv, const float* __restrict__ Wo,
                                                u16* __restrict__ outh, u16* __restrict__ outl) {
  __shared__ float st[64][65];
  int z = blockIdx.z;
  const float* W = z == 0 ? Wq : (z == 1 ? Wk : (z == 2 ? Wv : Wo));
  int k0 = blockIdx.x << 6, n0 = blockIdx.y << 6;
  int tid = threadIdx.x;
  int r = tid >> 2, c4 = (tid & 3) << 4;
  #pragma unroll
  for (int j = 0; j < 16; j += 4) {
    float4 v = *(const float4*)(W + (size_t)(k0 + r) * 512 + n0 + c4 + j);
    st[c4 + j + 0][r] = v.x; st[c4 + j + 1][r] = v.y;
    st[c4 + j + 2][r] = v.z; st[c4 + j + 3][r] = v.w;
  }
  __syncthreads();
  int n = tid >> 2, kb = (tid & 3) << 4;
  u16 h8[8] __attribute__((aligned(16)));
  u16 l8[8] __attribute__((aligned(16)));
  size_t obase = (size_t)z * 262144 + (size_t)(n0 + n) * 512 + k0 + kb;
  #pragma unroll
  for (int half = 0; half < 2; ++half) {
    #pragma unroll
    for (int j = 0; j < 8; ++j) {
      float val = st[n][kb + half * 8 + j];
      h8[j] = f2b(val);
      l8[j] = f2b(val - b2f(h8[j]));
    }
    *(uint4*)(outh + obase + half * 8) = *(uint4*)h8;
    *(uint4*)(outl + obase + half * 8) = *(uint4*)l8;
  }
}

// ---- generic weight transpose -> bf16 [n][k] (per-expert via blockIdx.z) ----
__global__ __launch_bounds__(256) void k_wt(const float* __restrict__ W, u16* __restrict__ Wt,
                                            int K, int N) {
  __shared__ float st[64][65];
  int z = blockIdx.z;
  W += (size_t)z * K * N; Wt += (size_t)z * K * N;
  int k0 = blockIdx.x << 6, n0 = blockIdx.y << 6;
  int tid = threadIdx.x;
  int r = tid >> 2, c4 = (tid & 3) << 4;
  #pragma unroll
  for (int j = 0; j < 16; j += 4) {
    float4 v = *(const float4*)(W + (size_t)(k0 + r) * N + n0 + c4 + j);
    st[c4 + j + 0][r] = v.x; st[c4 + j + 1][r] = v.y;
    st[c4 + j + 2][r] = v.z; st[c4 + j + 3][r] = v.w;
  }
  __syncthreads();
  int n = tid >> 2, kb = (tid & 3) << 4;
  u16 h8[8] __attribute__((aligned(16)));
  size_t obase = (size_t)(n0 + n) * K + k0 + kb;
  #pragma unroll
  for (int half = 0; half < 2; ++half) {
    #pragma unroll
    for (int j = 0; j < 8; ++j) h8[j] = f2b(st[n][kb + half * 8 + j]);
    *(uint4*)(Wt + obase + half * 8) = *(uint4*)h8;
  }
}

// ---- h_lti = LN(-exp(log_A)*h + einj) -> hi/lo bf16 (segment-local) ----
__global__ __launch_bounds__(256) void k_lti(const float* __restrict__ h, const float* __restrict__ lA,
                                             const float* __restrict__ einj,
                                             const float* __restrict__ g, const float* __restrict__ be,
                                             u16* __restrict__ Xh, u16* __restrict__ Xl, int seg0) {
  __shared__ float sa[4], sb[4];
  int rowg = seg0 + blockIdx.x, b = rowg >> 10, tid = threadIdx.x;
  int d0 = tid, d1 = tid + 256;
  size_t gbase = (size_t)rowg * 512;
  size_t lbase = (size_t)blockIdx.x * 512;
  float v0 = -expf(lA[d0]) * h[gbase + d0] + einj[b * 512 + d0];
  float v1 = -expf(lA[d1]) * h[gbase + d1] + einj[b * 512 + d1];
  float s = v0 + v1, ss = v0 * v0 + v1 * v1;
  blockReduce2(s, ss, sa, sb);
  float mu = s * (1.f / 512.f);
  float var = fmaxf(ss * (1.f / 512.f) - mu * mu, 0.f);
  float r = rsqrtf(var + 1e-5f);
  float o0 = (v0 - mu) * r * g[d0] + be[d0];
  float o1 = (v1 - mu) * r * g[d1] + be[d1];
  u16 h0 = f2b(o0), h1 = f2b(o1);
  Xh[lbase + d0] = h0; Xl[lbase + d0] = f2b(o0 - b2f(h0));
  Xh[lbase + d1] = h1; Xl[lbase + d1] = f2b(o1 - b2f(h1));
}

// ---- residual LN: LN(recon(Xh,Xl) + Bv) -> f32 (+ optional bf16 copy) ----
__global__ __launch_bounds__(256) void k_ln_res2(const u16* __restrict__ Xh, const u16* __restrict__ Xl,
                                                 const float* __restrict__ Bv,
                                                 const float* __restrict__ g, const float* __restrict__ be,
                                                 float* __restrict__ outf, u16* __restrict__ outb) {
  __shared__ float sa[4], sb[4];
  int tid = threadIdx.x, d0 = tid, d1 = tid + 256;
  size_t base = (size_t)blockIdx.x * 512;
  float v0 = b2f(Xh[base + d0]) + b2f(Xl[base + d0]) + Bv[base + d0];
  float v1 = b2f(Xh[base + d1]) + b2f(Xl[base + d1]) + Bv[base + d1];
  float s = v0 + v1, ss = v0 * v0 + v1 * v1;
  blockReduce2(s, ss, sa, sb);
  float mu = s * (1.f / 512.f);
  float var = fmaxf(ss * (1.f / 512.f) - mu * mu, 0.f);
  float r = rsqrtf(var + 1e-5f);
  float o0 = (v0 - mu) * r * g[d0] + be[d0];
  float o1 = (v1 - mu) * r * g[d1] + be[d1];
  outf[base + d0] = o0;
  outf[base + d1] = o1;
  if (outb) { outb[base + d0] = f2b(o0); outb[base + d1] = f2b(o1); }
}

// ---- residual LN (both f32, optional bf16 copy) ----
__global__ __launch_bounds__(256) void k_ln_res(const float* __restrict__ A, const float* __restrict__ Bv,
                                                const float* __restrict__ g, const float* __restrict__ be,
                                                float* __restrict__ outf, u16* __restrict__ outb) {
  __shared__ float sa[4], sb[4];
  int tid = threadIdx.x, d0 = tid, d1 = tid + 256;
  size_t base = (size_t)blockIdx.x * 512;
  float v0 = A[base + d0] + Bv[base + d0];
  float v1 = A[base + d1] + Bv[base + d1];
  float s = v0 + v1, ss = v0 * v0 + v1 * v1;
  blockReduce2(s, ss, sa, sb);
  float mu = s * (1.f / 512.f);
  float var = fmaxf(ss * (1.f / 512.f) - mu * mu, 0.f);
  float r = rsqrtf(var + 1e-5f);
  float o0 = (v0 - mu) * r * g[d0] + be[d0];
  float o1 = (v1 - mu) * r * g[d1] + be[d1];
  outf[base + d0] = o0;
  outf[base + d1] = o1;
  if (outb) { outb[base + d0] = f2b(o0); outb[base + d1] = f2b(o1); }
}

// ---- split-precision MFMA GEMM v3: 128x128 tile, 8 waves (512 thr), double-buffered LDS,
//      register prefetch, ONE barrier per K-step. Wave owns 64x32 (4x2 frags x 3 MFMA).
// Math identical to gemm_sp2 (Xh.Wh + Xl.Wh + Xh.Wl, f32 accum). K=N=512 fixed.
template<int NOUT>
__global__ __launch_bounds__(512, 4) void gemm_sp3(
    const u16* __restrict__ Xh, const u16* __restrict__ Xl, int lda,
    const u16* __restrict__ Wth, const u16* __restrict__ Wtl,
    const float* __restrict__ b0c, const float* __restrict__ b1c, const float* __restrict__ b2c,
    float* __restrict__ C0, float* __restrict__ C1, float* __restrict__ C2) {
  const float* bias = b0c; float* C = C0;
  const u16* Wh = Wth; const u16* Wl = Wtl;
  if (NOUT == 3) {
    int z = blockIdx.z;
    Wh += (size_t)z * 262144; Wl += (size_t)z * 262144;
    if (z == 1) { bias = b1c; C = C1; }
    else if (z == 2) { bias = b2c; C = C2; }
  }
  const int bm = blockIdx.y << 7, bn = blockIdx.x << 7;
  __shared__ u16 Ah[2][128][40];
  __shared__ u16 Al[2][128][40];
  __shared__ u16 Bh[2][128][40];
  __shared__ u16 Bl[2][128][40];
  const int tid = threadIdx.x;
  const int sr = tid >> 2, sk = (tid & 3) << 3;
  const int wv = tid >> 6, lane = tid & 63, q = lane >> 4, m16 = lane & 15;
  const int wr = (wv >> 2) << 6;   // 0 / 64
  const int wc = (wv & 3) << 5;    // 0,32,64,96
  const u16* ahr = Xh + (size_t)(bm + sr) * lda;
  const u16* alr = Xl + (size_t)(bm + sr) * lda;
  const u16* bhr = Wh + (size_t)(bn + sr) * 512;
  const u16* blr = Wl + (size_t)(bn + sr) * 512;
  f32x4 acc[4][2];
  #pragma unroll
  for (int m = 0; m < 4; ++m)
    #pragma unroll
    for (int n = 0; n < 2; ++n)
      #pragma unroll
      for (int i = 0; i < 4; ++i) acc[m][n][i] = 0.f;

  uint4 rah = *(const uint4*)(ahr + sk);
  uint4 ral = *(const uint4*)(alr + sk);
  uint4 rbh = *(const uint4*)(bhr + sk);
  uint4 rbl = *(const uint4*)(blr + sk);
  *(uint4*)&Ah[0][sr][sk] = rah;
  *(uint4*)&Al[0][sr][sk] = ral;
  *(uint4*)&Bh[0][sr][sk] = rbh;
  *(uint4*)&Bl[0][sr][sk] = rbl;
  __syncthreads();
  int cur = 0;
  for (int k0 = 0; k0 < 512; k0 += 32) {
    if (k0 + 32 < 512) {             // prefetch next tile into regs (latency hides under MFMAs)
      rah = *(const uint4*)(ahr + k0 + 32 + sk);
      ral = *(const uint4*)(alr + k0 + 32 + sk);
      rbh = *(const uint4*)(bhr + k0 + 32 + sk);
      rbl = *(const uint4*)(blr + k0 + 32 + sk);
    }
    short8 ahf[4], alf[4];
    #pragma unroll
    for (int m = 0; m < 4; ++m) {
      ahf[m] = *(const short8*)&Ah[cur][wr + m * 16 + m16][q * 8];
      alf[m] = *(const short8*)&Al[cur][wr + m * 16 + m16][q * 8];
    }
    #pragma unroll
    for (int n = 0; n < 2; ++n) {
      short8 bhf = *(const short8*)&Bh[cur][wc + n * 16 + m16][q * 8];
      short8 blf = *(const short8*)&Bl[cur][wc + n * 16 + m16][q * 8];
      #pragma unroll
      for (int m = 0; m < 4; ++m) {
        acc[m][n] = __builtin_amdgcn_mfma_f32_16x16x32_bf16(ahf[m], bhf, acc[m][n], 0, 0, 0);
        acc[m][n] = __builtin_amdgcn_mfma_f32_16x16x32_bf16(alf[m], bhf, acc[m][n], 0, 0, 0);
        acc[m][n] = __builtin_amdgcn_mfma_f32_16x16x32_bf16(ahf[m], blf, acc[m][n], 0, 0, 0);
      }
    }
    if (k0 + 32 < 512) {
      *(uint4*)&Ah[cur ^ 1][sr][sk] = rah;
      *(uint4*)&Al[cur ^ 1][sr][sk] = ral;
      *(uint4*)&Bh[cur ^ 1][sr][sk] = rbh;
      *(uint4*)&Bl[cur ^ 1][sr][sk] = rbl;
      __syncthreads();
      cur ^= 1;
    }
  }
  #pragma unroll
  for (int n = 0; n < 2; ++n) {
    int col = bn + wc + n * 16 + m16;
    float bb = bias[col];
    #pragma unroll
    for (int m = 0; m < 4; ++m) {
      #pragma unroll
      for (int i = 0; i < 4; ++i) {
        int rl = bm + wr + m * 16 + q * 4 + i;
        C[(size_t)rl * 512 + col] = acc[m][n][i] + bb;
      }
    }
  }
}

// ---- per-node head attention -> per-row packed [hi(512)|lo(512)] u16, IN PLACE over q row t ----
__global__ __launch_bounds__(64) void k_attn(const float* __restrict__ q, const float* __restrict__ k,
                                             const float* __restrict__ v,
                                             u16* __restrict__ aohl) {
  __shared__ float qs[512], ks[512], vs[512], at[64];
  size_t t = blockIdx.x;
  int lane = threadIdx.x;
  for (int i = lane; i < 512; i += 64) {
    qs[i] = q[t * 512 + i]; ks[i] = k[t * 512 + i]; vs[i] = v[t * 512 + i];
  }
  __syncthreads();
  int h = lane >> 3, g = lane & 7;
  float s = 0.f;
  #pragma unroll 8
  for (int d = 0; d < 64; ++d) s = fmaf(qs[h * 64 + d], ks[g * 64 + d], s);
  s *= 0.125f;
  float m = s;
  #pragma unroll
  for (int off = 1; off < 8; off <<= 1) m = fmaxf(m, __shfl_xor(m, off));
  float ex = expf(s - m);
  float sum = ex;
  #pragma unroll
  for (int off = 1; off < 8; off <<= 1) sum += __shfl_xor(sum, off);
  at[lane] = ex / sum;
  __syncthreads();
  #pragma unroll
  for (int j = 0; j < 8; ++j) {
    int d = lane + j * 64, hh = d >> 6, hd = d & 63;
    float acc = 0.f;
    #pragma unroll
    for (int gg = 0; gg < 8; ++gg) acc = fmaf(at[hh * 8 + gg], vs[gg * 64 + hd], acc);
    u16 hi = f2b(acc);
    aohl[t * 1024 + d] = hi;
    aohl[t * 1024 + 512 + d] = f2b(acc - b2f(hi));
  }
}

// ---- gate phase A ----
__global__ __launch_bounds__(256) void k_gateA(const float* __restrict__ h2, const float* __restrict__ gw,
                                               const float* __restrict__ gb, float* __restrict__ probs,
                                               int* __restrict__ sel, float2* __restrict__ wpair) {
  int lane = threadIdx.x & 63, wid = threadIdx.x >> 6;
  int t = blockIdx.x * 4 + wid;
  const float* x = h2 + (size_t)t * 512;
  float acc[8] = {};
  for (int d = lane; d < 512; d += 64) {
    float xv = x[d];
    float4 g0 = *(const float4*)(gw + d * 8);
    float4 g1 = *(const float4*)(gw + d * 8 + 4);
    acc[0] = fmaf(xv, g0.x, acc[0]); acc[1] = fmaf(xv, g0.y, acc[1]);
    acc[2] = fmaf(xv, g0.z, acc[2]); acc[3] = fmaf(xv, g0.w, acc[3]);
    acc[4] = fmaf(xv, g1.x, acc[4]); acc[5] = fmaf(xv, g1.y, acc[5]);
    acc[6] = fmaf(xv, g1.z, acc[6]); acc[7] = fmaf(xv, g1.w, acc[7]);
  }
  #pragma unroll
  for (int off = 32; off; off >>= 1)
    #pragma unroll
    for (int e = 0; e < 8; ++e) acc[e] += __shfl_xor(acc[e], off);
  if (lane == 0) {
    float m = -1e30f;
    #pragma unroll
    for (int e = 0; e < 8; ++e) { acc[e] += gb[e]; m = fmaxf(m, acc[e]); }
    float p[8], sum = 0.f;
    #pragma unroll
    for (int e = 0; e < 8; ++e) { p[e] = expf(acc[e] - m); sum += p[e]; }
    float inv = 1.f / sum;
    #pragma unroll
    for (int e = 0; e < 8; ++e) { p[e] *= inv; probs[t * 8 + e] = p[e]; }
    int i1 = 0; float m1 = p[0];
    #pragma unroll
    for (int e = 1; e < 8; ++e) if (p[e] > m1) { m1 = p[e]; i1 = e; }
    int i2 = -1; float m2 = -1.f;
    #pragma unroll
    for (int e = 0; e < 8; ++e) if (e != i1 && p[e] > m2) { m2 = p[e]; i2 = e; }
    if (i2 < 0) i2 = (i1 + 1) & 7;
    float den = m1 + m2;
    float invs = (den > 0.f) ? 1.f / den : 0.f;
    sel[t] = i1 | (i2 << 4);
    wpair[t] = make_float2(m1 * invs, m2 * invs);
  }
}

// ---- gate phase B ----
__global__ __launch_bounds__(256) void k_gateB(const int* __restrict__ sel, const float2* __restrict__ wpair,
                                               int* __restrict__ toklist, float* __restrict__ wlist,
                                               int* __restrict__ cnt) {
  int e = blockIdx.x;
  int tid = threadIdx.x, lane = tid & 63, wv = tid >> 6;
  __shared__ int wsum[4];
  int base = 0;
  for (int t0 = 0; t0 < 8192; t0 += 256) {
    int t = t0 + tid;
    int s = sel[t];
    int i1 = s & 15, i2 = (s >> 4) & 15;
    bool f = (i1 == e) || (i2 == e);
    float wt = (i1 == e) ? wpair[t].x : ((i2 == e) ? wpair[t].y : 0.f);
    unsigned long long m = __ballot(f);
    int rank = __popcll(m & ((1ull << lane) - 1ull));
    int wtot = __popcll(m);
    if (lane == 0) wsum[wv] = wtot;
    __syncthreads();
    int prev = 0;
    for (int ww = 0; ww < wv; ++ww) prev += wsum[ww];
    int tot = wsum[0] + wsum[1] + wsum[2] + wsum[3];
    if (f) {
      int pos = base + prev + rank;
      toklist[e * 8192 + pos] = t;
      wlist[e * 8192 + pos] = wt;
    }
    base += tot;
    __syncthreads();
  }
  if (tid == 0) cnt[e] = base;
}

// ---- OLD MFMA bf16 GEMM: 64x64 tile (kept for small-workspace tiers) ----
template<int XMODE, int ACT, int OUTMODE, int EXPERT>
__global__ __launch_bounds__(256) void mfma_gemm(
    const float* __restrict__ Xf, const u16* __restrict__ Xb,
    const float* __restrict__ Wg, const float* __restrict__ biasg,
    float* __restrict__ C, u16* __restrict__ C16,
    const int* __restrict__ toklist, const float* __restrict__ wlist,
    const int* __restrict__ cnt, int M, int K, int N, int chunk0,
    size_t hidstride, float* __restrict__ moe) {
  int e = EXPERT ? blockIdx.z : 0;
  const float* W = Wg + (size_t)e * K * N;
  const float* bias = biasg + (size_t)e * N;
  int Mloc = M;
  if (EXPERT) {
    int ce = cnt[e]; if (ce > 8192) ce = 8192;
    Mloc = ce - chunk0;
    if (XMODE == 1) Xb += (size_t)e * hidstride;
    if (OUTMODE == 2) C16 += (size_t)e * hidstride;
  }
  const int bm = blockIdx.y << 6, bn = blockIdx.x << 6;
  if (EXPERT && bm >= Mloc) return;
  __shared__ u16 As[64][40];
  __shared__ u16 Bs[64][40];
  __shared__ int rows[64];
  const int tid = threadIdx.x;
  if (EXPERT && XMODE == 2 && tid < 64) {
    int ce = cnt[e]; if (ce > 8192) ce = 8192;
    int r = chunk0 + bm + tid;
    rows[tid] = toklist[e * 8192 + (r < ce ? r : chunk0)] & 8191;
  }
  const int srow = tid >> 2;
  const int skg = (tid & 3) << 3;
  const int wv = tid >> 6, lane = tid & 63, q = lane >> 4, m16 = lane & 15;
  f32x4 acc[4];
  #pragma unroll
  for (int c = 0; c < 4; ++c)
    #pragma unroll
    for (int i = 0; i < 4; ++i) acc[c][i] = 0.f;

  for (int k0 = 0; k0 < K; k0 += 32) {
    __syncthreads();
    {
      u16 a8[8] __attribute__((aligned(16)));
      if (XMODE == 1) {
        *(uint4*)a8 = *(const uint4*)(Xb + (size_t)(bm + srow) * K + k0 + skg);
      } else {
        const float* src = (XMODE == 2) ? (Xf + (size_t)rows[srow] * K + k0 + skg)
                                        : (Xf + (size_t)(bm + srow) * K + k0 + skg);
        float4 x0 = *(const float4*)(src);
        float4 x1 = *(const float4*)(src + 4);
        a8[0] = f2b(x0.x); a8[1] = f2b(x0.y); a8[2] = f2b(x0.z); a8[3] = f2b(x0.w);
        a8[4] = f2b(x1.x); a8[5] = f2b(x1.y); a8[6] = f2b(x1.z); a8[7] = f2b(x1.w);
      }
      *(uint4*)&As[srow][skg] = *(uint4*)a8;
    }
    {
      u16 b8[8] __attribute__((aligned(16)));
      const float* src = W + (size_t)(k0 + skg) * N + bn + srow;
      #pragma unroll
      for (int j = 0; j < 8; ++j) b8[j] = f2b(src[(size_t)j * N]);
      *(uint4*)&Bs[srow][skg] = *(uint4*)b8;
    }
    __syncthreads();
    short8 af = *(const short8*)&As[wv * 16 + m16][q * 8];
    #pragma unroll
    for (int c = 0; c < 4; ++c) {
      short8 bf = *(const short8*)&Bs[c * 16 + m16][q * 8];
      acc[c] = __builtin_amdgcn_mfma_f32_16x16x32_bf16(af, bf, acc[c], 0, 0, 0);
    }
  }
  #pragma unroll
  for (int c = 0; c < 4; ++c) {
    int col = bn + c * 16 + m16;
    float bb = bias[col];
    #pragma unroll
    for (int i = 0; i < 4; ++i) {
      int rl = bm + wv * 16 + q * 4 + i;
      if (EXPERT && rl >= Mloc) continue;
      float v = acc[c][i] + bb;
      if (ACT == 1) v = v / (1.f + expf(-v));
      else if (ACT == 2) v = tanhf(v);
      if (OUTMODE == 0) C[(size_t)rl * N + col] = v;
      else if (OUTMODE == 1) C[(size_t)rl * N + col] += v;
      else if (OUTMODE == 2) C16[(size_t)rl * N + col] = f2b(v);
      else {
        int rg = chunk0 + rl;
        int tok = toklist[e * 8192 + rg] & 8191;
        float wt = wlist[e * 8192 + rg];
        atomicAdd(&moe[(size_t)tok * 512 + col], v * wt);
      }
    }
  }
}

// ---- FAST MFMA bf16 GEMM v3: 128x128 tile, 8 waves (512 thr), double-buffered LDS,
//      register prefetch, ONE barrier per K-step. Wave owns 64x32 (4x2 frags).
// XMODE: 1 dense bf16 (NO per-expert input offset), 2 gathered bf16 rows (toklist),
//        3 per-expert bf16 (Xb += e*hidstride)
// ACT: 0 none, 1 silu, 2 tanh
// OUTMODE: 0 f32 store, 1 f32 +=, 2 bf16 store (+e*hidstride if EXPERT), 3 weighted scatter-atomicAdd,
//          4 dense atomicAdd
// EXPERT: 0 none; 1 routed (cnt-bounded, z=expert); 2 dense-z (z offsets W/bias/hid only)
template<int XMODE, int ACT, int OUTMODE, int EXPERT>
__global__ __launch_bounds__(512, 4) void mfma_gemm3(
    const u16* __restrict__ Xb, const u16* __restrict__ Wt, const float* __restrict__ biasg,
    float* __restrict__ C, u16* __restrict__ C16,
    const int* __restrict__ toklist, const float* __restrict__ wlist,
    const int* __restrict__ cnt, int M, int K, int N, int chunk0,
    size_t hidstride, float* __restrict__ moe) {
  int e = EXPERT ? blockIdx.z : 0;
  const u16* W = Wt + (size_t)e * K * N;
  const float* bias = biasg + (size_t)e * N;
  int Mloc = M;
  if (EXPERT == 1) {
    int ce = cnt[e]; if (ce > 8192) ce = 8192;
    Mloc = ce - chunk0;
  }
  if (EXPERT) {
    if (XMODE == 3) Xb += (size_t)e * hidstride;
    if (OUTMODE == 2) C16 += (size_t)e * hidstride;
  }
  const int bm = blockIdx.y << 7, bn = blockIdx.x << 7;
  if (EXPERT == 1 && bm >= Mloc) return;
  __shared__ u16 As[2][128][40];
  __shared__ u16 Bs[2][128][40];
  __shared__ int rows[128];
  const int tid = threadIdx.x;
  if (EXPERT == 1 && XMODE == 2) {
    if (tid < 128) {
      int ce = cnt[e]; if (ce > 8192) ce = 8192;
      int r = chunk0 + bm + tid;
      rows[tid] = toklist[e * 8192 + (r < ce ? r : chunk0)] & 8191;
    }
    __syncthreads();
  }
  const int sr = tid >> 2, sk = (tid & 3) << 3;
  const int wv = tid >> 6, lane = tid & 63, q = lane >> 4, m16 = lane & 15;
  const int wr = (wv >> 2) << 6;
  const int wc = (wv & 3) << 5;
  const u16* arow = (XMODE == 2) ? (Xb + (size_t)rows[sr] * K) : (Xb + (size_t)(bm + sr) * K);
  const u16* brow = W + (size_t)(bn + sr) * K;
  f32x4 acc[4][2];
  #pragma unroll
  for (int m = 0; m < 4; ++m)
    #pragma unroll
    for (int n = 0; n < 2; ++n)
      #pragma unroll
      for (int i = 0; i < 4; ++i) acc[m][n][i] = 0.f;

  uint4 ar = *(const uint4*)(arow + sk);
  uint4 br = *(const uint4*)(brow + sk);
  *(uint4*)&As[0][sr][sk] = ar;
  *(uint4*)&Bs[0][sr][sk] = br;
  __syncthreads();
  int cur = 0;
  for (int k0 = 0; k0 < K; k0 += 32) {
    if (k0 + 32 < K) {
      ar = *(const uint4*)(arow + k0 + 32 + sk);
      br = *(const uint4*)(brow + k0 + 32 + sk);
    }
    short8 af[4];
    #pragma unroll
    for (int m = 0; m < 4; ++m)
      af[m] = *(const short8*)&As[cur][wr + m * 16 + m16][q * 8];
    short8 bf[2];
    #pragma unroll
    for (int n = 0; n < 2; ++n)
      bf[n] = *(const short8*)&Bs[cur][wc + n * 16 + m16][q * 8];
    #pragma unroll
    for (int n = 0; n < 2; ++n)
      #pragma unroll
      for (int m = 0; m < 4; ++m)
        acc[m][n] = __builtin_amdgcn_mfma_f32_16x16x32_bf16(af[m], bf[n], acc[m][n], 0, 0, 0);
    if (k0 + 32 < K) {
      *(uint4*)&As[cur ^ 1][sr][sk] = ar;
      *(uint4*)&Bs[cur ^ 1][sr][sk] = br;
      __syncthreads();
      cur ^= 1;
    }
  }
  #pragma unroll
  for (int n = 0; n < 2; ++n) {
    int col = bn + wc + n * 16 + m16;
    float bb = bias[col];
    #pragma unroll
    for (int m = 0; m < 4; ++m) {
      #pragma unroll
      for (int i = 0; i < 4; ++i) {
        int rl = bm + wr + m * 16 + q * 4 + i;
        if (EXPERT == 1 && rl >= Mloc) continue;
        float v = acc[m][n][i] + bb;
        if (ACT == 1) v = v / (1.f + expf(-v));
        else if (ACT == 2) v = tanhf(v);
        if (OUTMODE == 0) C[(size_t)rl * N + col] = v;
        else if (OUTMODE == 1) C[(size_t)rl * N + col] += v;
        else if (OUTMODE == 2) C16[(size_t)rl * N + col] = f2b(v);
        else if (OUTMODE == 3) {
          int rg = chunk0 + rl;
          int tok = toklist[e * 8192 + rg] & 8191;
          float wt = wlist[e * 8192 + rg];
          atomicAdd(&moe[(size_t)tok * 512 + col], v * wt);
        } else {
          atomicAdd(&C[(size_t)rl * N + col], v);
        }
      }
    }
  }
}

// ---- halt head ----
__global__ __launch_bounds__(256) void k_halt(const u16* __restrict__ hh, const float* __restrict__ hW2,
                                              const float* __restrict__ hb2, float* __restrict__ out) {
  int lane = threadIdx.x & 63, wid = threadIdx.x >> 6;
  int t = blockIdx.x * 4 + wid;
  const u16* x = hh + (size_t)t * 256;
  float a = b2f(x[lane]) * hW2[lane] + b2f(x[lane + 64]) * hW2[lane + 64] +
            b2f(x[lane + 128]) * hW2[lane + 128] + b2f(x[lane + 192]) * hW2[lane + 192];
  #pragma unroll
  for (int off = 32; off; off >>= 1) a += __shfl_xor(a, off);
  if (lane == 0) {
    float p = 1.f / (1.f + expf(-(a + hb2[0])));
    out[4194304 + t] = p;
    out[4194304 + 8192 + t] = p;
  }
}

// ---- scalar: stab + aux loss ----
__global__ __launch_bounds__(256) void k_final(const float* __restrict__ probs, const int* __restrict__ cnt,
                                               const float* __restrict__ lA, float* __restrict__ out) {
  __shared__ float sp[4][8];
  __shared__ float sm[4];
  int tid = threadIdx.x, lane = tid & 63, wid = tid >> 6;
  float part[8] = {};
  for (int i = tid; i < 8192; i += 256) {
    const float* p = probs + i * 8;
    #pragma unroll
    for (int e = 0; e < 8; ++e) part[e] += p[e];
  }
  #pragma unroll
  for (int off = 32; off; off >>= 1)
    #pragma unroll
    for (int e = 0; e < 8; ++e) part[e] += __shfl_xor(part[e], off);
  float mx = 0.f;
  for (int d = tid; d < 512; d += 256) mx = fmaxf(mx, expf(lA[d]));
  #pragma unroll
  for (int off = 32; off; off >>= 1) mx = fmaxf(mx, __shfl_xor(mx, off));
  if (lane == 0) {
    #pragma unroll
    for (int e = 0; e < 8; ++e) sp[wid][e] = part[e];
    sm[wid] = mx;
  }
  __syncthreads();
  if (tid == 0) {
    float loss = 0.f;
    for (int e = 0; e < 8; ++e) {
      float pm = (sp[0][e] + sp[1][e] + sp[2][e] + sp[3][e]) * (1.f / 8192.f);
      int c = cnt[e]; if (c > 8192) c = 8192;
      loss += (float)c * (1.f / 8192.f) * pm;
    }
    loss *= 0.01f * 8.f;
    float mall = fmaxf(fmaxf(sm[0], sm[1]), fmaxf(sm[2], sm[3]));
    out[4194304 + 16384] = fmaxf(mall - 0.95f, 0.f) + loss;
  }
}

extern "C" void kernel_launch(void* const* d_in, const int* in_sizes, int n_in,
                              void* d_out, int out_size, void* d_ws, size_t ws_size,
                              hipStream_t stream) {
  const float* h   = (const float*)d_in[0];
  const float* ef  = (const float*)d_in[1];
  const float* lA  = (const float*)d_in[2];
  const float* Bw  = (const float*)d_in[3];
  const float* Bb  = (const float*)d_in[4];
  const float* Wq  = (const float*)d_in[5];  const float* bq  = (const float*)d_in[6];
  const float* Wk  = (const float*)d_in[7];  const float* bk  = (const float*)d_in[8];
  const float* Wv  = (const float*)d_in[9];  const float* bv  = (const float*)d_in[10];
  const float* Wo  = (const float*)d_in[11]; const float* bo  = (const float*)d_in[12];
  const float* n1g = (const float*)d_in[13]; const float* n1b = (const float*)d_in[14];
  const float* n2g = (const float*)d_in[15]; const float* n2b = (const float*)d_in[16];
  const float* n3g = (const float*)d_in[17]; const float* n3b = (const float*)d_in[18];
  const float* gw  = (const float*)d_in[19]; const float* gb  = (const float*)d_in[20];
  const float* eW1 = (const float*)d_in[21]; const float* eb1 = (const float*)d_in[22];
  const float* eW2 = (const float*)d_in[23]; const float* eb2 = (const float*)d_in[24];
  const float* sW1 = (const float*)d_in[25]; const float* sb1 = (const float*)d_in[26];
  const float* sW2 = (const float*)d_in[27]; const float* sb2 = (const float*)d_in[28];
  const float* hW1 = (const float*)d_in[29]; const float* hb1 = (const float*)d_in[30];
  const float* hW2 = (const float*)d_in[31]; const float* hb2 = (const float*)d_in[32];
  float* out = (float*)d_out;
  float* ws = (float*)d_ws;

  // ---- tiered workspace layout ----
  const size_t R = (size_t)TT * DD;   // 4,194,304 floats
  const size_t SM = 155648 + 73744;
  size_t wsf = ws_size / 4;
  int S; size_t ARENA;
  bool FAST;
  if (wsf >= 6 * R + SM)      { S = 8192; ARENA = 4 * R; FAST = true; }
  else if (wsf >= 3 * R + SM) { S = 2048; ARENA = R; FAST = false; }
  else                        { S = 512;  ARENA = 1048576; FAST = false; }
  const int CAPE = (int)(ARENA / 4096);
  const int NCH  = 8192 / CAPE;
  const size_t HIDSTRIDE = (size_t)CAPE * 1024;
  const int CAPS = (ARENA / 512 >= 8192) ? 8192 : (int)(ARENA / 512);

  float* f_h2  = ws;
  float* f_moe = ws + R;
  float* arena = ws + 2 * R;
  const size_t SD = (size_t)S * 512;
  u16* f_xh = (u16*)arena;
  u16* f_xl = f_xh + SD;
  float* f_q = arena + SD;
  float* f_k = arena + 2 * SD;
  float* f_v = arena + 3 * SD;
  u16* f_aohl = (u16*)f_q;
  float* f_hp = f_k;
  u16* f_wh = (u16*)f_moe;             // [4][512][512] split QKV/Wo weights (hi)
  u16* f_wl = f_wh + 4 * 262144;       // (lo)
  u16* f_hid = (u16*)arena;            // old-path hid
  u16* f_hh  = (u16*)arena;            // old-path halt hid
  // FAST-path arena carve (u16 indices into arena; arena = 4R floats = 8R u16):
  //   hid   [0, 16777216)        shared: 2 x [8192][1024]; routed: 8 x [2048][1024]
  //   eW1t  [16777216, 20971520) over dead hp region
  //   eW2t  [20971520, 25165824)
  //   h2b   [25165824, 29360128) over dead v region (written by ln_res2)
  //   sW1t  [29360128, 30408704)
  //   sW2t  [30408704, 31457280)
  //   (after routed experts, hid region is dead -> halt scratch:)
  //   h3b   [0, 4194304) | hW1t [4194304, 4325376) | hh3 [4325376, 6422528)
  u16* a16 = (u16*)arena;
  const int CAPE_F = 2048, NCH_F = 4;
  const size_t HSF = (size_t)CAPE_F * 1024;
  u16* f_hidF = a16;
  u16* f_eW1t = a16 + 16777216;
  u16* f_eW2t = a16 + 20971520;
  u16* f_h2b  = a16 + 25165824;
  u16* f_sW1t = a16 + 29360128;
  u16* f_sW2t = a16 + 30408704;
  u16* f_h3b  = a16;
  u16* f_hW1t = a16 + 4194304;
  u16* f_hh3  = a16 + 4325376;
  float* smr = ws + 2 * R + ARENA;
  float* f_esum = smr;
  float* f_einj = smr + 4096;
  float* f_probs = smr + 8192;
  float2* f_wpair = (float2*)(smr + 8192 + 65536);
  float* f_wlist = smr + 8192 + 65536 + 16384;
  int* ip = (int*)(smr + 8192 + 65536 + 16384 + 65536);
  int* sel = ip; int* cnt = ip + 8192; int* toklist = ip + 8192 + 16;

  // ---- LTI prep + QKV weight split ----
  k_zero<<<16, 256, 0, stream>>>(f_esum);
  k_esum<<<dim3(8, 32), 256, 0, stream>>>(ef, f_esum);
  k_einj<<<16, 256, 0, stream>>>(f_esum, Bw, Bb, f_einj);
  k_wsplit<<<dim3(8, 8, 4), 256, 0, stream>>>(Wq, Wk, Wv, Wo, f_wh, f_wl);

  // ---- LTI + attention (v3 split-precision GEMMs) ----
  for (int s = 0; s < TT / S; ++s) {
    int seg0 = s * S;
    k_lti<<<S, 256, 0, stream>>>(h, lA, f_einj, n1g, n1b, f_xh, f_xl, seg0);
    gemm_sp3<3><<<dim3(4, S / 128, 3), 512, 0, stream>>>(
        f_xh, f_xl, 512, f_wh, f_wl, bq, bk, bv, f_q, f_k, f_v);
    k_attn<<<S, 64, 0, stream>>>(f_q, f_k, f_v, f_aohl);
    gemm_sp3<1><<<dim3(4, S / 128, 1), 512, 0, stream>>>(
        f_aohl, f_aohl + 512, 1024, f_wh + 3 * 262144, f_wl + 3 * 262144,
        bo, nullptr, nullptr, f_hp, nullptr, nullptr);
    k_ln_res2<<<S, 256, 0, stream>>>(f_xh, f_xl, f_hp, n2g, n2b,
                                     f_h2 + (size_t)seg0 * 512,
                                     FAST ? f_h2b + (size_t)seg0 * 512 : nullptr);
  }

  // ---- gate ----
  k_gateA<<<TT / 4, 256, 0, stream>>>(f_h2, gw, gb, f_probs, sel, f_wpair);
  k_gateB<<<8, 256, 0, stream>>>(sel, f_wpair, toklist, f_wlist, cnt);

  if (FAST) {
    // ---- zero moe + convert MoE weights ----
    k_zero4<<<4096, 256, 0, stream>>>((float4*)f_moe);
    k_wt<<<dim3(8, 16, 8), 256, 0, stream>>>(eW1, f_eW1t, 512, 1024);
    k_wt<<<dim3(16, 8, 8), 256, 0, stream>>>(eW2, f_eW2t, 1024, 512);
    k_wt<<<dim3(8, 16, 2), 256, 0, stream>>>(sW1, f_sW1t, 512, 1024);
    k_wt<<<dim3(16, 8, 2), 256, 0, stream>>>(sW2, f_sW2t, 1024, 512);

    // ---- shared experts (dense-z) ----
    mfma_gemm3<1,1,2,2><<<dim3(8, 64, 2), 512, 0, stream>>>(
        f_h2b, f_sW1t, sb1, nullptr, f_hidF, nullptr, nullptr, nullptr,
        TT, 512, 1024, 0, (size_t)TT * 1024, nullptr);
    mfma_gemm3<3,0,4,2><<<dim3(4, 64, 2), 512, 0, stream>>>(
        f_hidF, f_sW2t, sb2, f_moe, nullptr, nullptr, nullptr, nullptr,
        TT, 1024, 512, 0, (size_t)TT * 1024, nullptr);

    // ---- routed experts ----
    for (int c = 0; c < NCH_F; ++c) {
      mfma_gemm3<2,1,2,1><<<dim3(8, CAPE_F / 128, 8), 512, 0, stream>>>(
          f_h2b, f_eW1t, eb1, nullptr, f_hidF, toklist, nullptr, cnt,
          CAPE_F, 512, 1024, c * CAPE_F, HSF, nullptr);
      mfma_gemm3<3,0,3,1><<<dim3(4, CAPE_F / 128, 8), 512, 0, stream>>>(
          f_hidF, f_eW2t, eb2, nullptr, nullptr, toklist, f_wlist, cnt,
          CAPE_F, 1024, 512, c * CAPE_F, HSF, f_moe);
    }

    // ---- final LN (f32 out + bf16 h3b), halt head via v3 GEMM ----
    k_ln_res<<<TT, 256, 0, stream>>>(f_h2, f_moe, n3g, n3b, out, f_h3b);
    k_wt<<<dim3(8, 4, 1), 256, 0, stream>>>(hW1, f_hW1t, 512, 256);
    mfma_gemm3<1,2,2,0><<<dim3(2, 64), 512, 0, stream>>>(
        f_h3b, f_hW1t, hb1, nullptr, f_hh3, nullptr, nullptr, nullptr,
        TT, 512, 256, 0, 0, nullptr);
    k_halt<<<TT / 4, 256, 0, stream>>>(f_hh3, hW2, hb2, out);
  } else {
    // ---- old path (small workspace tiers) ----
    for (int sx = 0; sx < 2; ++sx)
      for (int c = 0; c < TT / CAPS; ++c) {
        const float* xs = f_h2 + (size_t)c * CAPS * 512;
        float* ms = f_moe + (size_t)c * CAPS * 512;
        mfma_gemm<0,1,2,0><<<dim3(16, CAPS / 64), 256, 0, stream>>>(
            xs, nullptr, sW1 + (size_t)sx * 524288, sb1 + sx * 1024,
            nullptr, f_hid, nullptr, nullptr, nullptr, CAPS, 512, 1024, 0, 0, nullptr);
        if (sx == 0)
          mfma_gemm<1,0,0,0><<<dim3(8, CAPS / 64), 256, 0, stream>>>(
              nullptr, f_hid, sW2, sb2, ms, nullptr, nullptr, nullptr, nullptr, CAPS, 1024, 512, 0, 0, nullptr);
        else
          mfma_gemm<1,0,1,0><<<dim3(8, CAPS / 64), 256, 0, stream>>>(
              nullptr, f_hid, sW2 + 524288, sb2 + 512, ms, nullptr, nullptr, nullptr, nullptr, CAPS, 1024, 512, 0, 0, nullptr);
      }
    for (int c = 0; c < NCH; ++c) {
      mfma_gemm<2,1,2,1><<<dim3(16, CAPE / 64, 8), 256, 0, stream>>>(
          f_h2, nullptr, eW1, eb1, nullptr, f_hid, toklist, nullptr, cnt,
          CAPE, 512, 1024, c * CAPE, HIDSTRIDE, nullptr);
      mfma_gemm<1,0,3,1><<<dim3(8, CAPE / 64, 8), 256, 0, stream>>>(
          nullptr, f_hid, eW2, eb2, nullptr, nullptr, toklist, f_wlist, cnt,
          CAPE, 1024, 512, c * CAPE, HIDSTRIDE, f_moe);
    }
    k_ln_res<<<TT, 256, 0, stream>>>(f_h2, f_moe, n3g, n3b, out, nullptr);
    mfma_gemm<0,2,2,0><<<dim3(4, 128), 256, 0, stream>>>(
        out, nullptr, hW1, hb1, nullptr, f_hh, nullptr, nullptr, nullptr, TT, 512, 256, 0, 0, nullptr);
    k_halt<<<TT / 4, 256, 0, stream>>>(f_hh, hW2, hb2, out);
  }

  k_final<<<1, 256, 0, stream>>>(f_probs, cnt, lA, out);
}

// Round 8
// 637.717 us; speedup vs baseline: 1.6248x; 1.0836x over previous
//
#include <hip/hip_runtime.h>
#include <hip/hip_bf16.h>

// Problem constants (B=8, N=1024, D=512, H=8, HD=64, E=4096, NE=8, NSH=2, TOPK=2, DH=1024)
// ALL inputs/outputs are float32.
#define TT 8192
#define DD 512

typedef unsigned short u16;
typedef __attribute__((ext_vector_type(8))) short short8;
typedef __attribute__((ext_vector_type(4))) float f32x4;

__device__ __forceinline__ u16 f2b(float f) {
  union { float f; unsigned int i; } w; w.f = f;
  unsigned int x = w.i;
  unsigned int r = (x + 0x7FFFu + ((x >> 16) & 1u)) >> 16;
  if ((x & 0x7F800000u) == 0x7F800000u) r = x >> 16;
  return (u16)r;
}
__device__ __forceinline__ float b2f(u16 u) {
  union { unsigned int i; float f; } w; w.i = ((unsigned int)u) << 16; return w.f;
}

__device__ __forceinline__ void blockReduce2(float& a, float& b, float* s4a, float* s4b) {
  #pragma unroll
  for (int off = 32; off; off >>= 1) { a += __shfl_xor(a, off); b += __shfl_xor(b, off); }
  int wid = threadIdx.x >> 6;
  if ((threadIdx.x & 63) == 0) { s4a[wid] = a; s4b[wid] = b; }
  __syncthreads();
  a = s4a[0] + s4a[1] + s4a[2] + s4a[3];
  b = s4b[0] + s4b[1] + s4b[2] + s4b[3];
}

// ---- zero esum ----
__global__ __launch_bounds__(256) void k_zero(float* __restrict__ esum) {
  esum[blockIdx.x * 256 + threadIdx.x] = 0.f;
}

// ---- edge sum: [B,E,D] -> [B,D] ----
__global__ __launch_bounds__(256) void k_esum(const float* __restrict__ ef, float* __restrict__ esum) {
  int b = blockIdx.x, ec = blockIdx.y, tid = threadIdx.x;
  float a0 = 0.f, a1 = 0.f;
  const float* base = ef + ((size_t)b * 4096 + (size_t)ec * 128) * 512;
  for (int e = 0; e < 128; ++e) {
    a0 += base[(size_t)e * 512 + tid];
    a1 += base[(size_t)e * 512 + tid + 256];
  }
  atomicAdd(&esum[b * 512 + tid], a0);
  atomicAdd(&esum[b * 512 + tid + 256], a1);
}

// ---- einj[b,dp] = (esum[b,:]/E) @ B_w[:,dp] + B_b[dp] ----
__global__ __launch_bounds__(256) void k_einj(const float* __restrict__ esum,
                                              const float* __restrict__ Bw, const float* __restrict__ Bb,
                                              float* __restrict__ einj) {
  int idx = blockIdx.x * 256 + threadIdx.x;
  int b = idx >> 9, dp = idx & 511;
  float a = Bb[dp];
  const float inv = 1.f / 4096.f;
  for (int d = 0; d < 512; ++d)
    a = fmaf(esum[b * 512 + d] * inv, Bw[d * 512 + dp], a);
  einj[idx] = a;
}

// ---- weight transpose + hi/lo bf16 split: W[512][512] -> Wt{h,l}[z][n][k] ----
__global__ __launch_bounds__(256) void k_wsplit(const float* __restrict__ Wq, const float* __restrict__ Wk,
                                                const float* __restrict__ Wv, const float* __restrict__ Wo,
                                                u16* __restrict__ outh, u16* __restrict__ outl) {
  __shared__ float st[64][65];
  int z = blockIdx.z;
  const float* W = z == 0 ? Wq : (z == 1 ? Wk : (z == 2 ? Wv : Wo));
  int k0 = blockIdx.x << 6, n0 = blockIdx.y << 6;
  int tid = threadIdx.x;
  int r = tid >> 2, c4 = (tid & 3) << 4;
  #pragma unroll
  for (int j = 0; j < 16; j += 4) {
    float4 v = *(const float4*)(W + (size_t)(k0 + r) * 512 + n0 + c4 + j);
    st[c4 + j + 0][r] = v.x; st[c4 + j + 1][r] = v.y;
    st[c4 + j + 2][r] = v.z; st[c4 + j + 3][r] = v.w;
  }
  __syncthreads();
  int n = tid >> 2, kb = (tid & 3) << 4;
  u16 h8[8] __attribute__((aligned(16)));
  u16 l8[8] __attribute__((aligned(16)));
  size_t obase = (size_t)z * 262144 + (size_t)(n0 + n) * 512 + k0 + kb;
  #pragma unroll
  for (int half = 0; half < 2; ++half) {
    #pragma unroll
    for (int j = 0; j < 8; ++j) {
      float val = st[n][kb + half * 8 + j];
      h8[j] = f2b(val);
      l8[j] = f2b(val - b2f(h8[j]));
    }
    *(uint4*)(outh + obase + half * 8) = *(uint4*)h8;
    *(uint4*)(outl + obase + half * 8) = *(uint4*)l8;
  }
}

// ---- generic weight transpose -> bf16 [n][k] (per-expert via blockIdx.z) ----
__global__ __launch_bounds__(256) void k_wt(const float* __restrict__ W, u16* __restrict__ Wt,
                                            int K, int N) {
  __shared__ float st[64][65];
  int z = blockIdx.z;
  W += (size_t)z * K * N; Wt += (size_t)z * K * N;
  int k0 = blockIdx.x << 6, n0 = blockIdx.y << 6;
  int tid = threadIdx.x;
  int r = tid >> 2, c4 = (tid & 3) << 4;
  #pragma unroll
  for (int j = 0; j < 16; j += 4) {
    float4 v = *(const float4*)(W + (size_t)(k0 + r) * N + n0 + c4 + j);
    st[c4 + j + 0][r] = v.x; st[c4 + j + 1][r] = v.y;
    st[c4 + j + 2][r] = v.z; st[c4 + j + 3][r] = v.w;
  }
  __syncthreads();
  int n = tid >> 2, kb = (tid & 3) << 4;
  u16 h8[8] __attribute__((aligned(16)));
  size_t obase = (size_t)(n0 + n) * K + k0 + kb;
  #pragma unroll
  for (int half = 0; half < 2; ++half) {
    #pragma unroll
    for (int j = 0; j < 8; ++j) h8[j] = f2b(st[n][kb + half * 8 + j]);
    *(uint4*)(Wt + obase + half * 8) = *(uint4*)h8;
  }
}

// ---- h_lti = LN(-exp(log_A)*h + einj) -> hi/lo bf16 (segment-local) ----
__global__ __launch_bounds__(256) void k_lti(const float* __restrict__ h, const float* __restrict__ lA,
                                             const float* __restrict__ einj,
                                             const float* __restrict__ g, const float* __restrict__ be,
                                             u16* __restrict__ Xh, u16* __restrict__ Xl, int seg0) {
  __shared__ float sa[4], sb[4];
  int rowg = seg0 + blockIdx.x, b = rowg >> 10, tid = threadIdx.x;
  int d0 = tid, d1 = tid + 256;
  size_t gbase = (size_t)rowg * 512;
  size_t lbase = (size_t)blockIdx.x * 512;
  float v0 = -expf(lA[d0]) * h[gbase + d0] + einj[b * 512 + d0];
  float v1 = -expf(lA[d1]) * h[gbase + d1] + einj[b * 512 + d1];
  float s = v0 + v1, ss = v0 * v0 + v1 * v1;
  blockReduce2(s, ss, sa, sb);
  float mu = s * (1.f / 512.f);
  float var = fmaxf(ss * (1.f / 512.f) - mu * mu, 0.f);
  float r = rsqrtf(var + 1e-5f);
  float o0 = (v0 - mu) * r * g[d0] + be[d0];
  float o1 = (v1 - mu) * r * g[d1] + be[d1];
  u16 h0 = f2b(o0), h1 = f2b(o1);
  Xh[lbase + d0] = h0; Xl[lbase + d0] = f2b(o0 - b2f(h0));
  Xh[lbase + d1] = h1; Xl[lbase + d1] = f2b(o1 - b2f(h1));
}

// ---- residual LN: LN(recon(Xh,Xl) + Bv) -> f32 (+ optional bf16 copy, + optional fused gate) ----
__global__ __launch_bounds__(256) void k_ln_res2(const u16* __restrict__ Xh, const u16* __restrict__ Xl,
                                                 const float* __restrict__ Bv,
                                                 const float* __restrict__ g, const float* __restrict__ be,
                                                 float* __restrict__ outf, u16* __restrict__ outb,
                                                 const float* __restrict__ gw, const float* __restrict__ gb,
                                                 float* __restrict__ probs, int* __restrict__ sel,
                                                 float2* __restrict__ wpair) {
  __shared__ float sa[4], sb[4];
  __shared__ float s8[4][8];
  int tid = threadIdx.x, d0 = tid, d1 = tid + 256;
  size_t base = (size_t)blockIdx.x * 512;
  float v0 = b2f(Xh[base + d0]) + b2f(Xl[base + d0]) + Bv[base + d0];
  float v1 = b2f(Xh[base + d1]) + b2f(Xl[base + d1]) + Bv[base + d1];
  float s = v0 + v1, ss = v0 * v0 + v1 * v1;
  blockReduce2(s, ss, sa, sb);
  float mu = s * (1.f / 512.f);
  float var = fmaxf(ss * (1.f / 512.f) - mu * mu, 0.f);
  float r = rsqrtf(var + 1e-5f);
  float o0 = (v0 - mu) * r * g[d0] + be[d0];
  float o1 = (v1 - mu) * r * g[d1] + be[d1];
  outf[base + d0] = o0;
  outf[base + d1] = o1;
  if (outb) { outb[base + d0] = f2b(o0); outb[base + d1] = f2b(o1); }
  if (probs) {
    // fused gate: logits = h2_row @ gw + gb
    float4 g0a = *(const float4*)(gw + d0 * 8);
    float4 g0b = *(const float4*)(gw + d0 * 8 + 4);
    float4 g1a = *(const float4*)(gw + d1 * 8);
    float4 g1b = *(const float4*)(gw + d1 * 8 + 4);
    float ga[8] = { o0 * g0a.x + o1 * g1a.x, o0 * g0a.y + o1 * g1a.y,
                    o0 * g0a.z + o1 * g1a.z, o0 * g0a.w + o1 * g1a.w,
                    o0 * g0b.x + o1 * g1b.x, o0 * g0b.y + o1 * g1b.y,
                    o0 * g0b.z + o1 * g1b.z, o0 * g0b.w + o1 * g1b.w };
    #pragma unroll
    for (int off = 32; off; off >>= 1)
      #pragma unroll
      for (int e = 0; e < 8; ++e) ga[e] += __shfl_xor(ga[e], off);
    int lane = tid & 63, wid = tid >> 6;
    if (lane == 0) {
      #pragma unroll
      for (int e = 0; e < 8; ++e) s8[wid][e] = ga[e];
    }
    __syncthreads();
    if (tid == 0) {
      int t = blockIdx.x;
      float acc[8];
      float m = -1e30f;
      #pragma unroll
      for (int e = 0; e < 8; ++e) {
        acc[e] = s8[0][e] + s8[1][e] + s8[2][e] + s8[3][e] + gb[e];
        m = fmaxf(m, acc[e]);
      }
      float p[8], sum = 0.f;
      #pragma unroll
      for (int e = 0; e < 8; ++e) { p[e] = expf(acc[e] - m); sum += p[e]; }
      float inv = 1.f / sum;
      #pragma unroll
      for (int e = 0; e < 8; ++e) { p[e] *= inv; probs[t * 8 + e] = p[e]; }
      int i1 = 0; float m1 = p[0];
      #pragma unroll
      for (int e = 1; e < 8; ++e) if (p[e] > m1) { m1 = p[e]; i1 = e; }
      int i2 = -1; float m2 = -1.f;
      #pragma unroll
      for (int e = 0; e < 8; ++e) if (e != i1 && p[e] > m2) { m2 = p[e]; i2 = e; }
      if (i2 < 0) i2 = (i1 + 1) & 7;
      float den = m1 + m2;
      float invs = (den > 0.f) ? 1.f / den : 0.f;
      sel[t] = i1 | (i2 << 4);
      wpair[t] = make_float2(m1 * invs, m2 * invs);
    }
  }
}

// ---- residual LN (both f32, optional bf16 copy) ----
__global__ __launch_bounds__(256) void k_ln_res(const float* __restrict__ A, const float* __restrict__ Bv,
                                                const float* __restrict__ g, const float* __restrict__ be,
                                                float* __restrict__ outf, u16* __restrict__ outb) {
  __shared__ float sa[4], sb[4];
  int tid = threadIdx.x, d0 = tid, d1 = tid + 256;
  size_t base = (size_t)blockIdx.x * 512;
  float v0 = A[base + d0] + Bv[base + d0];
  float v1 = A[base + d1] + Bv[base + d1];
  float s = v0 + v1, ss = v0 * v0 + v1 * v1;
  blockReduce2(s, ss, sa, sb);
  float mu = s * (1.f / 512.f);
  float var = fmaxf(ss * (1.f / 512.f) - mu * mu, 0.f);
  float r = rsqrtf(var + 1e-5f);
  float o0 = (v0 - mu) * r * g[d0] + be[d0];
  float o1 = (v1 - mu) * r * g[d1] + be[d1];
  outf[base + d0] = o0;
  outf[base + d1] = o1;
  if (outb) { outb[base + d0] = f2b(o0); outb[base + d1] = f2b(o1); }
}

// ---- prefix: 128-aligned per-expert offsets for compact routed layout ----
__global__ __launch_bounds__(64) void k_prefix(const int* __restrict__ cnt, int* __restrict__ off) {
  if (threadIdx.x == 0) {
    int acc = 0;
    for (int e = 0; e < 8; ++e) {
      off[e] = acc;
      int c = cnt[e]; if (c > 8192) c = 8192;
      acc += (c + 127) & ~127;
    }
  }
}

// ---- split-precision MFMA GEMM v3: 128x128 tile, 8 waves (512 thr), double-buffered LDS,
//      register prefetch, ONE barrier per K-step. Wave owns 64x32 (4x2 frags x 3 MFMA).
template<int NOUT>
__global__ __launch_bounds__(512, 4) void gemm_sp3(
    const u16* __restrict__ Xh, const u16* __restrict__ Xl, int lda,
    const u16* __restrict__ Wth, const u16* __restrict__ Wtl,
    const float* __restrict__ b0c, const float* __restrict__ b1c, const float* __restrict__ b2c,
    float* __restrict__ C0, float* __restrict__ C1, float* __restrict__ C2) {
  const float* bias = b0c; float* C = C0;
  const u16* Wh = Wth; const u16* Wl = Wtl;
  if (NOUT == 3) {
    int z = blockIdx.z;
    Wh += (size_t)z * 262144; Wl += (size_t)z * 262144;
    if (z == 1) { bias = b1c; C = C1; }
    else if (z == 2) { bias = b2c; C = C2; }
  }
  const int bm = blockIdx.y << 7, bn = blockIdx.x << 7;
  __shared__ u16 Ah[2][128][40];
  __shared__ u16 Al[2][128][40];
  __shared__ u16 Bh[2][128][40];
  __shared__ u16 Bl[2][128][40];
  const int tid = threadIdx.x;
  const int sr = tid >> 2, sk = (tid & 3) << 3;
  const int wv = tid >> 6, lane = tid & 63, q = lane >> 4, m16 = lane & 15;
  const int wr = (wv >> 2) << 6;   // 0 / 64
  const int wc = (wv & 3) << 5;    // 0,32,64,96
  const u16* ahr = Xh + (size_t)(bm + sr) * lda;
  const u16* alr = Xl + (size_t)(bm + sr) * lda;
  const u16* bhr = Wh + (size_t)(bn + sr) * 512;
  const u16* blr = Wl + (size_t)(bn + sr) * 512;
  f32x4 acc[4][2];
  #pragma unroll
  for (int m = 0; m < 4; ++m)
    #pragma unroll
    for (int n = 0; n < 2; ++n)
      #pragma unroll
      for (int i = 0; i < 4; ++i) acc[m][n][i] = 0.f;

  uint4 rah = *(const uint4*)(ahr + sk);
  uint4 ral = *(const uint4*)(alr + sk);
  uint4 rbh = *(const uint4*)(bhr + sk);
  uint4 rbl = *(const uint4*)(blr + sk);
  *(uint4*)&Ah[0][sr][sk] = rah;
  *(uint4*)&Al[0][sr][sk] = ral;
  *(uint4*)&Bh[0][sr][sk] = rbh;
  *(uint4*)&Bl[0][sr][sk] = rbl;
  __syncthreads();
  int cur = 0;
  for (int k0 = 0; k0 < 512; k0 += 32) {
    if (k0 + 32 < 512) {
      rah = *(const uint4*)(ahr + k0 + 32 + sk);
      ral = *(const uint4*)(alr + k0 + 32 + sk);
      rbh = *(const uint4*)(bhr + k0 + 32 + sk);
      rbl = *(const uint4*)(blr + k0 + 32 + sk);
    }
    short8 ahf[4], alf[4];
    #pragma unroll
    for (int m = 0; m < 4; ++m) {
      ahf[m] = *(const short8*)&Ah[cur][wr + m * 16 + m16][q * 8];
      alf[m] = *(const short8*)&Al[cur][wr + m * 16 + m16][q * 8];
    }
    #pragma unroll
    for (int n = 0; n < 2; ++n) {
      short8 bhf = *(const short8*)&Bh[cur][wc + n * 16 + m16][q * 8];
      short8 blf = *(const short8*)&Bl[cur][wc + n * 16 + m16][q * 8];
      #pragma unroll
      for (int m = 0; m < 4; ++m) {
        acc[m][n] = __builtin_amdgcn_mfma_f32_16x16x32_bf16(ahf[m], bhf, acc[m][n], 0, 0, 0);
        acc[m][n] = __builtin_amdgcn_mfma_f32_16x16x32_bf16(alf[m], bhf, acc[m][n], 0, 0, 0);
        acc[m][n] = __builtin_amdgcn_mfma_f32_16x16x32_bf16(ahf[m], blf, acc[m][n], 0, 0, 0);
      }
    }
    if (k0 + 32 < 512) {
      *(uint4*)&Ah[cur ^ 1][sr][sk] = rah;
      *(uint4*)&Al[cur ^ 1][sr][sk] = ral;
      *(uint4*)&Bh[cur ^ 1][sr][sk] = rbh;
      *(uint4*)&Bl[cur ^ 1][sr][sk] = rbl;
      __syncthreads();
      cur ^= 1;
    }
  }
  #pragma unroll
  for (int n = 0; n < 2; ++n) {
    int col = bn + wc + n * 16 + m16;
    float bb = bias[col];
    #pragma unroll
    for (int m = 0; m < 4; ++m) {
      #pragma unroll
      for (int i = 0; i < 4; ++i) {
        int rl = bm + wr + m * 16 + q * 4 + i;
        C[(size_t)rl * 512 + col] = acc[m][n][i] + bb;
      }
    }
  }
}

// ---- per-node head attention -> per-row packed [hi(512)|lo(512)] u16, IN PLACE over q row t ----
__global__ __launch_bounds__(64) void k_attn(const float* __restrict__ q, const float* __restrict__ k,
                                             const float* __restrict__ v,
                                             u16* __restrict__ aohl) {
  __shared__ float qs[512], ks[512], vs[512], at[64];
  size_t t = blockIdx.x;
  int lane = threadIdx.x;
  for (int i = lane; i < 512; i += 64) {
    qs[i] = q[t * 512 + i]; ks[i] = k[t * 512 + i]; vs[i] = v[t * 512 + i];
  }
  __syncthreads();
  int h = lane >> 3, g = lane & 7;
  float s = 0.f;
  #pragma unroll 8
  for (int d = 0; d < 64; ++d) s = fmaf(qs[h * 64 + d], ks[g * 64 + d], s);
  s *= 0.125f;
  float m = s;
  #pragma unroll
  for (int off = 1; off < 8; off <<= 1) m = fmaxf(m, __shfl_xor(m, off));
  float ex = expf(s - m);
  float sum = ex;
  #pragma unroll
  for (int off = 1; off < 8; off <<= 1) sum += __shfl_xor(sum, off);
  at[lane] = ex / sum;
  __syncthreads();
  #pragma unroll
  for (int j = 0; j < 8; ++j) {
    int d = lane + j * 64, hh = d >> 6, hd = d & 63;
    float acc = 0.f;
    #pragma unroll
    for (int gg = 0; gg < 8; ++gg) acc = fmaf(at[hh * 8 + gg], vs[gg * 64 + hd], acc);
    u16 hi = f2b(acc);
    aohl[t * 1024 + d] = hi;
    aohl[t * 1024 + 512 + d] = f2b(acc - b2f(hi));
  }
}

// ---- gate phase A (old path only) ----
__global__ __launch_bounds__(256) void k_gateA(const float* __restrict__ h2, const float* __restrict__ gw,
                                               const float* __restrict__ gb, float* __restrict__ probs,
                                               int* __restrict__ sel, float2* __restrict__ wpair) {
  int lane = threadIdx.x & 63, wid = threadIdx.x >> 6;
  int t = blockIdx.x * 4 + wid;
  const float* x = h2 + (size_t)t * 512;
  float acc[8] = {};
  for (int d = lane; d < 512; d += 64) {
    float xv = x[d];
    float4 g0 = *(const float4*)(gw + d * 8);
    float4 g1 = *(const float4*)(gw + d * 8 + 4);
    acc[0] = fmaf(xv, g0.x, acc[0]); acc[1] = fmaf(xv, g0.y, acc[1]);
    acc[2] = fmaf(xv, g0.z, acc[2]); acc[3] = fmaf(xv, g0.w, acc[3]);
    acc[4] = fmaf(xv, g1.x, acc[4]); acc[5] = fmaf(xv, g1.y, acc[5]);
    acc[6] = fmaf(xv, g1.z, acc[6]); acc[7] = fmaf(xv, g1.w, acc[7]);
  }
  #pragma unroll
  for (int off = 32; off; off >>= 1)
    #pragma unroll
    for (int e = 0; e < 8; ++e) acc[e] += __shfl_xor(acc[e], off);
  if (lane == 0) {
    float m = -1e30f;
    #pragma unroll
    for (int e = 0; e < 8; ++e) { acc[e] += gb[e]; m = fmaxf(m, acc[e]); }
    float p[8], sum = 0.f;
    #pragma unroll
    for (int e = 0; e < 8; ++e) { p[e] = expf(acc[e] - m); sum += p[e]; }
    float inv = 1.f / sum;
    #pragma unroll
    for (int e = 0; e < 8; ++e) { p[e] *= inv; probs[t * 8 + e] = p[e]; }
    int i1 = 0; float m1 = p[0];
    #pragma unroll
    for (int e = 1; e < 8; ++e) if (p[e] > m1) { m1 = p[e]; i1 = e; }
    int i2 = -1; float m2 = -1.f;
    #pragma unroll
    for (int e = 0; e < 8; ++e) if (e != i1 && p[e] > m2) { m2 = p[e]; i2 = e; }
    if (i2 < 0) i2 = (i1 + 1) & 7;
    float den = m1 + m2;
    float invs = (den > 0.f) ? 1.f / den : 0.f;
    sel[t] = i1 | (i2 << 4);
    wpair[t] = make_float2(m1 * invs, m2 * invs);
  }
}

// ---- gate phase B ----
__global__ __launch_bounds__(256) void k_gateB(const int* __restrict__ sel, const float2* __restrict__ wpair,
                                               int* __restrict__ toklist, float* __restrict__ wlist,
                                               int* __restrict__ cnt) {
  int e = blockIdx.x;
  int tid = threadIdx.x, lane = tid & 63, wv = tid >> 6;
  __shared__ int wsum[4];
  int base = 0;
  for (int t0 = 0; t0 < 8192; t0 += 256) {
    int t = t0 + tid;
    int s = sel[t];
    int i1 = s & 15, i2 = (s >> 4) & 15;
    bool f = (i1 == e) || (i2 == e);
    float wt = (i1 == e) ? wpair[t].x : ((i2 == e) ? wpair[t].y : 0.f);
    unsigned long long m = __ballot(f);
    int rank = __popcll(m & ((1ull << lane) - 1ull));
    int wtot = __popcll(m);
    if (lane == 0) wsum[wv] = wtot;
    __syncthreads();
    int prev = 0;
    for (int ww = 0; ww < wv; ++ww) prev += wsum[ww];
    int tot = wsum[0] + wsum[1] + wsum[2] + wsum[3];
    if (f) {
      int pos = base + prev + rank;
      toklist[e * 8192 + pos] = t;
      wlist[e * 8192 + pos] = wt;
    }
    base += tot;
    __syncthreads();
  }
  if (tid == 0) cnt[e] = base;
}

// ---- OLD MFMA bf16 GEMM: 64x64 tile (kept for small-workspace tiers) ----
template<int XMODE, int ACT, int OUTMODE, int EXPERT>
__global__ __launch_bounds__(256) void mfma_gemm(
    const float* __restrict__ Xf, const u16* __restrict__ Xb,
    const float* __restrict__ Wg, const float* __restrict__ biasg,
    float* __restrict__ C, u16* __restrict__ C16,
    const int* __restrict__ toklist, const float* __restrict__ wlist,
    const int* __restrict__ cnt, int M, int K, int N, int chunk0,
    size_t hidstride, float* __restrict__ moe) {
  int e = EXPERT ? blockIdx.z : 0;
  const float* W = Wg + (size_t)e * K * N;
  const float* bias = biasg + (size_t)e * N;
  int Mloc = M;
  if (EXPERT) {
    int ce = cnt[e]; if (ce > 8192) ce = 8192;
    Mloc = ce - chunk0;
    if (XMODE == 1) Xb += (size_t)e * hidstride;
    if (OUTMODE == 2) C16 += (size_t)e * hidstride;
  }
  const int bm = blockIdx.y << 6, bn = blockIdx.x << 6;
  if (EXPERT && bm >= Mloc) return;
  __shared__ u16 As[64][40];
  __shared__ u16 Bs[64][40];
  __shared__ int rows[64];
  const int tid = threadIdx.x;
  if (EXPERT && XMODE == 2 && tid < 64) {
    int ce = cnt[e]; if (ce > 8192) ce = 8192;
    int r = chunk0 + bm + tid;
    rows[tid] = toklist[e * 8192 + (r < ce ? r : chunk0)] & 8191;
  }
  const int srow = tid >> 2;
  const int skg = (tid & 3) << 3;
  const int wv = tid >> 6, lane = tid & 63, q = lane >> 4, m16 = lane & 15;
  f32x4 acc[4];
  #pragma unroll
  for (int c = 0; c < 4; ++c)
    #pragma unroll
    for (int i = 0; i < 4; ++i) acc[c][i] = 0.f;

  for (int k0 = 0; k0 < K; k0 += 32) {
    __syncthreads();
    {
      u16 a8[8] __attribute__((aligned(16)));
      if (XMODE == 1) {
        *(uint4*)a8 = *(const uint4*)(Xb + (size_t)(bm + srow) * K + k0 + skg);
      } else {
        const float* src = (XMODE == 2) ? (Xf + (size_t)rows[srow] * K + k0 + skg)
                                        : (Xf + (size_t)(bm + srow) * K + k0 + skg);
        float4 x0 = *(const float4*)(src);
        float4 x1 = *(const float4*)(src + 4);
        a8[0] = f2b(x0.x); a8[1] = f2b(x0.y); a8[2] = f2b(x0.z); a8[3] = f2b(x0.w);
        a8[4] = f2b(x1.x); a8[5] = f2b(x1.y); a8[6] = f2b(x1.z); a8[7] = f2b(x1.w);
      }
      *(uint4*)&As[srow][skg] = *(uint4*)a8;
    }
    {
      u16 b8[8] __attribute__((aligned(16)));
      const float* src = W + (size_t)(k0 + skg) * N + bn + srow;
      #pragma unroll
      for (int j = 0; j < 8; ++j) b8[j] = f2b(src[(size_t)j * N]);
      *(uint4*)&Bs[srow][skg] = *(uint4*)b8;
    }
    __syncthreads();
    short8 af = *(const short8*)&As[wv * 16 + m16][q * 8];
    #pragma unroll
    for (int c = 0; c < 4; ++c) {
      short8 bf = *(const short8*)&Bs[c * 16 + m16][q * 8];
      acc[c] = __builtin_amdgcn_mfma_f32_16x16x32_bf16(af, bf, acc[c], 0, 0, 0);
    }
  }
  #pragma unroll
  for (int c = 0; c < 4; ++c) {
    int col = bn + c * 16 + m16;
    float bb = bias[col];
    #pragma unroll
    for (int i = 0; i < 4; ++i) {
      int rl = bm + wv * 16 + q * 4 + i;
      if (EXPERT && rl >= Mloc) continue;
      float v = acc[c][i] + bb;
      if (ACT == 1) v = v / (1.f + expf(-v));
      else if (ACT == 2) v = tanhf(v);
      if (OUTMODE == 0) C[(size_t)rl * N + col] = v;
      else if (OUTMODE == 1) C[(size_t)rl * N + col] += v;
      else if (OUTMODE == 2) C16[(size_t)rl * N + col] = f2b(v);
      else {
        int rg = chunk0 + rl;
        int tok = toklist[e * 8192 + rg] & 8191;
        float wt = wlist[e * 8192 + rg];
        atomicAdd(&moe[(size_t)tok * 512 + col], v * wt);
      }
    }
  }
}

// ---- FAST MFMA bf16 GEMM v3: 128x128 tile, 8 waves (512 thr), double-buffered LDS,
//      register prefetch, ONE barrier per K-step. Wave owns 64x32 (4x2 frags).
// XMODE: 1 dense bf16, 2 gathered bf16 rows (toklist), 3 per-expert bf16 (Xb += e*hidstride)
// ACT: 0 none, 1 silu, 2 tanh
// OUTMODE: 0 f32 store, 1 f32 +=, 2 bf16 store, 3 weighted scatter-atomicAdd, 4 dense atomicAdd
// EXPERT: 0 none; 1 routed chunked (z=expert); 2 dense-z (z offsets W/bias/hid);
//         3 routed COMPACT (expert found from 128-aligned off[]=cnt+8; hid rows = global compact idx)
template<int XMODE, int ACT, int OUTMODE, int EXPERT>
__global__ __launch_bounds__(512, 4) void mfma_gemm3(
    const u16* __restrict__ Xb, const u16* __restrict__ Wt, const float* __restrict__ biasg,
    float* __restrict__ C, u16* __restrict__ C16,
    const int* __restrict__ toklist, const float* __restrict__ wlist,
    const int* __restrict__ cnt, int M, int K, int N, int chunk0,
    size_t hidstride, float* __restrict__ moe) {
  const int bm = blockIdx.y << 7, bn = blockIdx.x << 7;
  int e = 0, offe = 0;
  int Mloc = M;
  if (EXPERT == 1) {
    e = blockIdx.z;
    int ce = cnt[e]; if (ce > 8192) ce = 8192;
    Mloc = ce - chunk0;
    if (bm >= Mloc) return;
  } else if (EXPERT == 2) {
    e = blockIdx.z;
  } else if (EXPERT == 3) {
    const int* off = cnt + 8;
    int found = -1;
    #pragma unroll
    for (int ee = 0; ee < 8; ++ee) {
      int c = cnt[ee]; if (c > 8192) c = 8192;
      int st = off[ee], len = (c + 127) & ~127;
      if (found < 0 && bm >= st && bm < st + len) found = ee;
    }
    if (found < 0) return;
    e = found; offe = off[e];
    int ce = cnt[e]; if (ce > 8192) ce = 8192;
    Mloc = offe + ce;
    if (bm >= Mloc) return;
  }
  const u16* W = Wt + (size_t)e * K * N;
  const float* bias = biasg + (size_t)e * N;
  if (EXPERT == 1 || EXPERT == 2) {
    if (XMODE == 3) Xb += (size_t)e * hidstride;
    if (OUTMODE == 2) C16 += (size_t)e * hidstride;
  }
  __shared__ u16 As[2][128][40];
  __shared__ u16 Bs[2][128][40];
  __shared__ int rows[128];
  const int tid = threadIdx.x;
  if (XMODE == 2) {
    if (tid < 128) {
      int ce = cnt[e]; if (ce > 8192) ce = 8192;
      int r = (EXPERT == 3) ? (bm - offe + tid) : (chunk0 + bm + tid);
      rows[tid] = toklist[e * 8192 + (r < ce ? r : (ce > 0 ? ce - 1 : 0))] & 8191;
    }
    __syncthreads();
  }
  const int sr = tid >> 2, sk = (tid & 3) << 3;
  const int wv = tid >> 6, lane = tid & 63, q = lane >> 4, m16 = lane & 15;
  const int wr = (wv >> 2) << 6;
  const int wc = (wv & 3) << 5;
  const u16* arow = (XMODE == 2) ? (Xb + (size_t)rows[sr] * K) : (Xb + (size_t)(bm + sr) * K);
  const u16* brow = W + (size_t)(bn + sr) * K;
  f32x4 acc[4][2];
  #pragma unroll
  for (int m = 0; m < 4; ++m)
    #pragma unroll
    for (int n = 0; n < 2; ++n)
      #pragma unroll
      for (int i = 0; i < 4; ++i) acc[m][n][i] = 0.f;

  uint4 ar = *(const uint4*)(arow + sk);
  uint4 br = *(const uint4*)(brow + sk);
  *(uint4*)&As[0][sr][sk] = ar;
  *(uint4*)&Bs[0][sr][sk] = br;
  __syncthreads();
  int cur = 0;
  for (int k0 = 0; k0 < K; k0 += 32) {
    if (k0 + 32 < K) {
      ar = *(const uint4*)(arow + k0 + 32 + sk);
      br = *(const uint4*)(brow + k0 + 32 + sk);
    }
    short8 af[4];
    #pragma unroll
    for (int m = 0; m < 4; ++m)
      af[m] = *(const short8*)&As[cur][wr + m * 16 + m16][q * 8];
    short8 bf[2];
    #pragma unroll
    for (int n = 0; n < 2; ++n)
      bf[n] = *(const short8*)&Bs[cur][wc + n * 16 + m16][q * 8];
    #pragma unroll
    for (int n = 0; n < 2; ++n)
      #pragma unroll
      for (int m = 0; m < 4; ++m)
        acc[m][n] = __builtin_amdgcn_mfma_f32_16x16x32_bf16(af[m], bf[n], acc[m][n], 0, 0, 0);
    if (k0 + 32 < K) {
      *(uint4*)&As[cur ^ 1][sr][sk] = ar;
      *(uint4*)&Bs[cur ^ 1][sr][sk] = br;
      __syncthreads();
      cur ^= 1;
    }
  }
  #pragma unroll
  for (int n = 0; n < 2; ++n) {
    int col = bn + wc + n * 16 + m16;
    float bb = bias[col];
    #pragma unroll
    for (int m = 0; m < 4; ++m) {
      #pragma unroll
      for (int i = 0; i < 4; ++i) {
        int rl = bm + wr + m * 16 + q * 4 + i;
        if ((EXPERT == 1 || EXPERT == 3) && rl >= Mloc) continue;
        float v = acc[m][n][i] + bb;
        if (ACT == 1) v = v / (1.f + expf(-v));
        else if (ACT == 2) v = tanhf(v);
        if (OUTMODE == 0) C[(size_t)rl * N + col] = v;
        else if (OUTMODE == 1) C[(size_t)rl * N + col] += v;
        else if (OUTMODE == 2) C16[(size_t)rl * N + col] = f2b(v);
        else if (OUTMODE == 3) {
          int rg = (EXPERT == 3) ? (rl - offe) : (chunk0 + rl);
          int tok = toklist[e * 8192 + rg] & 8191;
          float wt = wlist[e * 8192 + rg];
          atomicAdd(&moe[(size_t)tok * 512 + col], v * wt);
        } else {
          atomicAdd(&C[(size_t)rl * N + col], v);
        }
      }
    }
  }
}

// ---- halt head ----
__global__ __launch_bounds__(256) void k_halt(const u16* __restrict__ hh, const float* __restrict__ hW2,
                                              const float* __restrict__ hb2, float* __restrict__ out) {
  int lane = threadIdx.x & 63, wid = threadIdx.x >> 6;
  int t = blockIdx.x * 4 + wid;
  const u16* x = hh + (size_t)t * 256;
  float a = b2f(x[lane]) * hW2[lane] + b2f(x[lane + 64]) * hW2[lane + 64] +
            b2f(x[lane + 128]) * hW2[lane + 128] + b2f(x[lane + 192]) * hW2[lane + 192];
  #pragma unroll
  for (int off = 32; off; off >>= 1) a += __shfl_xor(a, off);
  if (lane == 0) {
    float p = 1.f / (1.f + expf(-(a + hb2[0])));
    out[4194304 + t] = p;
    out[4194304 + 8192 + t] = p;
  }
}

// ---- scalar: stab + aux loss ----
__global__ __launch_bounds__(256) void k_final(const float* __restrict__ probs, const int* __restrict__ cnt,
                                               const float* __restrict__ lA, float* __restrict__ out) {
  __shared__ float sp[4][8];
  __shared__ float sm[4];
  int tid = threadIdx.x, lane = tid & 63, wid = tid >> 6;
  float part[8] = {};
  for (int i = tid; i < 8192; i += 256) {
    const float* p = probs + i * 8;
    #pragma unroll
    for (int e = 0; e < 8; ++e) part[e] += p[e];
  }
  #pragma unroll
  for (int off = 32; off; off >>= 1)
    #pragma unroll
    for (int e = 0; e < 8; ++e) part[e] += __shfl_xor(part[e], off);
  float mx = 0.f;
  for (int d = tid; d < 512; d += 256) mx = fmaxf(mx, expf(lA[d]));
  #pragma unroll
  for (int off = 32; off; off >>= 1) mx = fmaxf(mx, __shfl_xor(mx, off));
  if (lane == 0) {
    #pragma unroll
    for (int e = 0; e < 8; ++e) sp[wid][e] = part[e];
    sm[wid] = mx;
  }
  __syncthreads();
  if (tid == 0) {
    float loss = 0.f;
    for (int e = 0; e < 8; ++e) {
      float pm = (sp[0][e] + sp[1][e] + sp[2][e] + sp[3][e]) * (1.f / 8192.f);
      int c = cnt[e]; if (c > 8192) c = 8192;
      loss += (float)c * (1.f / 8192.f) * pm;
    }
    loss *= 0.01f * 8.f;
    float mall = fmaxf(fmaxf(sm[0], sm[1]), fmaxf(sm[2], sm[3]));
    out[4194304 + 16384] = fmaxf(mall - 0.95f, 0.f) + loss;
  }
}

extern "C" void kernel_launch(void* const* d_in, const int* in_sizes, int n_in,
                              void* d_out, int out_size, void* d_ws, size_t ws_size,
                              hipStream_t stream) {
  const float* h   = (const float*)d_in[0];
  const float* ef  = (const float*)d_in[1];
  const float* lA  = (const float*)d_in[2];
  const float* Bw  = (const float*)d_in[3];
  const float* Bb  = (const float*)d_in[4];
  const float* Wq  = (const float*)d_in[5];  const float* bq  = (const float*)d_in[6];
  const float* Wk  = (const float*)d_in[7];  const float* bk  = (const float*)d_in[8];
  const float* Wv  = (const float*)d_in[9];  const float* bv  = (const float*)d_in[10];
  const float* Wo  = (const float*)d_in[11]; const float* bo  = (const float*)d_in[12];
  const float* n1g = (const float*)d_in[13]; const float* n1b = (const float*)d_in[14];
  const float* n2g = (const float*)d_in[15]; const float* n2b = (const float*)d_in[16];
  const float* n3g = (const float*)d_in[17]; const float* n3b = (const float*)d_in[18];
  const float* gw  = (const float*)d_in[19]; const float* gb  = (const float*)d_in[20];
  const float* eW1 = (const float*)d_in[21]; const float* eb1 = (const float*)d_in[22];
  const float* eW2 = (const float*)d_in[23]; const float* eb2 = (const float*)d_in[24];
  const float* sW1 = (const float*)d_in[25]; const float* sb1 = (const float*)d_in[26];
  const float* sW2 = (const float*)d_in[27]; const float* sb2 = (const float*)d_in[28];
  const float* hW1 = (const float*)d_in[29]; const float* hb1 = (const float*)d_in[30];
  const float* hW2 = (const float*)d_in[31]; const float* hb2 = (const float*)d_in[32];
  float* out = (float*)d_out;
  float* ws = (float*)d_ws;

  // ---- tiered workspace layout ----
  const size_t R = (size_t)TT * DD;   // 4,194,304 floats
  const size_t SM = 155648 + 73744;
  size_t wsf = ws_size / 4;
  int S; size_t ARENA;
  bool FAST;
  if (wsf >= 6 * R + SM)      { S = 8192; ARENA = 4 * R; FAST = true; }
  else if (wsf >= 3 * R + SM) { S = 2048; ARENA = R; FAST = false; }
  else                        { S = 512;  ARENA = 1048576; FAST = false; }
  const int CAPE = (int)(ARENA / 4096);
  const int NCH  = 8192 / CAPE;
  const size_t HIDSTRIDE = (size_t)CAPE * 1024;
  const int CAPS = (ARENA / 512 >= 8192) ? 8192 : (int)(ARENA / 512);

  float* f_h2  = ws;
  float* f_moe = ws + R;
  float* arena = ws + 2 * R;
  const size_t SD = (size_t)S * 512;
  u16* f_xh = (u16*)arena;
  u16* f_xl = f_xh + SD;
  float* f_q = arena + SD;
  float* f_k = arena + 2 * SD;
  float* f_v = arena + 3 * SD;
  u16* f_aohl = (u16*)f_q;
  float* f_hp = f_k;
  u16* f_wh = (u16*)f_moe;             // [4][512][512] split QKV/Wo weights (hi)
  u16* f_wl = f_wh + 4 * 262144;       // (lo)
  u16* f_hid = (u16*)arena;            // old-path hid
  u16* f_hh  = (u16*)arena;            // old-path halt hid
  // FAST-path arena carve (u16 indices into arena; arena = 4R floats = 8R u16 = 33554432):
  //   hidC  [0, 17825792)          17408 rows x 1024 (compact routed; shared uses 2x8192 rows)
  //   eW1t  [17825792, 22020096)
  //   eW2t  [22020096, 26214400)
  //   h2b   [26214400, 30408704)   over dead v region (written by ln_res2)
  //   sW1t  [30408704, 31457280)
  //   sW2t  [31457280, 32505856)
  //   (after routed experts, hidC dead -> halt scratch:)
  //   h3b [0, 4194304) | hW1t [4194304, 4325376) | hh3 [4325376, 6422528)
  u16* a16 = (u16*)arena;
  u16* f_hidC = a16;
  u16* f_eW1t = a16 + 17825792;
  u16* f_eW2t = a16 + 22020096;
  u16* f_h2b  = a16 + 26214400;
  u16* f_sW1t = a16 + 30408704;
  u16* f_sW2t = a16 + 31457280;
  u16* f_h3b  = a16;
  u16* f_hW1t = a16 + 4194304;
  u16* f_hh3  = a16 + 4325376;
  float* smr = ws + 2 * R + ARENA;
  float* f_esum = smr;
  float* f_einj = smr + 4096;
  float* f_probs = smr + 8192;
  float2* f_wpair = (float2*)(smr + 8192 + 65536);
  float* f_wlist = smr + 8192 + 65536 + 16384;
  int* ip = (int*)(smr + 8192 + 65536 + 16384 + 65536);
  int* sel = ip; int* cnt = ip + 8192; int* off = ip + 8192 + 8; int* toklist = ip + 8192 + 16;

  // ---- LTI prep + QKV weight split ----
  k_zero<<<16, 256, 0, stream>>>(f_esum);
  k_esum<<<dim3(8, 32), 256, 0, stream>>>(ef, f_esum);
  k_einj<<<16, 256, 0, stream>>>(f_esum, Bw, Bb, f_einj);
  k_wsplit<<<dim3(8, 8, 4), 256, 0, stream>>>(Wq, Wk, Wv, Wo, f_wh, f_wl);

  // ---- LTI + attention (v3 split-precision GEMMs; gate fused into ln_res2 in FAST) ----
  for (int s = 0; s < TT / S; ++s) {
    int seg0 = s * S;
    k_lti<<<S, 256, 0, stream>>>(h, lA, f_einj, n1g, n1b, f_xh, f_xl, seg0);
    gemm_sp3<3><<<dim3(4, S / 128, 3), 512, 0, stream>>>(
        f_xh, f_xl, 512, f_wh, f_wl, bq, bk, bv, f_q, f_k, f_v);
    k_attn<<<S, 64, 0, stream>>>(f_q, f_k, f_v, f_aohl);
    gemm_sp3<1><<<dim3(4, S / 128, 1), 512, 0, stream>>>(
        f_aohl, f_aohl + 512, 1024, f_wh + 3 * 262144, f_wl + 3 * 262144,
        bo, nullptr, nullptr, f_hp, nullptr, nullptr);
    if (FAST)
      k_ln_res2<<<S, 256, 0, stream>>>(f_xh, f_xl, f_hp, n2g, n2b,
                                       f_h2, f_h2b, gw, gb, f_probs, sel, f_wpair);
    else
      k_ln_res2<<<S, 256, 0, stream>>>(f_xh, f_xl, f_hp, n2g, n2b,
                                       f_h2 + (size_t)seg0 * 512, nullptr,
                                       nullptr, nullptr, nullptr, nullptr, nullptr);
  }

  // ---- gate compaction ----
  if (!FAST)
    k_gateA<<<TT / 4, 256, 0, stream>>>(f_h2, gw, gb, f_probs, sel, f_wpair);
  k_gateB<<<8, 256, 0, stream>>>(sel, f_wpair, toklist, f_wlist, cnt);

  if (FAST) {
    k_prefix<<<1, 64, 0, stream>>>(cnt, off);
    // ---- convert MoE weights to bf16 [n][k] ----
    k_wt<<<dim3(8, 16, 8), 256, 0, stream>>>(eW1, f_eW1t, 512, 1024);
    k_wt<<<dim3(16, 8, 8), 256, 0, stream>>>(eW2, f_eW2t, 1024, 512);
    k_wt<<<dim3(8, 16, 2), 256, 0, stream>>>(sW1, f_sW1t, 512, 1024);
    k_wt<<<dim3(16, 8, 2), 256, 0, stream>>>(sW2, f_sW2t, 1024, 512);

    // ---- shared experts: W1 dense-z; W2 sx0 store, sx1 += (no zeroing, no atomics) ----
    mfma_gemm3<1,1,2,2><<<dim3(8, 64, 2), 512, 0, stream>>>(
        f_h2b, f_sW1t, sb1, nullptr, f_hidC, nullptr, nullptr, nullptr,
        TT, 512, 1024, 0, (size_t)TT * 1024, nullptr);
    mfma_gemm3<1,0,0,0><<<dim3(4, 64), 512, 0, stream>>>(
        f_hidC, f_sW2t, sb2, f_moe, nullptr, nullptr, nullptr, nullptr,
        TT, 1024, 512, 0, 0, nullptr);
    mfma_gemm3<1,0,1,0><<<dim3(4, 64), 512, 0, stream>>>(
        f_hidC + (size_t)TT * 1024, f_sW2t + 524288, sb2 + 512, f_moe, nullptr,
        nullptr, nullptr, nullptr, TT, 1024, 512, 0, 0, nullptr);

    // ---- routed experts: compact layout, ONE dispatch per GEMM ----
    mfma_gemm3<2,1,2,3><<<dim3(8, 136), 512, 0, stream>>>(
        f_h2b, f_eW1t, eb1, nullptr, f_hidC, toklist, nullptr, cnt,
        0, 512, 1024, 0, 0, nullptr);
    mfma_gemm3<1,0,3,3><<<dim3(4, 136), 512, 0, stream>>>(
        f_hidC, f_eW2t, eb2, nullptr, nullptr, toklist, f_wlist, cnt,
        0, 1024, 512, 0, 0, f_moe);

    // ---- final LN (f32 out + bf16 h3b), halt head via v3 GEMM ----
    k_ln_res<<<TT, 256, 0, stream>>>(f_h2, f_moe, n3g, n3b, out, f_h3b);
    k_wt<<<dim3(8, 4, 1), 256, 0, stream>>>(hW1, f_hW1t, 512, 256);
    mfma_gemm3<1,2,2,0><<<dim3(2, 64), 512, 0, stream>>>(
        f_h3b, f_hW1t, hb1, nullptr, f_hh3, nullptr, nullptr, nullptr,
        TT, 512, 256, 0, 0, nullptr);
    k_halt<<<TT / 4, 256, 0, stream>>>(f_hh3, hW2, hb2, out);
  } else {
    // ---- old path (small workspace tiers) ----
    for (int sx = 0; sx < 2; ++sx)
      for (int c = 0; c < TT / CAPS; ++c) {
        const float* xs = f_h2 + (size_t)c * CAPS * 512;
        float* ms = f_moe + (size_t)c * CAPS * 512;
        mfma_gemm<0,1,2,0><<<dim3(16, CAPS / 64), 256, 0, stream>>>(
            xs, nullptr, sW1 + (size_t)sx * 524288, sb1 + sx * 1024,
            nullptr, f_hid, nullptr, nullptr, nullptr, CAPS, 512, 1024, 0, 0, nullptr);
        if (sx == 0)
          mfma_gemm<1,0,0,0><<<dim3(8, CAPS / 64), 256, 0, stream>>>(
              nullptr, f_hid, sW2, sb2, ms, nullptr, nullptr, nullptr, nullptr, CAPS, 1024, 512, 0, 0, nullptr);
        else
          mfma_gemm<1,0,1,0><<<dim3(8, CAPS / 64), 256, 0, stream>>>(
              nullptr, f_hid, sW2 + 524288, sb2 + 512, ms, nullptr, nullptr, nullptr, nullptr, CAPS, 1024, 512, 0, 0, nullptr);
      }
    for (int c = 0; c < NCH; ++c) {
      mfma_gemm<2,1,2,1><<<dim3(16, CAPE / 64, 8), 256, 0, stream>>>(
          f_h2, nullptr, eW1, eb1, nullptr, f_hid, toklist, nullptr, cnt,
          CAPE, 512, 1024, c * CAPE, HIDSTRIDE, nullptr);
      mfma_gemm<1,0,3,1><<<dim3(8, CAPE / 64, 8), 256, 0, stream>>>(
          nullptr, f_hid, eW2, eb2, nullptr, nullptr, toklist, f_wlist, cnt,
          CAPE, 1024, 512, c * CAPE, HIDSTRIDE, f_moe);
    }
    k_ln_res<<<TT, 256, 0, stream>>>(f_h2, f_moe, n3g, n3b, out, nullptr);
    mfma_gemm<0,2,2,0><<<dim3(4, 128), 256, 0, stream>>>(
        out, nullptr, hW1, hb1, nullptr, f_hh, nullptr, nullptr, nullptr, TT, 512, 256, 0, 0, nullptr);
    k_halt<<<TT / 4, 256, 0, stream>>>(f_hh, hW2, hb2, out);
  }

  k_final<<<1, 256, 0, stream>>>(f_probs, cnt, lA, out);
}

// Round 9
// 623.782 us; speedup vs baseline: 1.6611x; 1.0223x over previous
//
#include <hip/hip_runtime.h>
#include <hip/hip_bf16.h>

// Problem constants (B=8, N=1024, D=512, H=8, HD=64, E=4096, NE=8, NSH=2, TOPK=2, DH=1024)
// ALL inputs/outputs are float32.
#define TT 8192
#define DD 512

typedef unsigned short u16;
typedef __attribute__((ext_vector_type(8))) short short8;
typedef __attribute__((ext_vector_type(4))) float f32x4;

__device__ __forceinline__ u16 f2b(float f) {
  union { float f; unsigned int i; } w; w.f = f;
  unsigned int x = w.i;
  unsigned int r = (x + 0x7FFFu + ((x >> 16) & 1u)) >> 16;
  if ((x & 0x7F800000u) == 0x7F800000u) r = x >> 16;
  return (u16)r;
}
__device__ __forceinline__ float b2f(u16 u) {
  union { unsigned int i; float f; } w; w.i = ((unsigned int)u) << 16; return w.f;
}

// XCD-chunked bijective tile remap (T1): HW assigns flat%8 -> XCD; give each XCD
// a contiguous run of row-panels (y-major) so same-A-panel tiles share one L2.
__device__ __forceinline__ void xcd_remap(int& bx, int& by, int& bz) {
  int gx = gridDim.x, gy = gridDim.y, gz = gridDim.z;
  int total = gx * gy * gz;
  int flat = blockIdx.x + gx * (blockIdx.y + gy * blockIdx.z);
  if ((total & 7) == 0) {
    int nper = total >> 3;
    int t = (flat & 7) * nper + (flat >> 3);
    int gxz = gx * gz;
    by = t / gxz;
    int r = t - by * gxz;
    bz = r / gx;
    bx = r - bz * gx;
  } else {
    bx = blockIdx.x; by = blockIdx.y; bz = blockIdx.z;
  }
}

__device__ __forceinline__ void blockReduce2(float& a, float& b, float* s4a, float* s4b) {
  #pragma unroll
  for (int off = 32; off; off >>= 1) { a += __shfl_xor(a, off); b += __shfl_xor(b, off); }
  int wid = threadIdx.x >> 6;
  if ((threadIdx.x & 63) == 0) { s4a[wid] = a; s4b[wid] = b; }
  __syncthreads();
  a = s4a[0] + s4a[1] + s4a[2] + s4a[3];
  b = s4b[0] + s4b[1] + s4b[2] + s4b[3];
}

// ---- zero esum ----
__global__ __launch_bounds__(256) void k_zero(float* __restrict__ esum) {
  esum[blockIdx.x * 256 + threadIdx.x] = 0.f;
}

// ---- edge sum: [B,E,D] -> [B,D] ----
__global__ __launch_bounds__(256) void k_esum(const float* __restrict__ ef, float* __restrict__ esum) {
  int b = blockIdx.x, ec = blockIdx.y, tid = threadIdx.x;
  float a0 = 0.f, a1 = 0.f;
  const float* base = ef + ((size_t)b * 4096 + (size_t)ec * 128) * 512;
  for (int e = 0; e < 128; ++e) {
    a0 += base[(size_t)e * 512 + tid];
    a1 += base[(size_t)e * 512 + tid + 256];
  }
  atomicAdd(&esum[b * 512 + tid], a0);
  atomicAdd(&esum[b * 512 + tid + 256], a1);
}

// ---- einj[b,dp] = (esum[b,:]/E) @ B_w[:,dp] + B_b[dp] ----
__global__ __launch_bounds__(256) void k_einj(const float* __restrict__ esum,
                                              const float* __restrict__ Bw, const float* __restrict__ Bb,
                                              float* __restrict__ einj) {
  int idx = blockIdx.x * 256 + threadIdx.x;
  int b = idx >> 9, dp = idx & 511;
  float a = Bb[dp];
  const float inv = 1.f / 4096.f;
  for (int d = 0; d < 512; ++d)
    a = fmaf(esum[b * 512 + d] * inv, Bw[d * 512 + dp], a);
  einj[idx] = a;
}

// ---- weight transpose + hi/lo bf16 split: W[512][512] -> Wt{h,l}[z][n][k] ----
__global__ __launch_bounds__(256) void k_wsplit(const float* __restrict__ Wq, const float* __restrict__ Wk,
                                                const float* __restrict__ Wv, const float* __restrict__ Wo,
                                                u16* __restrict__ outh, u16* __restrict__ outl) {
  __shared__ float st[64][65];
  int z = blockIdx.z;
  const float* W = z == 0 ? Wq : (z == 1 ? Wk : (z == 2 ? Wv : Wo));
  int k0 = blockIdx.x << 6, n0 = blockIdx.y << 6;
  int tid = threadIdx.x;
  int r = tid >> 2, c4 = (tid & 3) << 4;
  #pragma unroll
  for (int j = 0; j < 16; j += 4) {
    float4 v = *(const float4*)(W + (size_t)(k0 + r) * 512 + n0 + c4 + j);
    st[c4 + j + 0][r] = v.x; st[c4 + j + 1][r] = v.y;
    st[c4 + j + 2][r] = v.z; st[c4 + j + 3][r] = v.w;
  }
  __syncthreads();
  int n = tid >> 2, kb = (tid & 3) << 4;
  u16 h8[8] __attribute__((aligned(16)));
  u16 l8[8] __attribute__((aligned(16)));
  size_t obase = (size_t)z * 262144 + (size_t)(n0 + n) * 512 + k0 + kb;
  #pragma unroll
  for (int half = 0; half < 2; ++half) {
    #pragma unroll
    for (int j = 0; j < 8; ++j) {
      float val = st[n][kb + half * 8 + j];
      h8[j] = f2b(val);
      l8[j] = f2b(val - b2f(h8[j]));
    }
    *(uint4*)(outh + obase + half * 8) = *(uint4*)h8;
    *(uint4*)(outl + obase + half * 8) = *(uint4*)l8;
  }
}

// ---- generic weight transpose -> bf16 [n][k] (per-expert via blockIdx.z) ----
__global__ __launch_bounds__(256) void k_wt(const float* __restrict__ W, u16* __restrict__ Wt,
                                            int K, int N) {
  __shared__ float st[64][65];
  int z = blockIdx.z;
  W += (size_t)z * K * N; Wt += (size_t)z * K * N;
  int k0 = blockIdx.x << 6, n0 = blockIdx.y << 6;
  int tid = threadIdx.x;
  int r = tid >> 2, c4 = (tid & 3) << 4;
  #pragma unroll
  for (int j = 0; j < 16; j += 4) {
    float4 v = *(const float4*)(W + (size_t)(k0 + r) * N + n0 + c4 + j);
    st[c4 + j + 0][r] = v.x; st[c4 + j + 1][r] = v.y;
    st[c4 + j + 2][r] = v.z; st[c4 + j + 3][r] = v.w;
  }
  __syncthreads();
  int n = tid >> 2, kb = (tid & 3) << 4;
  u16 h8[8] __attribute__((aligned(16)));
  size_t obase = (size_t)(n0 + n) * K + k0 + kb;
  #pragma unroll
  for (int half = 0; half < 2; ++half) {
    #pragma unroll
    for (int j = 0; j < 8; ++j) h8[j] = f2b(st[n][kb + half * 8 + j]);
    *(uint4*)(Wt + obase + half * 8) = *(uint4*)h8;
  }
}

// ---- h_lti = LN(-exp(log_A)*h + einj) -> hi/lo bf16 (segment-local) ----
__global__ __launch_bounds__(256) void k_lti(const float* __restrict__ h, const float* __restrict__ lA,
                                             const float* __restrict__ einj,
                                             const float* __restrict__ g, const float* __restrict__ be,
                                             u16* __restrict__ Xh, u16* __restrict__ Xl, int seg0) {
  __shared__ float sa[4], sb[4];
  int rowg = seg0 + blockIdx.x, b = rowg >> 10, tid = threadIdx.x;
  int d0 = tid, d1 = tid + 256;
  size_t gbase = (size_t)rowg * 512;
  size_t lbase = (size_t)blockIdx.x * 512;
  float v0 = -expf(lA[d0]) * h[gbase + d0] + einj[b * 512 + d0];
  float v1 = -expf(lA[d1]) * h[gbase + d1] + einj[b * 512 + d1];
  float s = v0 + v1, ss = v0 * v0 + v1 * v1;
  blockReduce2(s, ss, sa, sb);
  float mu = s * (1.f / 512.f);
  float var = fmaxf(ss * (1.f / 512.f) - mu * mu, 0.f);
  float r = rsqrtf(var + 1e-5f);
  float o0 = (v0 - mu) * r * g[d0] + be[d0];
  float o1 = (v1 - mu) * r * g[d1] + be[d1];
  u16 h0 = f2b(o0), h1 = f2b(o1);
  Xh[lbase + d0] = h0; Xl[lbase + d0] = f2b(o0 - b2f(h0));
  Xh[lbase + d1] = h1; Xl[lbase + d1] = f2b(o1 - b2f(h1));
}

// ---- residual LN: LN(recon(Xh,Xl) + Bv) -> f32 (+ optional bf16 copy, + optional fused gate) ----
__global__ __launch_bounds__(256) void k_ln_res2(const u16* __restrict__ Xh, const u16* __restrict__ Xl,
                                                 const float* __restrict__ Bv,
                                                 const float* __restrict__ g, const float* __restrict__ be,
                                                 float* __restrict__ outf, u16* __restrict__ outb,
                                                 const float* __restrict__ gw, const float* __restrict__ gb,
                                                 float* __restrict__ probs, int* __restrict__ sel,
                                                 float2* __restrict__ wpair) {
  __shared__ float sa[4], sb[4];
  __shared__ float s8[4][8];
  int tid = threadIdx.x, d0 = tid, d1 = tid + 256;
  size_t base = (size_t)blockIdx.x * 512;
  float v0 = b2f(Xh[base + d0]) + b2f(Xl[base + d0]) + Bv[base + d0];
  float v1 = b2f(Xh[base + d1]) + b2f(Xl[base + d1]) + Bv[base + d1];
  float s = v0 + v1, ss = v0 * v0 + v1 * v1;
  blockReduce2(s, ss, sa, sb);
  float mu = s * (1.f / 512.f);
  float var = fmaxf(ss * (1.f / 512.f) - mu * mu, 0.f);
  float r = rsqrtf(var + 1e-5f);
  float o0 = (v0 - mu) * r * g[d0] + be[d0];
  float o1 = (v1 - mu) * r * g[d1] + be[d1];
  outf[base + d0] = o0;
  outf[base + d1] = o1;
  if (outb) { outb[base + d0] = f2b(o0); outb[base + d1] = f2b(o1); }
  if (probs) {
    float4 g0a = *(const float4*)(gw + d0 * 8);
    float4 g0b = *(const float4*)(gw + d0 * 8 + 4);
    float4 g1a = *(const float4*)(gw + d1 * 8);
    float4 g1b = *(const float4*)(gw + d1 * 8 + 4);
    float ga[8] = { o0 * g0a.x + o1 * g1a.x, o0 * g0a.y + o1 * g1a.y,
                    o0 * g0a.z + o1 * g1a.z, o0 * g0a.w + o1 * g1a.w,
                    o0 * g0b.x + o1 * g1b.x, o0 * g0b.y + o1 * g1b.y,
                    o0 * g0b.z + o1 * g1b.z, o0 * g0b.w + o1 * g1b.w };
    #pragma unroll
    for (int off = 32; off; off >>= 1)
      #pragma unroll
      for (int e = 0; e < 8; ++e) ga[e] += __shfl_xor(ga[e], off);
    int lane = tid & 63, wid = tid >> 6;
    if (lane == 0) {
      #pragma unroll
      for (int e = 0; e < 8; ++e) s8[wid][e] = ga[e];
    }
    __syncthreads();
    if (tid == 0) {
      int t = blockIdx.x;
      float acc[8];
      float m = -1e30f;
      #pragma unroll
      for (int e = 0; e < 8; ++e) {
        acc[e] = s8[0][e] + s8[1][e] + s8[2][e] + s8[3][e] + gb[e];
        m = fmaxf(m, acc[e]);
      }
      float p[8], sum = 0.f;
      #pragma unroll
      for (int e = 0; e < 8; ++e) { p[e] = expf(acc[e] - m); sum += p[e]; }
      float inv = 1.f / sum;
      #pragma unroll
      for (int e = 0; e < 8; ++e) { p[e] *= inv; probs[t * 8 + e] = p[e]; }
      int i1 = 0; float m1 = p[0];
      #pragma unroll
      for (int e = 1; e < 8; ++e) if (p[e] > m1) { m1 = p[e]; i1 = e; }
      int i2 = -1; float m2 = -1.f;
      #pragma unroll
      for (int e = 0; e < 8; ++e) if (e != i1 && p[e] > m2) { m2 = p[e]; i2 = e; }
      if (i2 < 0) i2 = (i1 + 1) & 7;
      float den = m1 + m2;
      float invs = (den > 0.f) ? 1.f / den : 0.f;
      sel[t] = i1 | (i2 << 4);
      wpair[t] = make_float2(m1 * invs, m2 * invs);
    }
  }
}

// ---- residual LN (both f32, optional bf16 copy) ----
__global__ __launch_bounds__(256) void k_ln_res(const float* __restrict__ A, const float* __restrict__ Bv,
                                                const float* __restrict__ g, const float* __restrict__ be,
                                                float* __restrict__ outf, u16* __restrict__ outb) {
  __shared__ float sa[4], sb[4];
  int tid = threadIdx.x, d0 = tid, d1 = tid + 256;
  size_t base = (size_t)blockIdx.x * 512;
  float v0 = A[base + d0] + Bv[base + d0];
  float v1 = A[base + d1] + Bv[base + d1];
  float s = v0 + v1, ss = v0 * v0 + v1 * v1;
  blockReduce2(s, ss, sa, sb);
  float mu = s * (1.f / 512.f);
  float var = fmaxf(ss * (1.f / 512.f) - mu * mu, 0.f);
  float r = rsqrtf(var + 1e-5f);
  float o0 = (v0 - mu) * r * g[d0] + be[d0];
  float o1 = (v1 - mu) * r * g[d1] + be[d1];
  outf[base + d0] = o0;
  outf[base + d1] = o1;
  if (outb) { outb[base + d0] = f2b(o0); outb[base + d1] = f2b(o1); }
}

// ---- prefix: 128-aligned per-expert offsets for compact routed layout ----
__global__ __launch_bounds__(64) void k_prefix(const int* __restrict__ cnt, int* __restrict__ off) {
  if (threadIdx.x == 0) {
    int acc = 0;
    for (int e = 0; e < 8; ++e) {
      off[e] = acc;
      int c = cnt[e]; if (c > 8192) c = 8192;
      acc += (c + 127) & ~127;
    }
  }
}

// ---- split-precision MFMA GEMM v3: 128x128 tile, 8 waves (512 thr), double-buffered LDS,
//      register prefetch, ONE barrier per K-step, XCD-chunked tile remap.
template<int NOUT>
__global__ __launch_bounds__(512, 4) void gemm_sp3(
    const u16* __restrict__ Xh, const u16* __restrict__ Xl, int lda,
    const u16* __restrict__ Wth, const u16* __restrict__ Wtl,
    const float* __restrict__ b0c, const float* __restrict__ b1c, const float* __restrict__ b2c,
    float* __restrict__ C0, float* __restrict__ C1, float* __restrict__ C2) {
  int bxi, byi, bzi;
  xcd_remap(bxi, byi, bzi);
  const float* bias = b0c; float* C = C0;
  const u16* Wh = Wth; const u16* Wl = Wtl;
  if (NOUT == 3) {
    int z = bzi;
    Wh += (size_t)z * 262144; Wl += (size_t)z * 262144;
    if (z == 1) { bias = b1c; C = C1; }
    else if (z == 2) { bias = b2c; C = C2; }
  }
  const int bm = byi << 7, bn = bxi << 7;
  __shared__ u16 Ah[2][128][40];
  __shared__ u16 Al[2][128][40];
  __shared__ u16 Bh[2][128][40];
  __shared__ u16 Bl[2][128][40];
  const int tid = threadIdx.x;
  const int sr = tid >> 2, sk = (tid & 3) << 3;
  const int wv = tid >> 6, lane = tid & 63, q = lane >> 4, m16 = lane & 15;
  const int wr = (wv >> 2) << 6;   // 0 / 64
  const int wc = (wv & 3) << 5;    // 0,32,64,96
  const u16* ahr = Xh + (size_t)(bm + sr) * lda;
  const u16* alr = Xl + (size_t)(bm + sr) * lda;
  const u16* bhr = Wh + (size_t)(bn + sr) * 512;
  const u16* blr = Wl + (size_t)(bn + sr) * 512;
  f32x4 acc[4][2];
  #pragma unroll
  for (int m = 0; m < 4; ++m)
    #pragma unroll
    for (int n = 0; n < 2; ++n)
      #pragma unroll
      for (int i = 0; i < 4; ++i) acc[m][n][i] = 0.f;

  uint4 rah = *(const uint4*)(ahr + sk);
  uint4 ral = *(const uint4*)(alr + sk);
  uint4 rbh = *(const uint4*)(bhr + sk);
  uint4 rbl = *(const uint4*)(blr + sk);
  *(uint4*)&Ah[0][sr][sk] = rah;
  *(uint4*)&Al[0][sr][sk] = ral;
  *(uint4*)&Bh[0][sr][sk] = rbh;
  *(uint4*)&Bl[0][sr][sk] = rbl;
  __syncthreads();
  int cur = 0;
  for (int k0 = 0; k0 < 512; k0 += 32) {
    if (k0 + 32 < 512) {
      rah = *(const uint4*)(ahr + k0 + 32 + sk);
      ral = *(const uint4*)(alr + k0 + 32 + sk);
      rbh = *(const uint4*)(bhr + k0 + 32 + sk);
      rbl = *(const uint4*)(blr + k0 + 32 + sk);
    }
    short8 ahf[4], alf[4];
    #pragma unroll
    for (int m = 0; m < 4; ++m) {
      ahf[m] = *(const short8*)&Ah[cur][wr + m * 16 + m16][q * 8];
      alf[m] = *(const short8*)&Al[cur][wr + m * 16 + m16][q * 8];
    }
    #pragma unroll
    for (int n = 0; n < 2; ++n) {
      short8 bhf = *(const short8*)&Bh[cur][wc + n * 16 + m16][q * 8];
      short8 blf = *(const short8*)&Bl[cur][wc + n * 16 + m16][q * 8];
      #pragma unroll
      for (int m = 0; m < 4; ++m) {
        acc[m][n] = __builtin_amdgcn_mfma_f32_16x16x32_bf16(ahf[m], bhf, acc[m][n], 0, 0, 0);
        acc[m][n] = __builtin_amdgcn_mfma_f32_16x16x32_bf16(alf[m], bhf, acc[m][n], 0, 0, 0);
        acc[m][n] = __builtin_amdgcn_mfma_f32_16x16x32_bf16(ahf[m], blf, acc[m][n], 0, 0, 0);
      }
    }
    if (k0 + 32 < 512) {
      *(uint4*)&Ah[cur ^ 1][sr][sk] = rah;
      *(uint4*)&Al[cur ^ 1][sr][sk] = ral;
      *(uint4*)&Bh[cur ^ 1][sr][sk] = rbh;
      *(uint4*)&Bl[cur ^ 1][sr][sk] = rbl;
      __syncthreads();
      cur ^= 1;
    }
  }
  #pragma unroll
  for (int n = 0; n < 2; ++n) {
    int col = bn + wc + n * 16 + m16;
    float bb = bias[col];
    #pragma unroll
    for (int m = 0; m < 4; ++m) {
      #pragma unroll
      for (int i = 0; i < 4; ++i) {
        int rl = bm + wr + m * 16 + q * 4 + i;
        C[(size_t)rl * 512 + col] = acc[m][n][i] + bb;
      }
    }
  }
}

// ---- per-node head attention -> per-row packed [hi(512)|lo(512)] u16, IN PLACE over q row t ----
__global__ __launch_bounds__(64) void k_attn(const float* __restrict__ q, const float* __restrict__ k,
                                             const float* __restrict__ v,
                                             u16* __restrict__ aohl) {
  __shared__ float qs[512], ks[512], vs[512], at[64];
  size_t t = blockIdx.x;
  int lane = threadIdx.x;
  for (int i = lane; i < 512; i += 64) {
    qs[i] = q[t * 512 + i]; ks[i] = k[t * 512 + i]; vs[i] = v[t * 512 + i];
  }
  __syncthreads();
  int h = lane >> 3, g = lane & 7;
  float s = 0.f;
  #pragma unroll 8
  for (int d = 0; d < 64; ++d) s = fmaf(qs[h * 64 + d], ks[g * 64 + d], s);
  s *= 0.125f;
  float m = s;
  #pragma unroll
  for (int off = 1; off < 8; off <<= 1) m = fmaxf(m, __shfl_xor(m, off));
  float ex = expf(s - m);
  float sum = ex;
  #pragma unroll
  for (int off = 1; off < 8; off <<= 1) sum += __shfl_xor(sum, off);
  at[lane] = ex / sum;
  __syncthreads();
  #pragma unroll
  for (int j = 0; j < 8; ++j) {
    int d = lane + j * 64, hh = d >> 6, hd = d & 63;
    float acc = 0.f;
    #pragma unroll
    for (int gg = 0; gg < 8; ++gg) acc = fmaf(at[hh * 8 + gg], vs[gg * 64 + hd], acc);
    u16 hi = f2b(acc);
    aohl[t * 1024 + d] = hi;
    aohl[t * 1024 + 512 + d] = f2b(acc - b2f(hi));
  }
}

// ---- gate phase A (old path only) ----
__global__ __launch_bounds__(256) void k_gateA(const float* __restrict__ h2, const float* __restrict__ gw,
                                               const float* __restrict__ gb, float* __restrict__ probs,
                                               int* __restrict__ sel, float2* __restrict__ wpair) {
  int lane = threadIdx.x & 63, wid = threadIdx.x >> 6;
  int t = blockIdx.x * 4 + wid;
  const float* x = h2 + (size_t)t * 512;
  float acc[8] = {};
  for (int d = lane; d < 512; d += 64) {
    float xv = x[d];
    float4 g0 = *(const float4*)(gw + d * 8);
    float4 g1 = *(const float4*)(gw + d * 8 + 4);
    acc[0] = fmaf(xv, g0.x, acc[0]); acc[1] = fmaf(xv, g0.y, acc[1]);
    acc[2] = fmaf(xv, g0.z, acc[2]); acc[3] = fmaf(xv, g0.w, acc[3]);
    acc[4] = fmaf(xv, g1.x, acc[4]); acc[5] = fmaf(xv, g1.y, acc[5]);
    acc[6] = fmaf(xv, g1.z, acc[6]); acc[7] = fmaf(xv, g1.w, acc[7]);
  }
  #pragma unroll
  for (int off = 32; off; off >>= 1)
    #pragma unroll
    for (int e = 0; e < 8; ++e) acc[e] += __shfl_xor(acc[e], off);
  if (lane == 0) {
    float m = -1e30f;
    #pragma unroll
    for (int e = 0; e < 8; ++e) { acc[e] += gb[e]; m = fmaxf(m, acc[e]); }
    float p[8], sum = 0.f;
    #pragma unroll
    for (int e = 0; e < 8; ++e) { p[e] = expf(acc[e] - m); sum += p[e]; }
    float inv = 1.f / sum;
    #pragma unroll
    for (int e = 0; e < 8; ++e) { p[e] *= inv; probs[t * 8 + e] = p[e]; }
    int i1 = 0; float m1 = p[0];
    #pragma unroll
    for (int e = 1; e < 8; ++e) if (p[e] > m1) { m1 = p[e]; i1 = e; }
    int i2 = -1; float m2 = -1.f;
    #pragma unroll
    for (int e = 0; e < 8; ++e) if (e != i1 && p[e] > m2) { m2 = p[e]; i2 = e; }
    if (i2 < 0) i2 = (i1 + 1) & 7;
    float den = m1 + m2;
    float invs = (den > 0.f) ? 1.f / den : 0.f;
    sel[t] = i1 | (i2 << 4);
    wpair[t] = make_float2(m1 * invs, m2 * invs);
  }
}

// ---- gate phase B ----
__global__ __launch_bounds__(256) void k_gateB(const int* __restrict__ sel, const float2* __restrict__ wpair,
                                               int* __restrict__ toklist, float* __restrict__ wlist,
                                               int* __restrict__ cnt) {
  int e = blockIdx.x;
  int tid = threadIdx.x, lane = tid & 63, wv = tid >> 6;
  __shared__ int wsum[4];
  int base = 0;
  for (int t0 = 0; t0 < 8192; t0 += 256) {
    int t = t0 + tid;
    int s = sel[t];
    int i1 = s & 15, i2 = (s >> 4) & 15;
    bool f = (i1 == e) || (i2 == e);
    float wt = (i1 == e) ? wpair[t].x : ((i2 == e) ? wpair[t].y : 0.f);
    unsigned long long m = __ballot(f);
    int rank = __popcll(m & ((1ull << lane) - 1ull));
    int wtot = __popcll(m);
    if (lane == 0) wsum[wv] = wtot;
    __syncthreads();
    int prev = 0;
    for (int ww = 0; ww < wv; ++ww) prev += wsum[ww];
    int tot = wsum[0] + wsum[1] + wsum[2] + wsum[3];
    if (f) {
      int pos = base + prev + rank;
      toklist[e * 8192 + pos] = t;
      wlist[e * 8192 + pos] = wt;
    }
    base += tot;
    __syncthreads();
  }
  if (tid == 0) cnt[e] = base;
}

// ---- OLD MFMA bf16 GEMM: 64x64 tile (kept for small-workspace tiers) ----
template<int XMODE, int ACT, int OUTMODE, int EXPERT>
__global__ __launch_bounds__(256) void mfma_gemm(
    const float* __restrict__ Xf, const u16* __restrict__ Xb,
    const float* __restrict__ Wg, const float* __restrict__ biasg,
    float* __restrict__ C, u16* __restrict__ C16,
    const int* __restrict__ toklist, const float* __restrict__ wlist,
    const int* __restrict__ cnt, int M, int K, int N, int chunk0,
    size_t hidstride, float* __restrict__ moe) {
  int e = EXPERT ? blockIdx.z : 0;
  const float* W = Wg + (size_t)e * K * N;
  const float* bias = biasg + (size_t)e * N;
  int Mloc = M;
  if (EXPERT) {
    int ce = cnt[e]; if (ce > 8192) ce = 8192;
    Mloc = ce - chunk0;
    if (XMODE == 1) Xb += (size_t)e * hidstride;
    if (OUTMODE == 2) C16 += (size_t)e * hidstride;
  }
  const int bm = blockIdx.y << 6, bn = blockIdx.x << 6;
  if (EXPERT && bm >= Mloc) return;
  __shared__ u16 As[64][40];
  __shared__ u16 Bs[64][40];
  __shared__ int rows[64];
  const int tid = threadIdx.x;
  if (EXPERT && XMODE == 2 && tid < 64) {
    int ce = cnt[e]; if (ce > 8192) ce = 8192;
    int r = chunk0 + bm + tid;
    rows[tid] = toklist[e * 8192 + (r < ce ? r : chunk0)] & 8191;
  }
  const int srow = tid >> 2;
  const int skg = (tid & 3) << 3;
  const int wv = tid >> 6, lane = tid & 63, q = lane >> 4, m16 = lane & 15;
  f32x4 acc[4];
  #pragma unroll
  for (int c = 0; c < 4; ++c)
    #pragma unroll
    for (int i = 0; i < 4; ++i) acc[c][i] = 0.f;

  for (int k0 = 0; k0 < K; k0 += 32) {
    __syncthreads();
    {
      u16 a8[8] __attribute__((aligned(16)));
      if (XMODE == 1) {
        *(uint4*)a8 = *(const uint4*)(Xb + (size_t)(bm + srow) * K + k0 + skg);
      } else {
        const float* src = (XMODE == 2) ? (Xf + (size_t)rows[srow] * K + k0 + skg)
                                        : (Xf + (size_t)(bm + srow) * K + k0 + skg);
        float4 x0 = *(const float4*)(src);
        float4 x1 = *(const float4*)(src + 4);
        a8[0] = f2b(x0.x); a8[1] = f2b(x0.y); a8[2] = f2b(x0.z); a8[3] = f2b(x0.w);
        a8[4] = f2b(x1.x); a8[5] = f2b(x1.y); a8[6] = f2b(x1.z); a8[7] = f2b(x1.w);
      }
      *(uint4*)&As[srow][skg] = *(uint4*)a8;
    }
    {
      u16 b8[8] __attribute__((aligned(16)));
      const float* src = W + (size_t)(k0 + skg) * N + bn + srow;
      #pragma unroll
      for (int j = 0; j < 8; ++j) b8[j] = f2b(src[(size_t)j * N]);
      *(uint4*)&Bs[srow][skg] = *(uint4*)b8;
    }
    __syncthreads();
    short8 af = *(const short8*)&As[wv * 16 + m16][q * 8];
    #pragma unroll
    for (int c = 0; c < 4; ++c) {
      short8 bf = *(const short8*)&Bs[c * 16 + m16][q * 8];
      acc[c] = __builtin_amdgcn_mfma_f32_16x16x32_bf16(af, bf, acc[c], 0, 0, 0);
    }
  }
  #pragma unroll
  for (int c = 0; c < 4; ++c) {
    int col = bn + c * 16 + m16;
    float bb = bias[col];
    #pragma unroll
    for (int i = 0; i < 4; ++i) {
      int rl = bm + wv * 16 + q * 4 + i;
      if (EXPERT && rl >= Mloc) continue;
      float v = acc[c][i] + bb;
      if (ACT == 1) v = v / (1.f + expf(-v));
      else if (ACT == 2) v = tanhf(v);
      if (OUTMODE == 0) C[(size_t)rl * N + col] = v;
      else if (OUTMODE == 1) C[(size_t)rl * N + col] += v;
      else if (OUTMODE == 2) C16[(size_t)rl * N + col] = f2b(v);
      else {
        int rg = chunk0 + rl;
        int tok = toklist[e * 8192 + rg] & 8191;
        float wt = wlist[e * 8192 + rg];
        atomicAdd(&moe[(size_t)tok * 512 + col], v * wt);
      }
    }
  }
}

// ---- FAST MFMA bf16 GEMM v3: 128x128 tile, 8 waves (512 thr), double-buffered LDS,
//      register prefetch, ONE barrier per K-step, XCD-chunked tile remap.
// XMODE: 1 dense bf16, 2 gathered bf16 rows (toklist), 3 per-expert bf16 (Xb += e*hidstride)
// ACT: 0 none, 1 silu, 2 tanh
// OUTMODE: 0 f32 store, 1 f32 +=, 2 bf16 store, 3 weighted scatter-atomicAdd, 4 dense atomicAdd
// EXPERT: 0 none; 1 routed chunked (z=expert); 2 dense-z (z offsets W/bias/hid);
//         3 routed COMPACT (expert found from 128-aligned off[]=cnt+8; hid rows = global compact idx)
template<int XMODE, int ACT, int OUTMODE, int EXPERT>
__global__ __launch_bounds__(512, 4) void mfma_gemm3(
    const u16* __restrict__ Xb, const u16* __restrict__ Wt, const float* __restrict__ biasg,
    float* __restrict__ C, u16* __restrict__ C16,
    const int* __restrict__ toklist, const float* __restrict__ wlist,
    const int* __restrict__ cnt, int M, int K, int N, int chunk0,
    size_t hidstride, float* __restrict__ moe) {
  int bxi, byi, bzi;
  xcd_remap(bxi, byi, bzi);
  const int bm = byi << 7, bn = bxi << 7;
  int e = 0, offe = 0;
  int Mloc = M;
  if (EXPERT == 1) {
    e = bzi;
    int ce = cnt[e]; if (ce > 8192) ce = 8192;
    Mloc = ce - chunk0;
    if (bm >= Mloc) return;
  } else if (EXPERT == 2) {
    e = bzi;
  } else if (EXPERT == 3) {
    const int* off = cnt + 8;
    int found = -1;
    #pragma unroll
    for (int ee = 0; ee < 8; ++ee) {
      int c = cnt[ee]; if (c > 8192) c = 8192;
      int st = off[ee], len = (c + 127) & ~127;
      if (found < 0 && bm >= st && bm < st + len) found = ee;
    }
    if (found < 0) return;
    e = found; offe = off[e];
    int ce = cnt[e]; if (ce > 8192) ce = 8192;
    Mloc = offe + ce;
    if (bm >= Mloc) return;
  }
  const u16* W = Wt + (size_t)e * K * N;
  const float* bias = biasg + (size_t)e * N;
  if (EXPERT == 1 || EXPERT == 2) {
    if (XMODE == 3) Xb += (size_t)e * hidstride;
    if (OUTMODE == 2) C16 += (size_t)e * hidstride;
  }
  __shared__ u16 As[2][128][40];
  __shared__ u16 Bs[2][128][40];
  __shared__ int rows[128];
  const int tid = threadIdx.x;
  if (XMODE == 2) {
    if (tid < 128) {
      int ce = cnt[e]; if (ce > 8192) ce = 8192;
      int r = (EXPERT == 3) ? (bm - offe + tid) : (chunk0 + bm + tid);
      rows[tid] = toklist[e * 8192 + (r < ce ? r : (ce > 0 ? ce - 1 : 0))] & 8191;
    }
    __syncthreads();
  }
  const int sr = tid >> 2, sk = (tid & 3) << 3;
  const int wv = tid >> 6, lane = tid & 63, q = lane >> 4, m16 = lane & 15;
  const int wr = (wv >> 2) << 6;
  const int wc = (wv & 3) << 5;
  const u16* arow = (XMODE == 2) ? (Xb + (size_t)rows[sr] * K) : (Xb + (size_t)(bm + sr) * K);
  const u16* brow = W + (size_t)(bn + sr) * K;
  f32x4 acc[4][2];
  #pragma unroll
  for (int m = 0; m < 4; ++m)
    #pragma unroll
    for (int n = 0; n < 2; ++n)
      #pragma unroll
      for (int i = 0; i < 4; ++i) acc[m][n][i] = 0.f;

  uint4 ar = *(const uint4*)(arow + sk);
  uint4 br = *(const uint4*)(brow + sk);
  *(uint4*)&As[0][sr][sk] = ar;
  *(uint4*)&Bs[0][sr][sk] = br;
  __syncthreads();
  int cur = 0;
  for (int k0 = 0; k0 < K; k0 += 32) {
    if (k0 + 32 < K) {
      ar = *(const uint4*)(arow + k0 + 32 + sk);
      br = *(const uint4*)(brow + k0 + 32 + sk);
    }
    short8 af[4];
    #pragma unroll
    for (int m = 0; m < 4; ++m)
      af[m] = *(const short8*)&As[cur][wr + m * 16 + m16][q * 8];
    short8 bf[2];
    #pragma unroll
    for (int n = 0; n < 2; ++n)
      bf[n] = *(const short8*)&Bs[cur][wc + n * 16 + m16][q * 8];
    #pragma unroll
    for (int n = 0; n < 2; ++n)
      #pragma unroll
      for (int m = 0; m < 4; ++m)
        acc[m][n] = __builtin_amdgcn_mfma_f32_16x16x32_bf16(af[m], bf[n], acc[m][n], 0, 0, 0);
    if (k0 + 32 < K) {
      *(uint4*)&As[cur ^ 1][sr][sk] = ar;
      *(uint4*)&Bs[cur ^ 1][sr][sk] = br;
      __syncthreads();
      cur ^= 1;
    }
  }
  #pragma unroll
  for (int n = 0; n < 2; ++n) {
    int col = bn + wc + n * 16 + m16;
    float bb = bias[col];
    #pragma unroll
    for (int m = 0; m < 4; ++m) {
      #pragma unroll
      for (int i = 0; i < 4; ++i) {
        int rl = bm + wr + m * 16 + q * 4 + i;
        if ((EXPERT == 1 || EXPERT == 3) && rl >= Mloc) continue;
        float v = acc[m][n][i] + bb;
        if (ACT == 1) v = v / (1.f + expf(-v));
        else if (ACT == 2) v = tanhf(v);
        if (OUTMODE == 0) C[(size_t)rl * N + col] = v;
        else if (OUTMODE == 1) C[(size_t)rl * N + col] += v;
        else if (OUTMODE == 2) C16[(size_t)rl * N + col] = f2b(v);
        else if (OUTMODE == 3) {
          int rg = (EXPERT == 3) ? (rl - offe) : (chunk0 + rl);
          int tok = toklist[e * 8192 + rg] & 8191;
          float wt = wlist[e * 8192 + rg];
          atomicAdd(&moe[(size_t)tok * 512 + col], v * wt);
        } else {
          atomicAdd(&C[(size_t)rl * N + col], v);
        }
      }
    }
  }
}

// ---- halt head ----
__global__ __launch_bounds__(256) void k_halt(const u16* __restrict__ hh, const float* __restrict__ hW2,
                                              const float* __restrict__ hb2, float* __restrict__ out) {
  int lane = threadIdx.x & 63, wid = threadIdx.x >> 6;
  int t = blockIdx.x * 4 + wid;
  const u16* x = hh + (size_t)t * 256;
  float a = b2f(x[lane]) * hW2[lane] + b2f(x[lane + 64]) * hW2[lane + 64] +
            b2f(x[lane + 128]) * hW2[lane + 128] + b2f(x[lane + 192]) * hW2[lane + 192];
  #pragma unroll
  for (int off = 32; off; off >>= 1) a += __shfl_xor(a, off);
  if (lane == 0) {
    float p = 1.f / (1.f + expf(-(a + hb2[0])));
    out[4194304 + t] = p;
    out[4194304 + 8192 + t] = p;
  }
}

// ---- scalar: stab + aux loss ----
__global__ __launch_bounds__(256) void k_final(const float* __restrict__ probs, const int* __restrict__ cnt,
                                               const float* __restrict__ lA, float* __restrict__ out) {
  __shared__ float sp[4][8];
  __shared__ float sm[4];
  int tid = threadIdx.x, lane = tid & 63, wid = tid >> 6;
  float part[8] = {};
  for (int i = tid; i < 8192; i += 256) {
    const float* p = probs + i * 8;
    #pragma unroll
    for (int e = 0; e < 8; ++e) part[e] += p[e];
  }
  #pragma unroll
  for (int off = 32; off; off >>= 1)
    #pragma unroll
    for (int e = 0; e < 8; ++e) part[e] += __shfl_xor(part[e], off);
  float mx = 0.f;
  for (int d = tid; d < 512; d += 256) mx = fmaxf(mx, expf(lA[d]));
  #pragma unroll
  for (int off = 32; off; off >>= 1) mx = fmaxf(mx, __shfl_xor(mx, off));
  if (lane == 0) {
    #pragma unroll
    for (int e = 0; e < 8; ++e) sp[wid][e] = part[e];
    sm[wid] = mx;
  }
  __syncthreads();
  if (tid == 0) {
    float loss = 0.f;
    for (int e = 0; e < 8; ++e) {
      float pm = (sp[0][e] + sp[1][e] + sp[2][e] + sp[3][e]) * (1.f / 8192.f);
      int c = cnt[e]; if (c > 8192) c = 8192;
      loss += (float)c * (1.f / 8192.f) * pm;
    }
    loss *= 0.01f * 8.f;
    float mall = fmaxf(fmaxf(sm[0], sm[1]), fmaxf(sm[2], sm[3]));
    out[4194304 + 16384] = fmaxf(mall - 0.95f, 0.f) + loss;
  }
}

extern "C" void kernel_launch(void* const* d_in, const int* in_sizes, int n_in,
                              void* d_out, int out_size, void* d_ws, size_t ws_size,
                              hipStream_t stream) {
  const float* h   = (const float*)d_in[0];
  const float* ef  = (const float*)d_in[1];
  const float* lA  = (const float*)d_in[2];
  const float* Bw  = (const float*)d_in[3];
  const float* Bb  = (const float*)d_in[4];
  const float* Wq  = (const float*)d_in[5];  const float* bq  = (const float*)d_in[6];
  const float* Wk  = (const float*)d_in[7];  const float* bk  = (const float*)d_in[8];
  const float* Wv  = (const float*)d_in[9];  const float* bv  = (const float*)d_in[10];
  const float* Wo  = (const float*)d_in[11]; const float* bo  = (const float*)d_in[12];
  const float* n1g = (const float*)d_in[13]; const float* n1b = (const float*)d_in[14];
  const float* n2g = (const float*)d_in[15]; const float* n2b = (const float*)d_in[16];
  const float* n3g = (const float*)d_in[17]; const float* n3b = (const float*)d_in[18];
  const float* gw  = (const float*)d_in[19]; const float* gb  = (const float*)d_in[20];
  const float* eW1 = (const float*)d_in[21]; const float* eb1 = (const float*)d_in[22];
  const float* eW2 = (const float*)d_in[23]; const float* eb2 = (const float*)d_in[24];
  const float* sW1 = (const float*)d_in[25]; const float* sb1 = (const float*)d_in[26];
  const float* sW2 = (const float*)d_in[27]; const float* sb2 = (const float*)d_in[28];
  const float* hW1 = (const float*)d_in[29]; const float* hb1 = (const float*)d_in[30];
  const float* hW2 = (const float*)d_in[31]; const float* hb2 = (const float*)d_in[32];
  float* out = (float*)d_out;
  float* ws = (float*)d_ws;

  // ---- tiered workspace layout ----
  const size_t R = (size_t)TT * DD;   // 4,194,304 floats
  const size_t SM = 155648 + 73744;
  size_t wsf = ws_size / 4;
  int S; size_t ARENA;
  bool FAST;
  if (wsf >= 6 * R + SM)      { S = 8192; ARENA = 4 * R; FAST = true; }
  else if (wsf >= 3 * R + SM) { S = 2048; ARENA = R; FAST = false; }
  else                        { S = 512;  ARENA = 1048576; FAST = false; }
  const int CAPE = (int)(ARENA / 4096);
  const int NCH  = 8192 / CAPE;
  const size_t HIDSTRIDE = (size_t)CAPE * 1024;
  const int CAPS = (ARENA / 512 >= 8192) ? 8192 : (int)(ARENA / 512);

  float* f_h2  = ws;
  float* f_moe = ws + R;
  float* arena = ws + 2 * R;
  const size_t SD = (size_t)S * 512;
  u16* f_xh = (u16*)arena;
  u16* f_xl = f_xh + SD;
  float* f_q = arena + SD;
  float* f_k = arena + 2 * SD;
  float* f_v = arena + 3 * SD;
  u16* f_aohl = (u16*)f_q;
  float* f_hp = f_k;
  u16* f_wh = (u16*)f_moe;             // [4][512][512] split QKV/Wo weights (hi)
  u16* f_wl = f_wh + 4 * 262144;       // (lo)
  u16* f_hid = (u16*)arena;            // old-path hid
  u16* f_hh  = (u16*)arena;            // old-path halt hid
  // FAST-path arena carve (u16 indices into arena; arena = 4R floats = 8R u16 = 33554432):
  //   hidC  [0, 17825792)          17408 rows x 1024 (compact routed; shared uses 2x8192 rows)
  //   eW1t  [17825792, 22020096)
  //   eW2t  [22020096, 26214400)
  //   h2b   [26214400, 30408704)   over dead v region (written by ln_res2)
  //   sW1t  [30408704, 31457280)
  //   sW2t  [31457280, 32505856)
  //   (after routed experts, hidC dead -> halt scratch:)
  //   h3b [0, 4194304) | hW1t [4194304, 4325376) | hh3 [4325376, 6422528)
  u16* a16 = (u16*)arena;
  u16* f_hidC = a16;
  u16* f_eW1t = a16 + 17825792;
  u16* f_eW2t = a16 + 22020096;
  u16* f_h2b  = a16 + 26214400;
  u16* f_sW1t = a16 + 30408704;
  u16* f_sW2t = a16 + 31457280;
  u16* f_h3b  = a16;
  u16* f_hW1t = a16 + 4194304;
  u16* f_hh3  = a16 + 4325376;
  float* smr = ws + 2 * R + ARENA;
  float* f_esum = smr;
  float* f_einj = smr + 4096;
  float* f_probs = smr + 8192;
  float2* f_wpair = (float2*)(smr + 8192 + 65536);
  float* f_wlist = smr + 8192 + 65536 + 16384;
  int* ip = (int*)(smr + 8192 + 65536 + 16384 + 65536);
  int* sel = ip; int* cnt = ip + 8192; int* off = ip + 8192 + 8; int* toklist = ip + 8192 + 16;

  // ---- LTI prep + QKV weight split ----
  k_zero<<<16, 256, 0, stream>>>(f_esum);
  k_esum<<<dim3(8, 32), 256, 0, stream>>>(ef, f_esum);
  k_einj<<<16, 256, 0, stream>>>(f_esum, Bw, Bb, f_einj);
  k_wsplit<<<dim3(8, 8, 4), 256, 0, stream>>>(Wq, Wk, Wv, Wo, f_wh, f_wl);

  // ---- LTI + attention (v3 split-precision GEMMs; gate fused into ln_res2 in FAST) ----
  for (int s = 0; s < TT / S; ++s) {
    int seg0 = s * S;
    k_lti<<<S, 256, 0, stream>>>(h, lA, f_einj, n1g, n1b, f_xh, f_xl, seg0);
    gemm_sp3<3><<<dim3(4, S / 128, 3), 512, 0, stream>>>(
        f_xh, f_xl, 512, f_wh, f_wl, bq, bk, bv, f_q, f_k, f_v);
    k_attn<<<S, 64, 0, stream>>>(f_q, f_k, f_v, f_aohl);
    gemm_sp3<1><<<dim3(4, S / 128, 1), 512, 0, stream>>>(
        f_aohl, f_aohl + 512, 1024, f_wh + 3 * 262144, f_wl + 3 * 262144,
        bo, nullptr, nullptr, f_hp, nullptr, nullptr);
    if (FAST)
      k_ln_res2<<<S, 256, 0, stream>>>(f_xh, f_xl, f_hp, n2g, n2b,
                                       f_h2, f_h2b, gw, gb, f_probs, sel, f_wpair);
    else
      k_ln_res2<<<S, 256, 0, stream>>>(f_xh, f_xl, f_hp, n2g, n2b,
                                       f_h2 + (size_t)seg0 * 512, nullptr,
                                       nullptr, nullptr, nullptr, nullptr, nullptr);
  }

  // ---- gate compaction ----
  if (!FAST)
    k_gateA<<<TT / 4, 256, 0, stream>>>(f_h2, gw, gb, f_probs, sel, f_wpair);
  k_gateB<<<8, 256, 0, stream>>>(sel, f_wpair, toklist, f_wlist, cnt);

  if (FAST) {
    k_prefix<<<1, 64, 0, stream>>>(cnt, off);
    // ---- convert MoE weights to bf16 [n][k] ----
    k_wt<<<dim3(8, 16, 8), 256, 0, stream>>>(eW1, f_eW1t, 512, 1024);
    k_wt<<<dim3(16, 8, 8), 256, 0, stream>>>(eW2, f_eW2t, 1024, 512);
    k_wt<<<dim3(8, 16, 2), 256, 0, stream>>>(sW1, f_sW1t, 512, 1024);
    k_wt<<<dim3(16, 8, 2), 256, 0, stream>>>(sW2, f_sW2t, 1024, 512);

    // ---- shared experts: W1 dense-z; W2 sx0 store, sx1 += (no zeroing, no atomics) ----
    mfma_gemm3<1,1,2,2><<<dim3(8, 64, 2), 512, 0, stream>>>(
        f_h2b, f_sW1t, sb1, nullptr, f_hidC, nullptr, nullptr, nullptr,
        TT, 512, 1024, 0, (size_t)TT * 1024, nullptr);
    mfma_gemm3<1,0,0,0><<<dim3(4, 64), 512, 0, stream>>>(
        f_hidC, f_sW2t, sb2, f_moe, nullptr, nullptr, nullptr, nullptr,
        TT, 1024, 512, 0, 0, nullptr);
    mfma_gemm3<1,0,1,0><<<dim3(4, 64), 512, 0, stream>>>(
        f_hidC + (size_t)TT * 1024, f_sW2t + 524288, sb2 + 512, f_moe, nullptr,
        nullptr, nullptr, nullptr, TT, 1024, 512, 0, 0, nullptr);

    // ---- routed experts: compact layout, ONE dispatch per GEMM ----
    mfma_gemm3<2,1,2,3><<<dim3(8, 136), 512, 0, stream>>>(
        f_h2b, f_eW1t, eb1, nullptr, f_hidC, toklist, nullptr, cnt,
        0, 512, 1024, 0, 0, nullptr);
    mfma_gemm3<1,0,3,3><<<dim3(4, 136), 512, 0, stream>>>(
        f_hidC, f_eW2t, eb2, nullptr, nullptr, toklist, f_wlist, cnt,
        0, 1024, 512, 0, 0, f_moe);

    // ---- final LN (f32 out + bf16 h3b), halt head via v3 GEMM ----
    k_ln_res<<<TT, 256, 0, stream>>>(f_h2, f_moe, n3g, n3b, out, f_h3b);
    k_wt<<<dim3(8, 4, 1), 256, 0, stream>>>(hW1, f_hW1t, 512, 256);
    mfma_gemm3<1,2,2,0><<<dim3(2, 64), 512, 0, stream>>>(
        f_h3b, f_hW1t, hb1, nullptr, f_hh3, nullptr, nullptr, nullptr,
        TT, 512, 256, 0, 0, nullptr);
    k_halt<<<TT / 4, 256, 0, stream>>>(f_hh3, hW2, hb2, out);
  } else {
    // ---- old path (small workspace tiers) ----
    for (int sx = 0; sx < 2; ++sx)
      for (int c = 0; c < TT / CAPS; ++c) {
        const float* xs = f_h2 + (size_t)c * CAPS * 512;
        float* ms = f_moe + (size_t)c * CAPS * 512;
        mfma_gemm<0,1,2,0><<<dim3(16, CAPS / 64), 256, 0, stream>>>(
            xs, nullptr, sW1 + (size_t)sx * 524288, sb1 + sx * 1024,
            nullptr, f_hid, nullptr, nullptr, nullptr, CAPS, 512, 1024, 0, 0, nullptr);
        if (sx == 0)
          mfma_gemm<1,0,0,0><<<dim3(8, CAPS / 64), 256, 0, stream>>>(
              nullptr, f_hid, sW2, sb2, ms, nullptr, nullptr, nullptr, nullptr, CAPS, 1024, 512, 0, 0, nullptr);
        else
          mfma_gemm<1,0,1,0><<<dim3(8, CAPS / 64), 256, 0, stream>>>(
              nullptr, f_hid, sW2 + 524288, sb2 + 512, ms, nullptr, nullptr, nullptr, nullptr, CAPS, 1024, 512, 0, 0, nullptr);
      }
    for (int c = 0; c < NCH; ++c) {
      mfma_gemm<2,1,2,1><<<dim3(16, CAPE / 64, 8), 256, 0, stream>>>(
          f_h2, nullptr, eW1, eb1, nullptr, f_hid, toklist, nullptr, cnt,
          CAPE, 512, 1024, c * CAPE, HIDSTRIDE, nullptr);
      mfma_gemm<1,0,3,1><<<dim3(8, CAPE / 64, 8), 256, 0, stream>>>(
          nullptr, f_hid, eW2, eb2, nullptr, nullptr, toklist, f_wlist, cnt,
          CAPE, 1024, 512, c * CAPE, HIDSTRIDE, f_moe);
    }
    k_ln_res<<<TT, 256, 0, stream>>>(f_h2, f_moe, n3g, n3b, out, nullptr);
    mfma_gemm<0,2,2,0><<<dim3(4, 128), 256, 0, stream>>>(
        out, nullptr, hW1, hb1, nullptr, f_hh, nullptr, nullptr, nullptr, TT, 512, 256, 0, 0, nullptr);
    k_halt<<<TT / 4, 256, 0, stream>>>(f_hh, hW2, hb2, out);
  }

  k_final<<<1, 256, 0, stream>>>(f_probs, cnt, lA, out);
}